// Round 1
// baseline (2779.554 us; speedup 1.0000x reference)
//
#include <hip/hip_runtime.h>
#include <math.h>

typedef __attribute__((ext_vector_type(8))) short short8;
typedef __attribute__((ext_vector_type(4))) float float4_t;

#define DEV static __device__ __forceinline__

DEV unsigned short f2b(float f) {
    union { float f; unsigned int u; } x; x.f = f;
    unsigned int r = x.u + 0x7fffu + ((x.u >> 16) & 1u);
    return (unsigned short)(r >> 16);
}
DEV float b2f(unsigned short u) {
    union { unsigned int u; float f; } x; x.u = ((unsigned int)u) << 16;
    return x.f;
}
DEV float gelu_f(float x) {
    float x3 = x * x * x;
    return 0.5f * x * (1.0f + tanhf(0.7978845608028654f * (x + 0.044715f * x3)));
}

// ---------------------------------------------------------------------------
// Tiled transpose + cast: W (K x N, f32) -> WT (N x K, bf16)
// ---------------------------------------------------------------------------
__global__ __launch_bounds__(256) void transpose_cast_kernel(
    const float* __restrict__ W, unsigned short* __restrict__ WT, int Kd, int Nd)
{
    __shared__ float tile[32][33];
    int n0 = blockIdx.x * 32, k0 = blockIdx.y * 32;
    int tx = threadIdx.x & 31, ty = threadIdx.x >> 5;   // 32 x 8
    #pragma unroll
    for (int r = ty; r < 32; r += 8)
        tile[r][tx] = W[(size_t)(k0 + r) * Nd + n0 + tx];
    __syncthreads();
    #pragma unroll
    for (int r = ty; r < 32; r += 8)
        WT[(size_t)(n0 + r) * Kd + k0 + tx] = f2b(tile[tx][r]);
}

// ---------------------------------------------------------------------------
// copy x -> XL (f32), XG (f32), XB (bf16)
// ---------------------------------------------------------------------------
__global__ __launch_bounds__(256) void copy_cast_kernel(
    const float* __restrict__ x, float* __restrict__ xl, float* __restrict__ xg,
    unsigned short* __restrict__ xb, int n)
{
    int i = blockIdx.x * 256 + threadIdx.x;
    if (i < n) { float v = x[i]; xl[i] = v; xg[i] = v; xb[i] = f2b(v); }
}

// ---------------------------------------------------------------------------
// bf16 MFMA GEMM: C = A(MxK) @ B(KxN) + bias, optional GELU, optional residual
// A: M x K bf16 row-major.  BT: N x K bf16 row-major (B transposed).
// ---------------------------------------------------------------------------
__global__ __launch_bounds__(256) void gemm_kernel(
    const unsigned short* __restrict__ A,
    const unsigned short* __restrict__ BT,
    const float* __restrict__ bias,
    const float* __restrict__ residual,
    float* __restrict__ Cf,
    unsigned short* __restrict__ Cb,
    int M, int N, int K, int act)
{
    __shared__ __align__(16) unsigned short As[64 * 32];
    __shared__ __align__(16) unsigned short Bs[64 * 32];
    const int tid = threadIdx.x;
    const int wave = tid >> 6, lane = tid & 63;
    const int quad = lane >> 4, l16 = lane & 15;
    const int m0 = blockIdx.x * 64, n0 = blockIdx.y * 64;
    const int wm = (wave >> 1) * 32, wn = (wave & 1) * 32;

    float4_t acc[2][2];
    #pragma unroll
    for (int i = 0; i < 2; i++)
        #pragma unroll
        for (int j = 0; j < 2; j++)
            acc[i][j] = (float4_t){0.f, 0.f, 0.f, 0.f};

    const int srow = tid >> 2;
    const int scol = (tid & 3) * 8;
    const unsigned short* Ag = A  + (size_t)(m0 + srow) * K + scol;
    const unsigned short* Bg = BT + (size_t)(n0 + srow) * K + scol;
    unsigned short* AsW = As + srow * 32 + scol;
    unsigned short* BsW = Bs + srow * 32 + scol;

    for (int k0 = 0; k0 < K; k0 += 32) {
        *(uint4*)AsW = *(const uint4*)(Ag + k0);
        *(uint4*)BsW = *(const uint4*)(Bg + k0);
        __syncthreads();
        short8 a0 = *(const short8*)(As + (wm +      l16) * 32 + quad * 8);
        short8 a1 = *(const short8*)(As + (wm + 16 + l16) * 32 + quad * 8);
        short8 b0 = *(const short8*)(Bs + (wn +      l16) * 32 + quad * 8);
        short8 b1 = *(const short8*)(Bs + (wn + 16 + l16) * 32 + quad * 8);
        acc[0][0] = __builtin_amdgcn_mfma_f32_16x16x32_bf16(a0, b0, acc[0][0], 0, 0, 0);
        acc[0][1] = __builtin_amdgcn_mfma_f32_16x16x32_bf16(a0, b1, acc[0][1], 0, 0, 0);
        acc[1][0] = __builtin_amdgcn_mfma_f32_16x16x32_bf16(a1, b0, acc[1][0], 0, 0, 0);
        acc[1][1] = __builtin_amdgcn_mfma_f32_16x16x32_bf16(a1, b1, acc[1][1], 0, 0, 0);
        __syncthreads();
    }

    #pragma unroll
    for (int i = 0; i < 2; i++) {
        #pragma unroll
        for (int j = 0; j < 2; j++) {
            int col = n0 + wn + j * 16 + l16;
            float bv = bias[col];
            #pragma unroll
            for (int r = 0; r < 4; r++) {
                int row = m0 + wm + i * 16 + quad * 4 + r;
                float v = acc[i][j][r] + bv;
                if (act == 1) v = gelu_f(v);
                size_t idx = (size_t)row * N + col;
                if (residual) v += residual[idx];
                if (Cf) Cf[idx] = v;
                if (Cb) Cb[idx] = f2b(v);
            }
        }
    }
}

// ---------------------------------------------------------------------------
// LayerNorm over D=512. One block (256 thr) per row. Optional f32/bf16 outs.
// ---------------------------------------------------------------------------
__global__ __launch_bounds__(256) void ln_kernel(
    const float* __restrict__ X, const float* __restrict__ g, const float* __restrict__ b,
    float* __restrict__ Yf, unsigned short* __restrict__ Yb)
{
    const int row = blockIdx.x, tid = threadIdx.x;
    const float* xr = X + (size_t)row * 512;
    float v0 = xr[tid], v1 = xr[tid + 256];
    float s = v0 + v1;
    #pragma unroll
    for (int o = 32; o > 0; o >>= 1) s += __shfl_down(s, o);
    __shared__ float red[4];
    __shared__ float stat[2];
    if ((tid & 63) == 0) red[tid >> 6] = s;
    __syncthreads();
    if (tid == 0) stat[0] = (red[0] + red[1] + red[2] + red[3]) * (1.0f / 512.0f);
    __syncthreads();
    float mu = stat[0];
    float d0 = v0 - mu, d1 = v1 - mu;
    float s2 = d0 * d0 + d1 * d1;
    #pragma unroll
    for (int o = 32; o > 0; o >>= 1) s2 += __shfl_down(s2, o);
    if ((tid & 63) == 0) red[tid >> 6] = s2;
    __syncthreads();
    if (tid == 0) stat[1] = rsqrtf((red[0] + red[1] + red[2] + red[3]) * (1.0f / 512.0f) + 1e-5f);
    __syncthreads();
    float rs = stat[1];
    float y0 = d0 * rs * g[tid] + b[tid];
    float y1 = d1 * rs * g[tid + 256] + b[tid + 256];
    if (Yf) { float* yr = Yf + (size_t)row * 512; yr[tid] = y0; yr[tid + 256] = y1; }
    if (Yb) { unsigned short* yb = Yb + (size_t)row * 512; yb[tid] = f2b(y0); yb[tid + 256] = f2b(y1); }
}

// ---------------------------------------------------------------------------
// Local windowed attention. One block per (b, window, head). W=32, HD=64.
// QKV: (B*S) x 1536 bf16 (q | k | v, each h-major 8x64). OUT: (B*S) x 512 bf16.
// ---------------------------------------------------------------------------
__global__ __launch_bounds__(256) void local_attn_kernel(
    const unsigned short* __restrict__ QKV, const float* __restrict__ rel,
    unsigned short* __restrict__ OUT)
{
    const int blk = blockIdx.x;          // (b*128 + win)*8 + h
    const int h = blk & 7;
    const int win = (blk >> 3) & 127;
    const int b = blk >> 10;
    const int rowbase = b * 4096 + win * 32;
    __shared__ float q[32][64], k[32][64], v[32][64];
    __shared__ float sc[32][33];
    const int tid = threadIdx.x;
    for (int idx = tid; idx < 2048; idx += 256) {
        int i = idx >> 6, d = idx & 63;
        const unsigned short* base = QKV + (size_t)(rowbase + i) * 1536 + h * 64 + d;
        q[i][d] = b2f(base[0]);
        k[i][d] = b2f(base[512]);
        v[i][d] = b2f(base[1024]);
    }
    __syncthreads();
    for (int idx = tid; idx < 1024; idx += 256) {
        int i = idx >> 5, j = idx & 31;
        float s = 0.f;
        #pragma unroll
        for (int d = 0; d < 64; d++) s += q[i][d] * k[j][d];
        sc[i][j] = s * 0.125f + rel[(i - j + 31) * 8 + h];
    }
    __syncthreads();
    if (tid < 32) {
        float mx = -1e30f;
        for (int j = 0; j < 32; j++) mx = fmaxf(mx, sc[tid][j]);
        float sum = 0.f;
        for (int j = 0; j < 32; j++) { float e = expf(sc[tid][j] - mx); sc[tid][j] = e; sum += e; }
        float inv = 1.0f / sum;
        for (int j = 0; j < 32; j++) sc[tid][j] *= inv;
    }
    __syncthreads();
    for (int idx = tid; idx < 2048; idx += 256) {
        int i = idx >> 6, d = idx & 63;
        float o = 0.f;
        #pragma unroll
        for (int j = 0; j < 32; j++) o += sc[i][j] * v[j][d];
        OUT[(size_t)(rowbase + i) * 512 + h * 64 + d] = f2b(o);
    }
}

// ---------------------------------------------------------------------------
// Gather strided tokens for global attention: XS[b,t,d] = bf16(XG[b, t*32, d])
// ---------------------------------------------------------------------------
__global__ __launch_bounds__(256) void gather_xs_kernel(
    const float* __restrict__ XG, unsigned short* __restrict__ XSB)
{
    int i = blockIdx.x * 256 + threadIdx.x;   // 4*128*512 = 262144
    if (i < 262144) {
        int d = i & 511, t = (i >> 9) & 127, b = i >> 16;
        XSB[i] = f2b(XG[((size_t)b * 4096 + t * 32) * 512 + d]);
    }
}

// ---------------------------------------------------------------------------
// Global attention on 128 tokens/batch. Block per (b, h, qtile of 32).
// ---------------------------------------------------------------------------
__global__ __launch_bounds__(256) void global_attn_kernel(
    const unsigned short* __restrict__ GQKV, unsigned short* __restrict__ GOUT)
{
    const int blk = blockIdx.x;       // b*32 + h*4 + qt
    const int qt = blk & 3, h = (blk >> 2) & 7, b = blk >> 5;
    __shared__ unsigned short ks[128 * 64], vs[128 * 64];
    __shared__ float qs[32 * 64];
    __shared__ float sc[32 * 128];
    const int tid = threadIdx.x;
    for (int idx = tid; idx < 128 * 64; idx += 256) {
        int j = idx >> 6, d = idx & 63;
        const unsigned short* rowp = GQKV + (size_t)(b * 128 + j) * 1536 + h * 64 + d;
        ks[idx] = rowp[512];
        vs[idx] = rowp[1024];
    }
    for (int idx = tid; idx < 32 * 64; idx += 256) {
        int i = idx >> 6, d = idx & 63;
        qs[idx] = b2f(GQKV[(size_t)(b * 128 + qt * 32 + i) * 1536 + h * 64 + d]);
    }
    __syncthreads();
    for (int idx = tid; idx < 32 * 128; idx += 256) {
        int i = idx >> 7, j = idx & 127;
        float s = 0.f;
        #pragma unroll
        for (int d = 0; d < 64; d++) s += qs[i * 64 + d] * b2f(ks[j * 64 + d]);
        sc[idx] = s * 0.125f;
    }
    __syncthreads();
    if (tid < 32) {
        float mx = -1e30f;
        for (int j = 0; j < 128; j++) mx = fmaxf(mx, sc[tid * 128 + j]);
        float sum = 0.f;
        for (int j = 0; j < 128; j++) { float e = expf(sc[tid * 128 + j] - mx); sc[tid * 128 + j] = e; sum += e; }
        float inv = 1.0f / sum;
        for (int j = 0; j < 128; j++) sc[tid * 128 + j] *= inv;
    }
    __syncthreads();
    for (int idx = tid; idx < 32 * 64; idx += 256) {
        int i = idx >> 6, d = idx & 63;
        float o = 0.f;
        for (int j = 0; j < 128; j++) o += sc[i * 128 + j] * b2f(vs[j * 64 + d]);
        GOUT[(size_t)(b * 128 + qt * 32 + i) * 512 + h * 64 + d] = f2b(o);
    }
}

// ---------------------------------------------------------------------------
// TMP = XG + lin_interp(GA from 128 -> 4096)
// ---------------------------------------------------------------------------
__global__ __launch_bounds__(256) void interp_add_kernel(
    const float* __restrict__ GA, const float* __restrict__ XG, float* __restrict__ TMP)
{
    int i = blockIdx.x * 256 + threadIdx.x;   // B*S*D = 2^23
    if (i < 8388608) {
        int d = i & 511, s = (i >> 9) & 4095, b = i >> 21;
        float pos = (s + 0.5f) * (128.0f / 4096.0f) - 0.5f;
        pos = fminf(fmaxf(pos, 0.0f), 127.0f);
        int i0 = (int)floorf(pos);
        int i1 = min(i0 + 1, 127);
        float w = pos - (float)i0;
        float a = GA[((size_t)b * 128 + i0) * 512 + d] * (1.0f - w)
                + GA[((size_t)b * 128 + i1) * 512 + d] * w;
        TMP[i] = XG[i] + a;
    }
}

// ---------------------------------------------------------------------------
// Y = X + dwconv(X) (K=7, zero pad). Writes f32 + bf16.
// ---------------------------------------------------------------------------
__global__ __launch_bounds__(256) void dwconv_add_kernel(
    const float* __restrict__ X, const float* __restrict__ wconv, const float* __restrict__ bconv,
    float* __restrict__ Yf, unsigned short* __restrict__ Yb)
{
    int i = blockIdx.x * 256 + threadIdx.x;
    if (i < 8388608) {
        int d = i & 511, s = (i >> 9) & 4095, b = i >> 21;
        float acc = bconv[d];
        #pragma unroll
        for (int t = 0; t < 7; t++) {
            int ss = s + t - 3;
            if (ss >= 0 && ss < 4096)
                acc += X[((size_t)b * 4096 + ss) * 512 + d] * wconv[d * 7 + t];
        }
        float v = X[i] + acc;
        Yf[i] = v;
        Yb[i] = f2b(v);
    }
}

// ---------------------------------------------------------------------------
// out = LN(w0*XL + w1*XG) with softmaxed scalar weights
// ---------------------------------------------------------------------------
__global__ __launch_bounds__(256) void final_kernel(
    const float* __restrict__ XL, const float* __restrict__ XG,
    const float* __restrict__ fwl, const float* __restrict__ fwg,
    const float* __restrict__ g, const float* __restrict__ bb, float* __restrict__ out)
{
    const int row = blockIdx.x, tid = threadIdx.x;
    float a = fwl[0], c = fwg[0];
    float m = fmaxf(a, c);
    float ea = expf(a - m), ec = expf(c - m);
    float w0 = ea / (ea + ec), w1 = ec / (ea + ec);
    const float* xlr = XL + (size_t)row * 512;
    const float* xgr = XG + (size_t)row * 512;
    float v0 = w0 * xlr[tid] + w1 * xgr[tid];
    float v1 = w0 * xlr[tid + 256] + w1 * xgr[tid + 256];
    float s = v0 + v1;
    #pragma unroll
    for (int o = 32; o > 0; o >>= 1) s += __shfl_down(s, o);
    __shared__ float red[4];
    __shared__ float stat[2];
    if ((tid & 63) == 0) red[tid >> 6] = s;
    __syncthreads();
    if (tid == 0) stat[0] = (red[0] + red[1] + red[2] + red[3]) * (1.0f / 512.0f);
    __syncthreads();
    float mu = stat[0];
    float d0 = v0 - mu, d1 = v1 - mu;
    float s2 = d0 * d0 + d1 * d1;
    #pragma unroll
    for (int o = 32; o > 0; o >>= 1) s2 += __shfl_down(s2, o);
    if ((tid & 63) == 0) red[tid >> 6] = s2;
    __syncthreads();
    if (tid == 0) stat[1] = rsqrtf((red[0] + red[1] + red[2] + red[3]) * (1.0f / 512.0f) + 1e-5f);
    __syncthreads();
    float rs = stat[1];
    float* orow = out + (size_t)row * 512;
    orow[tid]       = d0 * rs * g[tid] + bb[tid];
    orow[tid + 256] = d1 * rs * g[tid + 256] + bb[tid + 256];
}

// ---------------------------------------------------------------------------
extern "C" void kernel_launch(void* const* d_in, const int* in_sizes, int n_in,
                              void* d_out, int out_size, void* d_ws, size_t ws_size,
                              hipStream_t stream)
{
    (void)in_sizes; (void)n_in; (void)out_size; (void)ws_size;
    const float* x       = (const float*)d_in[0];
    const float* lqkv_w  = (const float*)d_in[1];
    const float* lqkv_b  = (const float*)d_in[2];
    const float* lproj_w = (const float*)d_in[3];
    const float* lproj_b = (const float*)d_in[4];
    const float* lrel    = (const float*)d_in[5];
    const float* lconv_w = (const float*)d_in[6];
    const float* lconv_b = (const float*)d_in[7];
    const float* ln1_g   = (const float*)d_in[8];
    const float* ln1_b   = (const float*)d_in[9];
    const float* lffn_w1 = (const float*)d_in[10];
    const float* lffn_b1 = (const float*)d_in[11];
    const float* lffn_w2 = (const float*)d_in[12];
    const float* lffn_b2 = (const float*)d_in[13];
    const float* ln2_g   = (const float*)d_in[14];
    const float* ln2_b   = (const float*)d_in[15];
    const float* gqkv_w  = (const float*)d_in[16];
    const float* gqkv_b  = (const float*)d_in[17];
    const float* gproj_w = (const float*)d_in[18];
    const float* gproj_b = (const float*)d_in[19];
    const float* gn1_g   = (const float*)d_in[20];
    const float* gn1_b   = (const float*)d_in[21];
    const float* gffn_w1 = (const float*)d_in[22];
    const float* gffn_b1 = (const float*)d_in[23];
    const float* gffn_w2 = (const float*)d_in[24];
    const float* gffn_b2 = (const float*)d_in[25];
    const float* gn2_g   = (const float*)d_in[26];
    const float* gn2_b   = (const float*)d_in[27];
    const float* fw_local  = (const float*)d_in[28];
    const float* fw_global = (const float*)d_in[29];
    const float* fn_g    = (const float*)d_in[30];
    const float* fn_b    = (const float*)d_in[31];
    float* out = (float*)d_out;

    const int Btot = 4 * 4096;     // 16384 token rows
    const int nel = Btot * 512;    // 8388608

    char* wsb = (char*)d_ws;
    size_t off = 0;
    auto alloc = [&](size_t bytes) -> void* {
        void* p = wsb + off;
        off = (off + bytes + 255) & ~(size_t)255;
        return p;
    };
    float*          XL   = (float*)alloc((size_t)nel * 4);
    float*          XG   = (float*)alloc((size_t)nel * 4);
    float*          TMP  = (float*)alloc((size_t)nel * 4);
    unsigned short* XBl  = (unsigned short*)alloc((size_t)nel * 2);
    unsigned short* XBg  = (unsigned short*)alloc((size_t)nel * 2);
    unsigned short* AOUT = (unsigned short*)alloc((size_t)nel * 2);
    unsigned short* BIG  = (unsigned short*)alloc((size_t)Btot * 2048 * 2); // QKV (Mx1536) or FFN hidden (Mx2048)
    unsigned short* WT   = (unsigned short*)alloc((size_t)22020096 * 2);
    unsigned short* XSB  = (unsigned short*)alloc((size_t)512 * 512 * 2);
    unsigned short* GQKV = (unsigned short*)alloc((size_t)512 * 1536 * 2);
    unsigned short* GOUT = (unsigned short*)alloc((size_t)512 * 512 * 2);
    float*          GA   = (float*)alloc((size_t)512 * 512 * 4);

    const size_t perL = 3145728;   // bf16 elems of transposed weights per layer
    auto transpose = [&](const float* W_, unsigned short* WT_, int Kd, int Nd) {
        dim3 g(Nd / 32, Kd / 32);
        transpose_cast_kernel<<<g, dim3(256), 0, stream>>>(W_, WT_, Kd, Nd);
    };
    for (int i = 0; i < 4; i++) {
        unsigned short* base = WT + (size_t)i * perL;
        transpose(lqkv_w  + (size_t)i * 512 * 1536, base,                         512, 1536);
        transpose(lproj_w + (size_t)i * 512 * 512,  base + 786432,                512, 512);
        transpose(lffn_w1 + (size_t)i * 512 * 2048, base + 786432 + 262144,       512, 2048);
        transpose(lffn_w2 + (size_t)i * 2048 * 512, base + 786432 + 262144 + 1048576, 2048, 512);
    }
    for (int i = 0; i < 3; i++) {
        unsigned short* base = WT + (size_t)(4 + i) * perL;
        transpose(gqkv_w  + (size_t)i * 512 * 1536, base,                         512, 1536);
        transpose(gproj_w + (size_t)i * 512 * 512,  base + 786432,                512, 512);
        transpose(gffn_w1 + (size_t)i * 512 * 2048, base + 786432 + 262144,       512, 2048);
        transpose(gffn_w2 + (size_t)i * 2048 * 512, base + 786432 + 262144 + 1048576, 2048, 512);
    }

    copy_cast_kernel<<<dim3(nel / 256), dim3(256), 0, stream>>>(x, XL, XG, XBl, nel);

    auto gemm = [&](const unsigned short* A_, const unsigned short* BT_, const float* bias_,
                    const float* res_, float* Cf_, unsigned short* Cb_,
                    int M_, int N_, int K_, int act_) {
        dim3 g(M_ / 64, N_ / 64);
        gemm_kernel<<<g, dim3(256), 0, stream>>>(A_, BT_, bias_, res_, Cf_, Cb_, M_, N_, K_, act_);
    };

    // ---------------- local branch: 4 layers ----------------
    for (int i = 0; i < 4; i++) {
        unsigned short* base  = WT + (size_t)i * perL;
        unsigned short* qkvT  = base;
        unsigned short* projT = base + 786432;
        unsigned short* w1T   = base + 786432 + 262144;
        unsigned short* w2T   = base + 786432 + 262144 + 1048576;

        gemm(XBl, qkvT, lqkv_b + i * 1536, nullptr, nullptr, BIG, Btot, 1536, 512, 0);
        local_attn_kernel<<<dim3(4096), dim3(256), 0, stream>>>(BIG, lrel + (size_t)i * 63 * 8, AOUT);
        gemm(AOUT, projT, lproj_b + i * 512, XL, TMP, nullptr, Btot, 512, 512, 0);
        ln_kernel<<<dim3(Btot), dim3(256), 0, stream>>>(TMP, ln1_g + i * 512, ln1_b + i * 512, XL, (unsigned short*)nullptr);
        dwconv_add_kernel<<<dim3(nel / 256), dim3(256), 0, stream>>>(XL, lconv_w + (size_t)i * 512 * 7, lconv_b + i * 512, TMP, XBl);
        gemm(XBl, w1T, lffn_b1 + i * 2048, nullptr, nullptr, BIG, Btot, 2048, 512, 1);
        gemm(BIG, w2T, lffn_b2 + i * 512, TMP, TMP, nullptr, Btot, 512, 2048, 0);
        ln_kernel<<<dim3(Btot), dim3(256), 0, stream>>>(TMP, ln2_g + i * 512, ln2_b + i * 512, XL, XBl);
    }

    // ---------------- global branch: 3 layers ----------------
    for (int i = 0; i < 3; i++) {
        unsigned short* base  = WT + (size_t)(4 + i) * perL;
        unsigned short* qkvT  = base;
        unsigned short* projT = base + 786432;
        unsigned short* w1T   = base + 786432 + 262144;
        unsigned short* w2T   = base + 786432 + 262144 + 1048576;

        gather_xs_kernel<<<dim3(1024), dim3(256), 0, stream>>>(XG, XSB);
        gemm(XSB, qkvT, gqkv_b + i * 1536, nullptr, nullptr, GQKV, 512, 1536, 512, 0);
        global_attn_kernel<<<dim3(128), dim3(256), 0, stream>>>(GQKV, GOUT);
        gemm(GOUT, projT, gproj_b + i * 512, nullptr, GA, nullptr, 512, 512, 512, 0);
        interp_add_kernel<<<dim3(nel / 256), dim3(256), 0, stream>>>(GA, XG, TMP);
        ln_kernel<<<dim3(Btot), dim3(256), 0, stream>>>(TMP, gn1_g + i * 512, gn1_b + i * 512, XG, XBg);
        gemm(XBg, w1T, gffn_b1 + i * 2048, nullptr, nullptr, BIG, Btot, 2048, 512, 1);
        gemm(BIG, w2T, gffn_b2 + i * 512, XG, TMP, nullptr, Btot, 512, 2048, 0);
        ln_kernel<<<dim3(Btot), dim3(256), 0, stream>>>(TMP, gn2_g + i * 512, gn2_b + i * 512, XG, XBg);
    }

    final_kernel<<<dim3(Btot), dim3(256), 0, stream>>>(XL, XG, fw_local, fw_global, fn_g, fn_b, out);
}

// Round 2
// 2760.850 us; speedup vs baseline: 1.0068x; 1.0068x over previous
//
#include <hip/hip_runtime.h>
#include <math.h>

typedef __attribute__((ext_vector_type(8))) short short8;
typedef __attribute__((ext_vector_type(4))) float float4_t;

#define DEV static __device__ __forceinline__

DEV unsigned short f2b(float f) {
    union { float f; unsigned int u; } x; x.f = f;
    unsigned int r = x.u + 0x7fffu + ((x.u >> 16) & 1u);
    return (unsigned short)(r >> 16);
}
DEV float b2f(unsigned short u) {
    union { unsigned int u; float f; } x; x.u = ((unsigned int)u) << 16;
    return x.f;
}
DEV float gelu_f(float x) {
    float x3 = x * x * x;
    return 0.5f * x * (1.0f + tanhf(0.7978845608028654f * (x + 0.044715f * x3)));
}

// async 16B global -> LDS (DMA, no VGPR round-trip). LDS dest must be
// wave-uniform base + lane*16 (m104/m108) — our layouts guarantee that.
DEV void gld16(unsigned short* lds, const unsigned short* g) {
    __builtin_amdgcn_global_load_lds(
        (const __attribute__((address_space(1))) unsigned int*)g,
        (__attribute__((address_space(3))) unsigned int*)lds,
        16, 0, 0);
}

// ---------------------------------------------------------------------------
// Tiled transpose + cast: W (K x N, f32) -> WT (N x K, bf16)
// ---------------------------------------------------------------------------
__global__ __launch_bounds__(256) void transpose_cast_kernel(
    const float* __restrict__ W, unsigned short* __restrict__ WT, int Kd, int Nd)
{
    __shared__ float tile[32][33];
    int n0 = blockIdx.x * 32, k0 = blockIdx.y * 32;
    int tx = threadIdx.x & 31, ty = threadIdx.x >> 5;   // 32 x 8
    #pragma unroll
    for (int r = ty; r < 32; r += 8)
        tile[r][tx] = W[(size_t)(k0 + r) * Nd + n0 + tx];
    __syncthreads();
    #pragma unroll
    for (int r = ty; r < 32; r += 8)
        WT[(size_t)(n0 + r) * Kd + k0 + tx] = f2b(tile[tx][r]);
}

// ---------------------------------------------------------------------------
// copy x -> XL (f32), XG (f32), XB (bf16)
// ---------------------------------------------------------------------------
__global__ __launch_bounds__(256) void copy_cast_kernel(
    const float* __restrict__ x, float* __restrict__ xl, float* __restrict__ xg,
    unsigned short* __restrict__ xb, int n)
{
    int i = blockIdx.x * 256 + threadIdx.x;
    if (i < n) { float v = x[i]; xl[i] = v; xg[i] = v; xb[i] = f2b(v); }
}

// ---------------------------------------------------------------------------
// bf16 MFMA GEMM, m97 structure: 128x128 block tile, 4 waves (2x2), 64x64
// per wave as 4x4 16x16x32 frags, BK=32, global_load_lds width-16 staging.
// A: M x K bf16 row-major.  BT: N x K bf16 row-major (B transposed).
// C = A@B + bias [, GELU][, +residual] -> f32 and/or bf16.
// ---------------------------------------------------------------------------
__global__ __launch_bounds__(256) void gemm_kernel(
    const unsigned short* __restrict__ A,
    const unsigned short* __restrict__ BT,
    const float* __restrict__ bias,
    const float* __restrict__ residual,
    float* __restrict__ Cf,
    unsigned short* __restrict__ Cb,
    int M, int N, int K, int act)
{
    __shared__ __align__(16) unsigned short As[128 * 32];
    __shared__ __align__(16) unsigned short Bs[128 * 32];
    const int tid = threadIdx.x;
    const int wave = tid >> 6, lane = tid & 63;
    const int quad = lane >> 4, l16 = lane & 15;
    const int m0 = blockIdx.x * 128, n0 = blockIdx.y * 128;
    const int wm = (wave >> 1) * 64, wn = (wave & 1) * 64;

    float4_t acc[4][4] = {};

    // Staging: tile is 128 rows x 32 cols bf16 (row stride 64 B).
    // One wave-instruction covers 16 rows (64 lanes x 16 B = 1024 B).
    // Round p in {0,1}: wave w stages rows [p*64 + w*16, +16).
    const int lrow = lane >> 2;           // 0..15
    const int lcol = (lane & 3) * 8;      // 0,8,16,24 (bf16 elems)
    const int r0 = wave * 16 + lrow;      // p=0 row
    const unsigned short* Ag0 = A  + (size_t)(m0 + r0) * K + lcol;
    const unsigned short* Ag1 = A  + (size_t)(m0 + 64 + r0) * K + lcol;
    const unsigned short* Bg0 = BT + (size_t)(n0 + r0) * K + lcol;
    const unsigned short* Bg1 = BT + (size_t)(n0 + 64 + r0) * K + lcol;
    unsigned short* AsW0 = As + (wave * 16) * 32 + lane * 8;
    unsigned short* AsW1 = As + (64 + wave * 16) * 32 + lane * 8;
    unsigned short* BsW0 = Bs + (wave * 16) * 32 + lane * 8;
    unsigned short* BsW1 = Bs + (64 + wave * 16) * 32 + lane * 8;

    for (int k0 = 0; k0 < K; k0 += 32) {
        gld16(AsW0, Ag0 + k0);
        gld16(AsW1, Ag1 + k0);
        gld16(BsW0, Bg0 + k0);
        gld16(BsW1, Bg1 + k0);
        __syncthreads();   // drains vmcnt -> LDS tile complete

        short8 a[4], b[4];
        #pragma unroll
        for (int i = 0; i < 4; i++)
            a[i] = *(const short8*)(As + (wm + i * 16 + l16) * 32 + quad * 8);
        #pragma unroll
        for (int j = 0; j < 4; j++)
            b[j] = *(const short8*)(Bs + (wn + j * 16 + l16) * 32 + quad * 8);
        #pragma unroll
        for (int i = 0; i < 4; i++)
            #pragma unroll
            for (int j = 0; j < 4; j++)
                acc[i][j] = __builtin_amdgcn_mfma_f32_16x16x32_bf16(a[i], b[j], acc[i][j], 0, 0, 0);
        __syncthreads();
    }

    #pragma unroll
    for (int i = 0; i < 4; i++) {
        #pragma unroll
        for (int j = 0; j < 4; j++) {
            int col = n0 + wn + j * 16 + l16;
            float bv = bias[col];
            #pragma unroll
            for (int r = 0; r < 4; r++) {
                int row = m0 + wm + i * 16 + quad * 4 + r;
                float v = acc[i][j][r] + bv;
                if (act == 1) v = gelu_f(v);
                size_t idx = (size_t)row * N + col;
                if (residual) v += residual[idx];
                if (Cf) Cf[idx] = v;
                if (Cb) Cb[idx] = f2b(v);
            }
        }
    }
}

// ---------------------------------------------------------------------------
// LayerNorm over D=512. One block (256 thr) per row. Optional f32/bf16 outs.
// ---------------------------------------------------------------------------
__global__ __launch_bounds__(256) void ln_kernel(
    const float* __restrict__ X, const float* __restrict__ g, const float* __restrict__ b,
    float* __restrict__ Yf, unsigned short* __restrict__ Yb)
{
    const int row = blockIdx.x, tid = threadIdx.x;
    const float* xr = X + (size_t)row * 512;
    float v0 = xr[tid], v1 = xr[tid + 256];
    float s = v0 + v1;
    #pragma unroll
    for (int o = 32; o > 0; o >>= 1) s += __shfl_down(s, o);
    __shared__ float red[4];
    __shared__ float stat[2];
    if ((tid & 63) == 0) red[tid >> 6] = s;
    __syncthreads();
    if (tid == 0) stat[0] = (red[0] + red[1] + red[2] + red[3]) * (1.0f / 512.0f);
    __syncthreads();
    float mu = stat[0];
    float d0 = v0 - mu, d1 = v1 - mu;
    float s2 = d0 * d0 + d1 * d1;
    #pragma unroll
    for (int o = 32; o > 0; o >>= 1) s2 += __shfl_down(s2, o);
    if ((tid & 63) == 0) red[tid >> 6] = s2;
    __syncthreads();
    if (tid == 0) stat[1] = rsqrtf((red[0] + red[1] + red[2] + red[3]) * (1.0f / 512.0f) + 1e-5f);
    __syncthreads();
    float rs = stat[1];
    float y0 = d0 * rs * g[tid] + b[tid];
    float y1 = d1 * rs * g[tid + 256] + b[tid + 256];
    if (Yf) { float* yr = Yf + (size_t)row * 512; yr[tid] = y0; yr[tid + 256] = y1; }
    if (Yb) { unsigned short* yb = Yb + (size_t)row * 512; yb[tid] = f2b(y0); yb[tid + 256] = f2b(y1); }
}

// ---------------------------------------------------------------------------
// Local windowed attention. One block per (b, window, head). W=32, HD=64.
// ---------------------------------------------------------------------------
__global__ __launch_bounds__(256) void local_attn_kernel(
    const unsigned short* __restrict__ QKV, const float* __restrict__ rel,
    unsigned short* __restrict__ OUT)
{
    const int blk = blockIdx.x;          // (b*128 + win)*8 + h
    const int h = blk & 7;
    const int win = (blk >> 3) & 127;
    const int b = blk >> 10;
    const int rowbase = b * 4096 + win * 32;
    __shared__ float q[32][64], k[32][64], v[32][64];
    __shared__ float sc[32][33];
    const int tid = threadIdx.x;
    for (int idx = tid; idx < 2048; idx += 256) {
        int i = idx >> 6, d = idx & 63;
        const unsigned short* base = QKV + (size_t)(rowbase + i) * 1536 + h * 64 + d;
        q[i][d] = b2f(base[0]);
        k[i][d] = b2f(base[512]);
        v[i][d] = b2f(base[1024]);
    }
    __syncthreads();
    for (int idx = tid; idx < 1024; idx += 256) {
        int i = idx >> 5, j = idx & 31;
        float s = 0.f;
        #pragma unroll
        for (int d = 0; d < 64; d++) s += q[i][d] * k[j][d];
        sc[i][j] = s * 0.125f + rel[(i - j + 31) * 8 + h];
    }
    __syncthreads();
    if (tid < 32) {
        float mx = -1e30f;
        for (int j = 0; j < 32; j++) mx = fmaxf(mx, sc[tid][j]);
        float sum = 0.f;
        for (int j = 0; j < 32; j++) { float e = expf(sc[tid][j] - mx); sc[tid][j] = e; sum += e; }
        float inv = 1.0f / sum;
        for (int j = 0; j < 32; j++) sc[tid][j] *= inv;
    }
    __syncthreads();
    for (int idx = tid; idx < 2048; idx += 256) {
        int i = idx >> 6, d = idx & 63;
        float o = 0.f;
        #pragma unroll
        for (int j = 0; j < 32; j++) o += sc[i][j] * v[j][d];
        OUT[(size_t)(rowbase + i) * 512 + h * 64 + d] = f2b(o);
    }
}

// ---------------------------------------------------------------------------
// Gather strided tokens for global attention: XS[b,t,d] = bf16(XG[b, t*32, d])
// ---------------------------------------------------------------------------
__global__ __launch_bounds__(256) void gather_xs_kernel(
    const float* __restrict__ XG, unsigned short* __restrict__ XSB)
{
    int i = blockIdx.x * 256 + threadIdx.x;   // 4*128*512 = 262144
    if (i < 262144) {
        int d = i & 511, t = (i >> 9) & 127, b = i >> 16;
        XSB[i] = f2b(XG[((size_t)b * 4096 + t * 32) * 512 + d]);
    }
}

// ---------------------------------------------------------------------------
// Global attention on 128 tokens/batch. Block per (b, h, qtile of 32).
// ---------------------------------------------------------------------------
__global__ __launch_bounds__(256) void global_attn_kernel(
    const unsigned short* __restrict__ GQKV, unsigned short* __restrict__ GOUT)
{
    const int blk = blockIdx.x;       // b*32 + h*4 + qt
    const int qt = blk & 3, h = (blk >> 2) & 7, b = blk >> 5;
    __shared__ unsigned short ks[128 * 64], vs[128 * 64];
    __shared__ float qs[32 * 64];
    __shared__ float sc[32 * 128];
    const int tid = threadIdx.x;
    for (int idx = tid; idx < 128 * 64; idx += 256) {
        int j = idx >> 6, d = idx & 63;
        const unsigned short* rowp = GQKV + (size_t)(b * 128 + j) * 1536 + h * 64 + d;
        ks[idx] = rowp[512];
        vs[idx] = rowp[1024];
    }
    for (int idx = tid; idx < 32 * 64; idx += 256) {
        int i = idx >> 6, d = idx & 63;
        qs[idx] = b2f(GQKV[(size_t)(b * 128 + qt * 32 + i) * 1536 + h * 64 + d]);
    }
    __syncthreads();
    for (int idx = tid; idx < 32 * 128; idx += 256) {
        int i = idx >> 7, j = idx & 127;
        float s = 0.f;
        #pragma unroll
        for (int d = 0; d < 64; d++) s += qs[i * 64 + d] * b2f(ks[j * 64 + d]);
        sc[idx] = s * 0.125f;
    }
    __syncthreads();
    if (tid < 32) {
        float mx = -1e30f;
        for (int j = 0; j < 128; j++) mx = fmaxf(mx, sc[tid * 128 + j]);
        float sum = 0.f;
        for (int j = 0; j < 128; j++) { float e = expf(sc[tid * 128 + j] - mx); sc[tid * 128 + j] = e; sum += e; }
        float inv = 1.0f / sum;
        for (int j = 0; j < 128; j++) sc[tid * 128 + j] *= inv;
    }
    __syncthreads();
    for (int idx = tid; idx < 32 * 64; idx += 256) {
        int i = idx >> 6, d = idx & 63;
        float o = 0.f;
        for (int j = 0; j < 128; j++) o += sc[i * 128 + j] * b2f(vs[j * 64 + d]);
        GOUT[(size_t)(b * 128 + qt * 32 + i) * 512 + h * 64 + d] = f2b(o);
    }
}

// ---------------------------------------------------------------------------
// TMP = XG + lin_interp(GA from 128 -> 4096)
// ---------------------------------------------------------------------------
__global__ __launch_bounds__(256) void interp_add_kernel(
    const float* __restrict__ GA, const float* __restrict__ XG, float* __restrict__ TMP)
{
    int i = blockIdx.x * 256 + threadIdx.x;   // B*S*D = 2^23
    if (i < 8388608) {
        int d = i & 511, s = (i >> 9) & 4095, b = i >> 21;
        float pos = (s + 0.5f) * (128.0f / 4096.0f) - 0.5f;
        pos = fminf(fmaxf(pos, 0.0f), 127.0f);
        int i0 = (int)floorf(pos);
        int i1 = min(i0 + 1, 127);
        float w = pos - (float)i0;
        float a = GA[((size_t)b * 128 + i0) * 512 + d] * (1.0f - w)
                + GA[((size_t)b * 128 + i1) * 512 + d] * w;
        TMP[i] = XG[i] + a;
    }
}

// ---------------------------------------------------------------------------
// Y = X + dwconv(X) (K=7, zero pad). Writes f32 + bf16.
// ---------------------------------------------------------------------------
__global__ __launch_bounds__(256) void dwconv_add_kernel(
    const float* __restrict__ X, const float* __restrict__ wconv, const float* __restrict__ bconv,
    float* __restrict__ Yf, unsigned short* __restrict__ Yb)
{
    int i = blockIdx.x * 256 + threadIdx.x;
    if (i < 8388608) {
        int d = i & 511, s = (i >> 9) & 4095, b = i >> 21;
        float acc = bconv[d];
        #pragma unroll
        for (int t = 0; t < 7; t++) {
            int ss = s + t - 3;
            if (ss >= 0 && ss < 4096)
                acc += X[((size_t)b * 4096 + ss) * 512 + d] * wconv[d * 7 + t];
        }
        float v = X[i] + acc;
        Yf[i] = v;
        Yb[i] = f2b(v);
    }
}

// ---------------------------------------------------------------------------
// out = LN(w0*XL + w1*XG) with softmaxed scalar weights
// ---------------------------------------------------------------------------
__global__ __launch_bounds__(256) void final_kernel(
    const float* __restrict__ XL, const float* __restrict__ XG,
    const float* __restrict__ fwl, const float* __restrict__ fwg,
    const float* __restrict__ g, const float* __restrict__ bb, float* __restrict__ out)
{
    const int row = blockIdx.x, tid = threadIdx.x;
    float a = fwl[0], c = fwg[0];
    float m = fmaxf(a, c);
    float ea = expf(a - m), ec = expf(c - m);
    float w0 = ea / (ea + ec), w1 = ec / (ea + ec);
    const float* xlr = XL + (size_t)row * 512;
    const float* xgr = XG + (size_t)row * 512;
    float v0 = w0 * xlr[tid] + w1 * xgr[tid];
    float v1 = w0 * xlr[tid + 256] + w1 * xgr[tid + 256];
    float s = v0 + v1;
    #pragma unroll
    for (int o = 32; o > 0; o >>= 1) s += __shfl_down(s, o);
    __shared__ float red[4];
    __shared__ float stat[2];
    if ((tid & 63) == 0) red[tid >> 6] = s;
    __syncthreads();
    if (tid == 0) stat[0] = (red[0] + red[1] + red[2] + red[3]) * (1.0f / 512.0f);
    __syncthreads();
    float mu = stat[0];
    float d0 = v0 - mu, d1 = v1 - mu;
    float s2 = d0 * d0 + d1 * d1;
    #pragma unroll
    for (int o = 32; o > 0; o >>= 1) s2 += __shfl_down(s2, o);
    if ((tid & 63) == 0) red[tid >> 6] = s2;
    __syncthreads();
    if (tid == 0) stat[1] = rsqrtf((red[0] + red[1] + red[2] + red[3]) * (1.0f / 512.0f) + 1e-5f);
    __syncthreads();
    float rs = stat[1];
    float* orow = out + (size_t)row * 512;
    orow[tid]       = d0 * rs * g[tid] + bb[tid];
    orow[tid + 256] = d1 * rs * g[tid + 256] + bb[tid + 256];
}

// ---------------------------------------------------------------------------
extern "C" void kernel_launch(void* const* d_in, const int* in_sizes, int n_in,
                              void* d_out, int out_size, void* d_ws, size_t ws_size,
                              hipStream_t stream)
{
    (void)in_sizes; (void)n_in; (void)out_size; (void)ws_size;
    const float* x       = (const float*)d_in[0];
    const float* lqkv_w  = (const float*)d_in[1];
    const float* lqkv_b  = (const float*)d_in[2];
    const float* lproj_w = (const float*)d_in[3];
    const float* lproj_b = (const float*)d_in[4];
    const float* lrel    = (const float*)d_in[5];
    const float* lconv_w = (const float*)d_in[6];
    const float* lconv_b = (const float*)d_in[7];
    const float* ln1_g   = (const float*)d_in[8];
    const float* ln1_b   = (const float*)d_in[9];
    const float* lffn_w1 = (const float*)d_in[10];
    const float* lffn_b1 = (const float*)d_in[11];
    const float* lffn_w2 = (const float*)d_in[12];
    const float* lffn_b2 = (const float*)d_in[13];
    const float* ln2_g   = (const float*)d_in[14];
    const float* ln2_b   = (const float*)d_in[15];
    const float* gqkv_w  = (const float*)d_in[16];
    const float* gqkv_b  = (const float*)d_in[17];
    const float* gproj_w = (const float*)d_in[18];
    const float* gproj_b = (const float*)d_in[19];
    const float* gn1_g   = (const float*)d_in[20];
    const float* gn1_b   = (const float*)d_in[21];
    const float* gffn_w1 = (const float*)d_in[22];
    const float* gffn_b1 = (const float*)d_in[23];
    const float* gffn_w2 = (const float*)d_in[24];
    const float* gffn_b2 = (const float*)d_in[25];
    const float* gn2_g   = (const float*)d_in[26];
    const float* gn2_b   = (const float*)d_in[27];
    const float* fw_local  = (const float*)d_in[28];
    const float* fw_global = (const float*)d_in[29];
    const float* fn_g    = (const float*)d_in[30];
    const float* fn_b    = (const float*)d_in[31];
    float* out = (float*)d_out;

    const int Btot = 4 * 4096;     // 16384 token rows
    const int nel = Btot * 512;    // 8388608

    char* wsb = (char*)d_ws;
    size_t off = 0;
    auto alloc = [&](size_t bytes) -> void* {
        void* p = wsb + off;
        off = (off + bytes + 255) & ~(size_t)255;
        return p;
    };
    float*          XL   = (float*)alloc((size_t)nel * 4);
    float*          XG   = (float*)alloc((size_t)nel * 4);
    float*          TMP  = (float*)alloc((size_t)nel * 4);
    unsigned short* XBl  = (unsigned short*)alloc((size_t)nel * 2);
    unsigned short* XBg  = (unsigned short*)alloc((size_t)nel * 2);
    unsigned short* AOUT = (unsigned short*)alloc((size_t)nel * 2);
    unsigned short* BIG  = (unsigned short*)alloc((size_t)Btot * 2048 * 2);
    unsigned short* WT   = (unsigned short*)alloc((size_t)22020096 * 2);
    unsigned short* XSB  = (unsigned short*)alloc((size_t)512 * 512 * 2);
    unsigned short* GQKV = (unsigned short*)alloc((size_t)512 * 1536 * 2);
    unsigned short* GOUT = (unsigned short*)alloc((size_t)512 * 512 * 2);
    float*          GA   = (float*)alloc((size_t)512 * 512 * 4);

    const size_t perL = 3145728;   // bf16 elems of transposed weights per layer
    auto transpose = [&](const float* W_, unsigned short* WT_, int Kd, int Nd) {
        dim3 g(Nd / 32, Kd / 32);
        transpose_cast_kernel<<<g, dim3(256), 0, stream>>>(W_, WT_, Kd, Nd);
    };
    for (int i = 0; i < 4; i++) {
        unsigned short* base = WT + (size_t)i * perL;
        transpose(lqkv_w  + (size_t)i * 512 * 1536, base,                         512, 1536);
        transpose(lproj_w + (size_t)i * 512 * 512,  base + 786432,                512, 512);
        transpose(lffn_w1 + (size_t)i * 512 * 2048, base + 786432 + 262144,       512, 2048);
        transpose(lffn_w2 + (size_t)i * 2048 * 512, base + 786432 + 262144 + 1048576, 2048, 512);
    }
    for (int i = 0; i < 3; i++) {
        unsigned short* base = WT + (size_t)(4 + i) * perL;
        transpose(gqkv_w  + (size_t)i * 512 * 1536, base,                         512, 1536);
        transpose(gproj_w + (size_t)i * 512 * 512,  base + 786432,                512, 512);
        transpose(gffn_w1 + (size_t)i * 512 * 2048, base + 786432 + 262144,       512, 2048);
        transpose(gffn_w2 + (size_t)i * 2048 * 512, base + 786432 + 262144 + 1048576, 2048, 512);
    }

    copy_cast_kernel<<<dim3(nel / 256), dim3(256), 0, stream>>>(x, XL, XG, XBl, nel);

    auto gemm = [&](const unsigned short* A_, const unsigned short* BT_, const float* bias_,
                    const float* res_, float* Cf_, unsigned short* Cb_,
                    int M_, int N_, int K_, int act_) {
        dim3 g(M_ / 128, N_ / 128);
        gemm_kernel<<<g, dim3(256), 0, stream>>>(A_, BT_, bias_, res_, Cf_, Cb_, M_, N_, K_, act_);
    };

    // ---------------- local branch: 4 layers ----------------
    for (int i = 0; i < 4; i++) {
        unsigned short* base  = WT + (size_t)i * perL;
        unsigned short* qkvT  = base;
        unsigned short* projT = base + 786432;
        unsigned short* w1T   = base + 786432 + 262144;
        unsigned short* w2T   = base + 786432 + 262144 + 1048576;

        gemm(XBl, qkvT, lqkv_b + i * 1536, nullptr, nullptr, BIG, Btot, 1536, 512, 0);
        local_attn_kernel<<<dim3(4096), dim3(256), 0, stream>>>(BIG, lrel + (size_t)i * 63 * 8, AOUT);
        gemm(AOUT, projT, lproj_b + i * 512, XL, TMP, nullptr, Btot, 512, 512, 0);
        ln_kernel<<<dim3(Btot), dim3(256), 0, stream>>>(TMP, ln1_g + i * 512, ln1_b + i * 512, XL, (unsigned short*)nullptr);
        dwconv_add_kernel<<<dim3(nel / 256), dim3(256), 0, stream>>>(XL, lconv_w + (size_t)i * 512 * 7, lconv_b + i * 512, TMP, XBl);
        gemm(XBl, w1T, lffn_b1 + i * 2048, nullptr, nullptr, BIG, Btot, 2048, 512, 1);
        gemm(BIG, w2T, lffn_b2 + i * 512, TMP, TMP, nullptr, Btot, 512, 2048, 0);
        ln_kernel<<<dim3(Btot), dim3(256), 0, stream>>>(TMP, ln2_g + i * 512, ln2_b + i * 512, XL, XBl);
    }

    // ---------------- global branch: 3 layers ----------------
    for (int i = 0; i < 3; i++) {
        unsigned short* base  = WT + (size_t)(4 + i) * perL;
        unsigned short* qkvT  = base;
        unsigned short* projT = base + 786432;
        unsigned short* w1T   = base + 786432 + 262144;
        unsigned short* w2T   = base + 786432 + 262144 + 1048576;

        gather_xs_kernel<<<dim3(1024), dim3(256), 0, stream>>>(XG, XSB);
        gemm(XSB, qkvT, gqkv_b + i * 1536, nullptr, nullptr, GQKV, 512, 1536, 512, 0);
        global_attn_kernel<<<dim3(128), dim3(256), 0, stream>>>(GQKV, GOUT);
        gemm(GOUT, projT, gproj_b + i * 512, nullptr, GA, nullptr, 512, 512, 512, 0);
        interp_add_kernel<<<dim3(nel / 256), dim3(256), 0, stream>>>(GA, XG, TMP);
        ln_kernel<<<dim3(Btot), dim3(256), 0, stream>>>(TMP, gn1_g + i * 512, gn1_b + i * 512, XG, XBg);
        gemm(XBg, w1T, gffn_b1 + i * 2048, nullptr, nullptr, BIG, Btot, 2048, 512, 1);
        gemm(BIG, w2T, gffn_b2 + i * 512, XG, TMP, nullptr, Btot, 512, 2048, 0);
        ln_kernel<<<dim3(Btot), dim3(256), 0, stream>>>(TMP, gn2_g + i * 512, gn2_b + i * 512, XG, XBg);
    }

    final_kernel<<<dim3(Btot), dim3(256), 0, stream>>>(XL, XG, fw_local, fw_global, fn_g, fn_b, out);
}

// Round 3
// 2575.879 us; speedup vs baseline: 1.0791x; 1.0718x over previous
//
#include <hip/hip_runtime.h>
#include <math.h>

typedef __attribute__((ext_vector_type(8))) short short8;
typedef __attribute__((ext_vector_type(4))) float float4_t;

#define DEV static __device__ __forceinline__

DEV unsigned short f2b(float f) {
    union { float f; unsigned int u; } x; x.f = f;
    unsigned int r = x.u + 0x7fffu + ((x.u >> 16) & 1u);
    return (unsigned short)(r >> 16);
}
DEV float b2f(unsigned short u) {
    union { unsigned int u; float f; } x; x.u = ((unsigned int)u) << 16;
    return x.f;
}
// gelu(x) = 0.5x(1+tanh(u)) = x * sigmoid(2u), u = 0.79788456(x + 0.044715x^3)
// tanh via __expf: ~8 VALU instr vs ~100 for library tanhf.
DEV float gelu_f(float x) {
    float u = 0.7978845608028654f * (x + 0.044715f * x * x * x);
    float e = __expf(-2.0f * u);
    return x / (1.0f + e);
}

// async 16B global -> LDS (DMA, no VGPR round-trip). LDS dest must be
// wave-uniform base + lane*16 (m104/m108) — our layouts guarantee that.
DEV void gld16(unsigned short* lds, const unsigned short* g) {
    __builtin_amdgcn_global_load_lds(
        (const __attribute__((address_space(1))) unsigned int*)g,
        (__attribute__((address_space(3))) unsigned int*)lds,
        16, 0, 0);
}

// ---------------------------------------------------------------------------
// Tiled transpose + cast: W (K x N, f32) -> WT (N x K, bf16)
// ---------------------------------------------------------------------------
__global__ __launch_bounds__(256) void transpose_cast_kernel(
    const float* __restrict__ W, unsigned short* __restrict__ WT, int Kd, int Nd)
{
    __shared__ float tile[32][33];
    int n0 = blockIdx.x * 32, k0 = blockIdx.y * 32;
    int tx = threadIdx.x & 31, ty = threadIdx.x >> 5;   // 32 x 8
    #pragma unroll
    for (int r = ty; r < 32; r += 8)
        tile[r][tx] = W[(size_t)(k0 + r) * Nd + n0 + tx];
    __syncthreads();
    #pragma unroll
    for (int r = ty; r < 32; r += 8)
        WT[(size_t)(n0 + r) * Kd + k0 + tx] = f2b(tile[tx][r]);
}

// ---------------------------------------------------------------------------
// copy x -> XL (f32), XG (f32), XB (bf16)
// ---------------------------------------------------------------------------
__global__ __launch_bounds__(256) void copy_cast_kernel(
    const float* __restrict__ x, float* __restrict__ xl, float* __restrict__ xg,
    unsigned short* __restrict__ xb, int n)
{
    int i = blockIdx.x * 256 + threadIdx.x;
    if (i < n) { float v = x[i]; xl[i] = v; xg[i] = v; xb[i] = f2b(v); }
}

// ---------------------------------------------------------------------------
// bf16 MFMA GEMM, m97 structure: 128x128 block tile, 4 waves (2x2), 64x64
// per wave as 4x4 16x16x32 frags, BK=32, global_load_lds width-16 staging.
// ---------------------------------------------------------------------------
__global__ __launch_bounds__(256) void gemm_kernel(
    const unsigned short* __restrict__ A,
    const unsigned short* __restrict__ BT,
    const float* __restrict__ bias,
    const float* __restrict__ residual,
    float* __restrict__ Cf,
    unsigned short* __restrict__ Cb,
    int M, int N, int K, int act)
{
    __shared__ __align__(16) unsigned short As[128 * 32];
    __shared__ __align__(16) unsigned short Bs[128 * 32];
    const int tid = threadIdx.x;
    const int wave = tid >> 6, lane = tid & 63;
    const int quad = lane >> 4, l16 = lane & 15;
    const int m0 = blockIdx.x * 128, n0 = blockIdx.y * 128;
    const int wm = (wave >> 1) * 64, wn = (wave & 1) * 64;

    float4_t acc[4][4] = {};

    const int lrow = lane >> 2;           // 0..15
    const int lcol = (lane & 3) * 8;      // 0,8,16,24 (bf16 elems)
    const int r0 = wave * 16 + lrow;      // p=0 row
    const unsigned short* Ag0 = A  + (size_t)(m0 + r0) * K + lcol;
    const unsigned short* Ag1 = A  + (size_t)(m0 + 64 + r0) * K + lcol;
    const unsigned short* Bg0 = BT + (size_t)(n0 + r0) * K + lcol;
    const unsigned short* Bg1 = BT + (size_t)(n0 + 64 + r0) * K + lcol;
    unsigned short* AsW0 = As + (wave * 16) * 32 + lane * 8;
    unsigned short* AsW1 = As + (64 + wave * 16) * 32 + lane * 8;
    unsigned short* BsW0 = Bs + (wave * 16) * 32 + lane * 8;
    unsigned short* BsW1 = Bs + (64 + wave * 16) * 32 + lane * 8;

    for (int k0 = 0; k0 < K; k0 += 32) {
        gld16(AsW0, Ag0 + k0);
        gld16(AsW1, Ag1 + k0);
        gld16(BsW0, Bg0 + k0);
        gld16(BsW1, Bg1 + k0);
        __syncthreads();

        short8 a[4], b[4];
        #pragma unroll
        for (int i = 0; i < 4; i++)
            a[i] = *(const short8*)(As + (wm + i * 16 + l16) * 32 + quad * 8);
        #pragma unroll
        for (int j = 0; j < 4; j++)
            b[j] = *(const short8*)(Bs + (wn + j * 16 + l16) * 32 + quad * 8);
        #pragma unroll
        for (int i = 0; i < 4; i++)
            #pragma unroll
            for (int j = 0; j < 4; j++)
                acc[i][j] = __builtin_amdgcn_mfma_f32_16x16x32_bf16(a[i], b[j], acc[i][j], 0, 0, 0);
        __syncthreads();
    }

    #pragma unroll
    for (int i = 0; i < 4; i++) {
        #pragma unroll
        for (int j = 0; j < 4; j++) {
            int col = n0 + wn + j * 16 + l16;
            float bv = bias[col];
            #pragma unroll
            for (int r = 0; r < 4; r++) {
                int row = m0 + wm + i * 16 + quad * 4 + r;
                float v = acc[i][j][r] + bv;
                if (act == 1) v = gelu_f(v);
                size_t idx = (size_t)row * N + col;
                if (residual) v += residual[idx];
                if (Cf) Cf[idx] = v;
                if (Cb) Cb[idx] = f2b(v);
            }
        }
    }
}

// ---------------------------------------------------------------------------
// LayerNorm over D=512. One block (256 thr) per row. Optional f32/bf16 outs.
// ---------------------------------------------------------------------------
__global__ __launch_bounds__(256) void ln_kernel(
    const float* __restrict__ X, const float* __restrict__ g, const float* __restrict__ b,
    float* __restrict__ Yf, unsigned short* __restrict__ Yb)
{
    const int row = blockIdx.x, tid = threadIdx.x;
    const float* xr = X + (size_t)row * 512;
    float v0 = xr[tid], v1 = xr[tid + 256];
    float s = v0 + v1;
    #pragma unroll
    for (int o = 32; o > 0; o >>= 1) s += __shfl_down(s, o);
    __shared__ float red[4];
    __shared__ float stat[2];
    if ((tid & 63) == 0) red[tid >> 6] = s;
    __syncthreads();
    if (tid == 0) stat[0] = (red[0] + red[1] + red[2] + red[3]) * (1.0f / 512.0f);
    __syncthreads();
    float mu = stat[0];
    float d0 = v0 - mu, d1 = v1 - mu;
    float s2 = d0 * d0 + d1 * d1;
    #pragma unroll
    for (int o = 32; o > 0; o >>= 1) s2 += __shfl_down(s2, o);
    if ((tid & 63) == 0) red[tid >> 6] = s2;
    __syncthreads();
    if (tid == 0) stat[1] = rsqrtf((red[0] + red[1] + red[2] + red[3]) * (1.0f / 512.0f) + 1e-5f);
    __syncthreads();
    float rs = stat[1];
    float y0 = d0 * rs * g[tid] + b[tid];
    float y1 = d1 * rs * g[tid + 256] + b[tid + 256];
    if (Yf) { float* yr = Yf + (size_t)row * 512; yr[tid] = y0; yr[tid + 256] = y1; }
    if (Yb) { unsigned short* yb = Yb + (size_t)row * 512; yb[tid] = f2b(y0); yb[tid + 256] = f2b(y1); }
}

// ---------------------------------------------------------------------------
// Fused: v = XG + lin_interp(GA 128->4096);  XG = LN(v; g,b); XBg = bf16(XG)
// One block per row. In-place safe: each block reads only its own row, and
// all reads are consumed before the first __syncthreads.
// ---------------------------------------------------------------------------
__global__ __launch_bounds__(256) void interp_ln_kernel(
    const float* __restrict__ GA, float* __restrict__ XG,
    const float* __restrict__ g, const float* __restrict__ b,
    unsigned short* __restrict__ Yb)
{
    const int row = blockIdx.x, tid = threadIdx.x;
    const int bb = row >> 12, s = row & 4095;
    float pos = (s + 0.5f) * (128.0f / 4096.0f) - 0.5f;
    pos = fminf(fmaxf(pos, 0.0f), 127.0f);
    int i0 = (int)floorf(pos);
    int i1 = min(i0 + 1, 127);
    float w = pos - (float)i0;
    const float* ga0 = GA + ((size_t)bb * 128 + i0) * 512;
    const float* ga1 = GA + ((size_t)bb * 128 + i1) * 512;
    float* xr = XG + (size_t)row * 512;
    float v0 = xr[tid]       + ga0[tid]       * (1.0f - w) + ga1[tid]       * w;
    float v1 = xr[tid + 256] + ga0[tid + 256] * (1.0f - w) + ga1[tid + 256] * w;
    float sm = v0 + v1;
    #pragma unroll
    for (int o = 32; o > 0; o >>= 1) sm += __shfl_down(sm, o);
    __shared__ float red[4];
    __shared__ float stat[2];
    if ((tid & 63) == 0) red[tid >> 6] = sm;
    __syncthreads();
    if (tid == 0) stat[0] = (red[0] + red[1] + red[2] + red[3]) * (1.0f / 512.0f);
    __syncthreads();
    float mu = stat[0];
    float d0 = v0 - mu, d1 = v1 - mu;
    float s2 = d0 * d0 + d1 * d1;
    #pragma unroll
    for (int o = 32; o > 0; o >>= 1) s2 += __shfl_down(s2, o);
    if ((tid & 63) == 0) red[tid >> 6] = s2;
    __syncthreads();
    if (tid == 0) stat[1] = rsqrtf((red[0] + red[1] + red[2] + red[3]) * (1.0f / 512.0f) + 1e-5f);
    __syncthreads();
    float rs = stat[1];
    float y0 = d0 * rs * g[tid] + b[tid];
    float y1 = d1 * rs * g[tid + 256] + b[tid + 256];
    xr[tid] = y0;           xr[tid + 256] = y1;
    unsigned short* yb = Yb + (size_t)row * 512;
    yb[tid] = f2b(y0);      yb[tid + 256] = f2b(y1);
}

// ---------------------------------------------------------------------------
// Local windowed attention. One block per (b, window, head). W=32, HD=64.
// ---------------------------------------------------------------------------
__global__ __launch_bounds__(256) void local_attn_kernel(
    const unsigned short* __restrict__ QKV, const float* __restrict__ rel,
    unsigned short* __restrict__ OUT)
{
    const int blk = blockIdx.x;          // (b*128 + win)*8 + h
    const int h = blk & 7;
    const int win = (blk >> 3) & 127;
    const int b = blk >> 10;
    const int rowbase = b * 4096 + win * 32;
    __shared__ float q[32][64], k[32][64], v[32][64];
    __shared__ float sc[32][33];
    const int tid = threadIdx.x;
    for (int idx = tid; idx < 2048; idx += 256) {
        int i = idx >> 6, d = idx & 63;
        const unsigned short* base = QKV + (size_t)(rowbase + i) * 1536 + h * 64 + d;
        q[i][d] = b2f(base[0]);
        k[i][d] = b2f(base[512]);
        v[i][d] = b2f(base[1024]);
    }
    __syncthreads();
    for (int idx = tid; idx < 1024; idx += 256) {
        int i = idx >> 5, j = idx & 31;
        float s = 0.f;
        #pragma unroll
        for (int d = 0; d < 64; d++) s += q[i][d] * k[j][d];
        sc[i][j] = s * 0.125f + rel[(i - j + 31) * 8 + h];
    }
    __syncthreads();
    if (tid < 32) {
        float mx = -1e30f;
        for (int j = 0; j < 32; j++) mx = fmaxf(mx, sc[tid][j]);
        float sum = 0.f;
        for (int j = 0; j < 32; j++) { float e = __expf(sc[tid][j] - mx); sc[tid][j] = e; sum += e; }
        float inv = 1.0f / sum;
        for (int j = 0; j < 32; j++) sc[tid][j] *= inv;
    }
    __syncthreads();
    for (int idx = tid; idx < 2048; idx += 256) {
        int i = idx >> 6, d = idx & 63;
        float o = 0.f;
        #pragma unroll
        for (int j = 0; j < 32; j++) o += sc[i][j] * v[j][d];
        OUT[(size_t)(rowbase + i) * 512 + h * 64 + d] = f2b(o);
    }
}

// ---------------------------------------------------------------------------
// Gather strided tokens for global attention
// ---------------------------------------------------------------------------
__global__ __launch_bounds__(256) void gather_xs_kernel(
    const float* __restrict__ XG, unsigned short* __restrict__ XSB)
{
    int i = blockIdx.x * 256 + threadIdx.x;   // 4*128*512 = 262144
    if (i < 262144) {
        int d = i & 511, t = (i >> 9) & 127, b = i >> 16;
        XSB[i] = f2b(XG[((size_t)b * 4096 + t * 32) * 512 + d]);
    }
}

// ---------------------------------------------------------------------------
// Global attention on 128 tokens/batch. Block per (b, h, qtile of 32).
// ---------------------------------------------------------------------------
__global__ __launch_bounds__(256) void global_attn_kernel(
    const unsigned short* __restrict__ GQKV, unsigned short* __restrict__ GOUT)
{
    const int blk = blockIdx.x;       // b*32 + h*4 + qt
    const int qt = blk & 3, h = (blk >> 2) & 7, b = blk >> 5;
    __shared__ unsigned short ks[128 * 64], vs[128 * 64];
    __shared__ float qs[32 * 64];
    __shared__ float sc[32 * 128];
    const int tid = threadIdx.x;
    for (int idx = tid; idx < 128 * 64; idx += 256) {
        int j = idx >> 6, d = idx & 63;
        const unsigned short* rowp = GQKV + (size_t)(b * 128 + j) * 1536 + h * 64 + d;
        ks[idx] = rowp[512];
        vs[idx] = rowp[1024];
    }
    for (int idx = tid; idx < 32 * 64; idx += 256) {
        int i = idx >> 6, d = idx & 63;
        qs[idx] = b2f(GQKV[(size_t)(b * 128 + qt * 32 + i) * 1536 + h * 64 + d]);
    }
    __syncthreads();
    for (int idx = tid; idx < 32 * 128; idx += 256) {
        int i = idx >> 7, j = idx & 127;
        float s = 0.f;
        #pragma unroll
        for (int d = 0; d < 64; d++) s += qs[i * 64 + d] * b2f(ks[j * 64 + d]);
        sc[idx] = s * 0.125f;
    }
    __syncthreads();
    if (tid < 32) {
        float mx = -1e30f;
        for (int j = 0; j < 128; j++) mx = fmaxf(mx, sc[tid * 128 + j]);
        float sum = 0.f;
        for (int j = 0; j < 128; j++) { float e = __expf(sc[tid * 128 + j] - mx); sc[tid * 128 + j] = e; sum += e; }
        float inv = 1.0f / sum;
        for (int j = 0; j < 128; j++) sc[tid * 128 + j] *= inv;
    }
    __syncthreads();
    for (int idx = tid; idx < 32 * 64; idx += 256) {
        int i = idx >> 6, d = idx & 63;
        float o = 0.f;
        for (int j = 0; j < 128; j++) o += sc[i * 128 + j] * b2f(vs[j * 64 + d]);
        GOUT[(size_t)(b * 128 + qt * 32 + i) * 512 + h * 64 + d] = f2b(o);
    }
}

// ---------------------------------------------------------------------------
// Y = X + dwconv(X) (K=7, zero pad). Writes f32 + bf16.
// ---------------------------------------------------------------------------
__global__ __launch_bounds__(256) void dwconv_add_kernel(
    const float* __restrict__ X, const float* __restrict__ wconv, const float* __restrict__ bconv,
    float* __restrict__ Yf, unsigned short* __restrict__ Yb)
{
    int i = blockIdx.x * 256 + threadIdx.x;
    if (i < 8388608) {
        int d = i & 511, s = (i >> 9) & 4095, b = i >> 21;
        float acc = bconv[d];
        #pragma unroll
        for (int t = 0; t < 7; t++) {
            int ss = s + t - 3;
            if (ss >= 0 && ss < 4096)
                acc += X[((size_t)b * 4096 + ss) * 512 + d] * wconv[d * 7 + t];
        }
        float v = X[i] + acc;
        Yf[i] = v;
        Yb[i] = f2b(v);
    }
}

// ---------------------------------------------------------------------------
// out = LN(w0*XL + w1*XG) with softmaxed scalar weights
// ---------------------------------------------------------------------------
__global__ __launch_bounds__(256) void final_kernel(
    const float* __restrict__ XL, const float* __restrict__ XG,
    const float* __restrict__ fwl, const float* __restrict__ fwg,
    const float* __restrict__ g, const float* __restrict__ bb, float* __restrict__ out)
{
    const int row = blockIdx.x, tid = threadIdx.x;
    float a = fwl[0], c = fwg[0];
    float m = fmaxf(a, c);
    float ea = __expf(a - m), ec = __expf(c - m);
    float w0 = ea / (ea + ec), w1 = ec / (ea + ec);
    const float* xlr = XL + (size_t)row * 512;
    const float* xgr = XG + (size_t)row * 512;
    float v0 = w0 * xlr[tid] + w1 * xgr[tid];
    float v1 = w0 * xlr[tid + 256] + w1 * xgr[tid + 256];
    float s = v0 + v1;
    #pragma unroll
    for (int o = 32; o > 0; o >>= 1) s += __shfl_down(s, o);
    __shared__ float red[4];
    __shared__ float stat[2];
    if ((tid & 63) == 0) red[tid >> 6] = s;
    __syncthreads();
    if (tid == 0) stat[0] = (red[0] + red[1] + red[2] + red[3]) * (1.0f / 512.0f);
    __syncthreads();
    float mu = stat[0];
    float d0 = v0 - mu, d1 = v1 - mu;
    float s2 = d0 * d0 + d1 * d1;
    #pragma unroll
    for (int o = 32; o > 0; o >>= 1) s2 += __shfl_down(s2, o);
    if ((tid & 63) == 0) red[tid >> 6] = s2;
    __syncthreads();
    if (tid == 0) stat[1] = rsqrtf((red[0] + red[1] + red[2] + red[3]) * (1.0f / 512.0f) + 1e-5f);
    __syncthreads();
    float rs = stat[1];
    float* orow = out + (size_t)row * 512;
    orow[tid]       = d0 * rs * g[tid] + bb[tid];
    orow[tid + 256] = d1 * rs * g[tid + 256] + bb[tid + 256];
}

// ---------------------------------------------------------------------------
extern "C" void kernel_launch(void* const* d_in, const int* in_sizes, int n_in,
                              void* d_out, int out_size, void* d_ws, size_t ws_size,
                              hipStream_t stream)
{
    (void)in_sizes; (void)n_in; (void)out_size; (void)ws_size;
    const float* x       = (const float*)d_in[0];
    const float* lqkv_w  = (const float*)d_in[1];
    const float* lqkv_b  = (const float*)d_in[2];
    const float* lproj_w = (const float*)d_in[3];
    const float* lproj_b = (const float*)d_in[4];
    const float* lrel    = (const float*)d_in[5];
    const float* lconv_w = (const float*)d_in[6];
    const float* lconv_b = (const float*)d_in[7];
    const float* ln1_g   = (const float*)d_in[8];
    const float* ln1_b   = (const float*)d_in[9];
    const float* lffn_w1 = (const float*)d_in[10];
    const float* lffn_b1 = (const float*)d_in[11];
    const float* lffn_w2 = (const float*)d_in[12];
    const float* lffn_b2 = (const float*)d_in[13];
    const float* ln2_g   = (const float*)d_in[14];
    const float* ln2_b   = (const float*)d_in[15];
    const float* gqkv_w  = (const float*)d_in[16];
    const float* gqkv_b  = (const float*)d_in[17];
    const float* gproj_w = (const float*)d_in[18];
    const float* gproj_b = (const float*)d_in[19];
    const float* gn1_g   = (const float*)d_in[20];
    const float* gn1_b   = (const float*)d_in[21];
    const float* gffn_w1 = (const float*)d_in[22];
    const float* gffn_b1 = (const float*)d_in[23];
    const float* gffn_w2 = (const float*)d_in[24];
    const float* gffn_b2 = (const float*)d_in[25];
    const float* gn2_g   = (const float*)d_in[26];
    const float* gn2_b   = (const float*)d_in[27];
    const float* fw_local  = (const float*)d_in[28];
    const float* fw_global = (const float*)d_in[29];
    const float* fn_g    = (const float*)d_in[30];
    const float* fn_b    = (const float*)d_in[31];
    float* out = (float*)d_out;

    const int Btot = 4 * 4096;     // 16384 token rows
    const int nel = Btot * 512;    // 8388608

    char* wsb = (char*)d_ws;
    size_t off = 0;
    auto alloc = [&](size_t bytes) -> void* {
        void* p = wsb + off;
        off = (off + bytes + 255) & ~(size_t)255;
        return p;
    };
    float*          XL   = (float*)alloc((size_t)nel * 4);
    float*          XG   = (float*)alloc((size_t)nel * 4);
    float*          TMP  = (float*)alloc((size_t)nel * 4);
    unsigned short* XBl  = (unsigned short*)alloc((size_t)nel * 2);
    unsigned short* XBg  = (unsigned short*)alloc((size_t)nel * 2);
    unsigned short* AOUT = (unsigned short*)alloc((size_t)nel * 2);
    unsigned short* BIG  = (unsigned short*)alloc((size_t)Btot * 2048 * 2);
    unsigned short* WT   = (unsigned short*)alloc((size_t)22020096 * 2);
    unsigned short* XSB  = (unsigned short*)alloc((size_t)512 * 512 * 2);
    unsigned short* GQKV = (unsigned short*)alloc((size_t)512 * 1536 * 2);
    unsigned short* GOUT = (unsigned short*)alloc((size_t)512 * 512 * 2);
    float*          GA   = (float*)alloc((size_t)512 * 512 * 4);

    const size_t perL = 3145728;   // bf16 elems of transposed weights per layer
    auto transpose = [&](const float* W_, unsigned short* WT_, int Kd, int Nd) {
        dim3 g(Nd / 32, Kd / 32);
        transpose_cast_kernel<<<g, dim3(256), 0, stream>>>(W_, WT_, Kd, Nd);
    };
    for (int i = 0; i < 4; i++) {
        unsigned short* base = WT + (size_t)i * perL;
        transpose(lqkv_w  + (size_t)i * 512 * 1536, base,                         512, 1536);
        transpose(lproj_w + (size_t)i * 512 * 512,  base + 786432,                512, 512);
        transpose(lffn_w1 + (size_t)i * 512 * 2048, base + 786432 + 262144,       512, 2048);
        transpose(lffn_w2 + (size_t)i * 2048 * 512, base + 786432 + 262144 + 1048576, 2048, 512);
    }
    for (int i = 0; i < 3; i++) {
        unsigned short* base = WT + (size_t)(4 + i) * perL;
        transpose(gqkv_w  + (size_t)i * 512 * 1536, base,                         512, 1536);
        transpose(gproj_w + (size_t)i * 512 * 512,  base + 786432,                512, 512);
        transpose(gffn_w1 + (size_t)i * 512 * 2048, base + 786432 + 262144,       512, 2048);
        transpose(gffn_w2 + (size_t)i * 2048 * 512, base + 786432 + 262144 + 1048576, 2048, 512);
    }

    copy_cast_kernel<<<dim3(nel / 256), dim3(256), 0, stream>>>(x, XL, XG, XBl, nel);

    auto gemm = [&](const unsigned short* A_, const unsigned short* BT_, const float* bias_,
                    const float* res_, float* Cf_, unsigned short* Cb_,
                    int M_, int N_, int K_, int act_) {
        dim3 g(M_ / 128, N_ / 128);
        gemm_kernel<<<g, dim3(256), 0, stream>>>(A_, BT_, bias_, res_, Cf_, Cb_, M_, N_, K_, act_);
    };

    // ---------------- local branch: 4 layers ----------------
    for (int i = 0; i < 4; i++) {
        unsigned short* base  = WT + (size_t)i * perL;
        unsigned short* qkvT  = base;
        unsigned short* projT = base + 786432;
        unsigned short* w1T   = base + 786432 + 262144;
        unsigned short* w2T   = base + 786432 + 262144 + 1048576;

        gemm(XBl, qkvT, lqkv_b + i * 1536, nullptr, nullptr, BIG, Btot, 1536, 512, 0);
        local_attn_kernel<<<dim3(4096), dim3(256), 0, stream>>>(BIG, lrel + (size_t)i * 63 * 8, AOUT);
        gemm(AOUT, projT, lproj_b + i * 512, XL, TMP, nullptr, Btot, 512, 512, 0);
        ln_kernel<<<dim3(Btot), dim3(256), 0, stream>>>(TMP, ln1_g + i * 512, ln1_b + i * 512, XL, (unsigned short*)nullptr);
        dwconv_add_kernel<<<dim3(nel / 256), dim3(256), 0, stream>>>(XL, lconv_w + (size_t)i * 512 * 7, lconv_b + i * 512, TMP, XBl);
        gemm(XBl, w1T, lffn_b1 + i * 2048, nullptr, nullptr, BIG, Btot, 2048, 512, 1);
        gemm(BIG, w2T, lffn_b2 + i * 512, TMP, TMP, nullptr, Btot, 512, 2048, 0);
        ln_kernel<<<dim3(Btot), dim3(256), 0, stream>>>(TMP, ln2_g + i * 512, ln2_b + i * 512, XL, XBl);
    }

    // ---------------- global branch: 3 layers ----------------
    for (int i = 0; i < 3; i++) {
        unsigned short* base  = WT + (size_t)(4 + i) * perL;
        unsigned short* qkvT  = base;
        unsigned short* projT = base + 786432;
        unsigned short* w1T   = base + 786432 + 262144;
        unsigned short* w2T   = base + 786432 + 262144 + 1048576;

        gather_xs_kernel<<<dim3(1024), dim3(256), 0, stream>>>(XG, XSB);
        gemm(XSB, qkvT, gqkv_b + i * 1536, nullptr, nullptr, GQKV, 512, 1536, 512, 0);
        global_attn_kernel<<<dim3(128), dim3(256), 0, stream>>>(GQKV, GOUT);
        gemm(GOUT, projT, gproj_b + i * 512, nullptr, GA, nullptr, 512, 512, 512, 0);
        interp_ln_kernel<<<dim3(Btot), dim3(256), 0, stream>>>(GA, XG, gn1_g + i * 512, gn1_b + i * 512, XBg);
        gemm(XBg, w1T, gffn_b1 + i * 2048, nullptr, nullptr, BIG, Btot, 2048, 512, 1);
        gemm(BIG, w2T, gffn_b2 + i * 512, XG, TMP, nullptr, Btot, 512, 2048, 0);
        ln_kernel<<<dim3(Btot), dim3(256), 0, stream>>>(TMP, gn2_g + i * 512, gn2_b + i * 512, XG, XBg);
    }

    final_kernel<<<dim3(Btot), dim3(256), 0, stream>>>(XL, XG, fw_local, fw_global, fn_g, fn_b, out);
}

// Round 4
// 2352.023 us; speedup vs baseline: 1.1818x; 1.0952x over previous
//
#include <hip/hip_runtime.h>
#include <math.h>

typedef __attribute__((ext_vector_type(8))) short short8;
typedef __attribute__((ext_vector_type(4))) float float4_t;

#define DEV static __device__ __forceinline__

DEV unsigned short f2b(float f) {
    union { float f; unsigned int u; } x; x.f = f;
    unsigned int r = x.u + 0x7fffu + ((x.u >> 16) & 1u);
    return (unsigned short)(r >> 16);
}
DEV float b2f(unsigned short u) {
    union { unsigned int u; float f; } x; x.u = ((unsigned int)u) << 16;
    return x.f;
}
// gelu(x) = x * sigmoid(2u), u = 0.79788456(x + 0.044715x^3); exp via v_exp_f32
DEV float gelu_f(float x) {
    float u = 0.7978845608028654f * (x + 0.044715f * x * x * x);
    float e = __expf(-2.0f * u);
    return x / (1.0f + e);
}

DEV void gld16(unsigned short* lds, const unsigned short* g) {
    __builtin_amdgcn_global_load_lds(
        (const __attribute__((address_space(1))) unsigned int*)g,
        (__attribute__((address_space(3))) unsigned int*)lds,
        16, 0, 0);
}

// ---------------------------------------------------------------------------
// Tiled transpose + cast: W (K x N, f32) -> WT (N x K, bf16)
// ---------------------------------------------------------------------------
__global__ __launch_bounds__(256) void transpose_cast_kernel(
    const float* __restrict__ W, unsigned short* __restrict__ WT, int Kd, int Nd)
{
    __shared__ float tile[32][33];
    int n0 = blockIdx.x * 32, k0 = blockIdx.y * 32;
    int tx = threadIdx.x & 31, ty = threadIdx.x >> 5;   // 32 x 8
    #pragma unroll
    for (int r = ty; r < 32; r += 8)
        tile[r][tx] = W[(size_t)(k0 + r) * Nd + n0 + tx];
    __syncthreads();
    #pragma unroll
    for (int r = ty; r < 32; r += 8)
        WT[(size_t)(n0 + r) * Kd + k0 + tx] = f2b(tile[tx][r]);
}

// ---------------------------------------------------------------------------
// copy x -> XL (f32), XG (f32), XB (bf16)
// ---------------------------------------------------------------------------
__global__ __launch_bounds__(256) void copy_cast_kernel(
    const float* __restrict__ x, float* __restrict__ xl, float* __restrict__ xg,
    unsigned short* __restrict__ xb, int n)
{
    int i = blockIdx.x * 256 + threadIdx.x;
    if (i < n) { float v = x[i]; xl[i] = v; xg[i] = v; xb[i] = f2b(v); }
}

// ---------------------------------------------------------------------------
// bf16 MFMA GEMM, double-buffered K-loop (one barrier/iter; prefetch of
// tile k+1 overlaps MFMA on tile k — short-K latency fix).
// BN=128: 128x128 block tile, wave grid 2x2, 64x64/wave (4x4 frags).
// BN=64 : 128x64 block tile, waves stacked along M, 32x64/wave (2x4 frags).
// A: M x K bf16 row-major.  BT: N x K bf16 row-major.
// ---------------------------------------------------------------------------
template<int BN>
__global__ __launch_bounds__(256) void gemm_db_kernel(
    const unsigned short* __restrict__ A,
    const unsigned short* __restrict__ BT,
    const float* __restrict__ bias,
    const float* __restrict__ residual,
    float* __restrict__ Cf,
    unsigned short* __restrict__ Cb,
    int M, int N, int K, int act)
{
    constexpr int NI = (BN == 128) ? 4 : 2;
    __shared__ __align__(16) unsigned short As[2][128 * 32];
    __shared__ __align__(16) unsigned short Bs[2][BN * 32];
    const int tid = threadIdx.x;
    const int wave = tid >> 6, lane = tid & 63;
    const int quad = lane >> 4, l16 = lane & 15;
    const int m0 = blockIdx.x * 128, n0 = blockIdx.y * BN;
    const int wm = (BN == 128) ? (wave >> 1) * 64 : wave * 32;
    const int wn = (BN == 128) ? (wave & 1) * 64 : 0;

    float4_t acc[NI][4] = {};

    const int lrow = lane >> 2;           // 0..15
    const int lcol = (lane & 3) * 8;      // 0,8,16,24 (bf16 elems)
    const int r0 = wave * 16 + lrow;      // staging row, round 0
    const unsigned short* Ag0 = A  + (size_t)(m0 + r0) * K + lcol;
    const unsigned short* Ag1 = A  + (size_t)(m0 + 64 + r0) * K + lcol;
    const unsigned short* Bg0 = BT + (size_t)(n0 + r0) * K + lcol;
    const unsigned short* Bg1 = (BN == 128) ? BT + (size_t)(n0 + 64 + r0) * K + lcol : nullptr;
    const int soff = (wave * 16) * 32 + lane * 8;   // LDS write offset (elems)

    const int iters = K >> 5;
    // prologue: stage tile 0 into buf 0
    {
        gld16(&As[0][soff], Ag0);
        gld16(&As[0][soff + 64 * 32], Ag1);
        gld16(&Bs[0][soff], Bg0);
        if (BN == 128) gld16(&Bs[0][soff + 64 * 32], Bg1);
    }
    __syncthreads();

    for (int k = 0; k < iters; k++) {
        const int cur = k & 1;
        if (k + 1 < iters) {
            const int koff = (k + 1) << 5;
            const int nxt = cur ^ 1;
            gld16(&As[nxt][soff], Ag0 + koff);
            gld16(&As[nxt][soff + 64 * 32], Ag1 + koff);
            gld16(&Bs[nxt][soff], Bg0 + koff);
            if (BN == 128) gld16(&Bs[nxt][soff + 64 * 32], Bg1 + koff);
        }
        short8 a[NI], b[4];
        #pragma unroll
        for (int i = 0; i < NI; i++)
            a[i] = *(const short8*)(&As[cur][(wm + i * 16 + l16) * 32 + quad * 8]);
        #pragma unroll
        for (int j = 0; j < 4; j++)
            b[j] = *(const short8*)(&Bs[cur][(wn + j * 16 + l16) * 32 + quad * 8]);
        #pragma unroll
        for (int i = 0; i < NI; i++)
            #pragma unroll
            for (int j = 0; j < 4; j++)
                acc[i][j] = __builtin_amdgcn_mfma_f32_16x16x32_bf16(a[i], b[j], acc[i][j], 0, 0, 0);
        __syncthreads();   // publishes prefetched tile + protects consumed buf
    }

    #pragma unroll
    for (int i = 0; i < NI; i++) {
        #pragma unroll
        for (int j = 0; j < 4; j++) {
            int col = n0 + wn + j * 16 + l16;
            float bv = bias[col];
            #pragma unroll
            for (int r = 0; r < 4; r++) {
                int row = m0 + wm + i * 16 + quad * 4 + r;
                float v = acc[i][j][r] + bv;
                if (act == 1) v = gelu_f(v);
                size_t idx = (size_t)row * N + col;
                if (residual) v += residual[idx];
                if (Cf) Cf[idx] = v;
                if (Cb) Cb[idx] = f2b(v);
            }
        }
    }
}

// ---------------------------------------------------------------------------
// LayerNorm over D=512. One block (256 thr) per row. Optional f32/bf16 outs.
// ---------------------------------------------------------------------------
__global__ __launch_bounds__(256) void ln_kernel(
    const float* __restrict__ X, const float* __restrict__ g, const float* __restrict__ b,
    float* __restrict__ Yf, unsigned short* __restrict__ Yb)
{
    const int row = blockIdx.x, tid = threadIdx.x;
    const float* xr = X + (size_t)row * 512;
    float v0 = xr[tid], v1 = xr[tid + 256];
    float s = v0 + v1;
    #pragma unroll
    for (int o = 32; o > 0; o >>= 1) s += __shfl_down(s, o);
    __shared__ float red[4];
    __shared__ float stat[2];
    if ((tid & 63) == 0) red[tid >> 6] = s;
    __syncthreads();
    if (tid == 0) stat[0] = (red[0] + red[1] + red[2] + red[3]) * (1.0f / 512.0f);
    __syncthreads();
    float mu = stat[0];
    float d0 = v0 - mu, d1 = v1 - mu;
    float s2 = d0 * d0 + d1 * d1;
    #pragma unroll
    for (int o = 32; o > 0; o >>= 1) s2 += __shfl_down(s2, o);
    if ((tid & 63) == 0) red[tid >> 6] = s2;
    __syncthreads();
    if (tid == 0) stat[1] = rsqrtf((red[0] + red[1] + red[2] + red[3]) * (1.0f / 512.0f) + 1e-5f);
    __syncthreads();
    float rs = stat[1];
    float y0 = d0 * rs * g[tid] + b[tid];
    float y1 = d1 * rs * g[tid + 256] + b[tid + 256];
    if (Yf) { float* yr = Yf + (size_t)row * 512; yr[tid] = y0; yr[tid + 256] = y1; }
    if (Yb) { unsigned short* yb = Yb + (size_t)row * 512; yb[tid] = f2b(y0); yb[tid + 256] = f2b(y1); }
}

// ---------------------------------------------------------------------------
// Fused: v = XG + lin_interp(GA 128->4096);  XG = LN(v); XBg = bf16(XG)
// ---------------------------------------------------------------------------
__global__ __launch_bounds__(256) void interp_ln_kernel(
    const float* __restrict__ GA, float* __restrict__ XG,
    const float* __restrict__ g, const float* __restrict__ b,
    unsigned short* __restrict__ Yb)
{
    const int row = blockIdx.x, tid = threadIdx.x;
    const int bb = row >> 12, s = row & 4095;
    float pos = (s + 0.5f) * (128.0f / 4096.0f) - 0.5f;
    pos = fminf(fmaxf(pos, 0.0f), 127.0f);
    int i0 = (int)floorf(pos);
    int i1 = min(i0 + 1, 127);
    float w = pos - (float)i0;
    const float* ga0 = GA + ((size_t)bb * 128 + i0) * 512;
    const float* ga1 = GA + ((size_t)bb * 128 + i1) * 512;
    float* xr = XG + (size_t)row * 512;
    float v0 = xr[tid]       + ga0[tid]       * (1.0f - w) + ga1[tid]       * w;
    float v1 = xr[tid + 256] + ga0[tid + 256] * (1.0f - w) + ga1[tid + 256] * w;
    float sm = v0 + v1;
    #pragma unroll
    for (int o = 32; o > 0; o >>= 1) sm += __shfl_down(sm, o);
    __shared__ float red[4];
    __shared__ float stat[2];
    if ((tid & 63) == 0) red[tid >> 6] = sm;
    __syncthreads();
    if (tid == 0) stat[0] = (red[0] + red[1] + red[2] + red[3]) * (1.0f / 512.0f);
    __syncthreads();
    float mu = stat[0];
    float d0 = v0 - mu, d1 = v1 - mu;
    float s2 = d0 * d0 + d1 * d1;
    #pragma unroll
    for (int o = 32; o > 0; o >>= 1) s2 += __shfl_down(s2, o);
    if ((tid & 63) == 0) red[tid >> 6] = s2;
    __syncthreads();
    if (tid == 0) stat[1] = rsqrtf((red[0] + red[1] + red[2] + red[3]) * (1.0f / 512.0f) + 1e-5f);
    __syncthreads();
    float rs = stat[1];
    float y0 = d0 * rs * g[tid] + b[tid];
    float y1 = d1 * rs * g[tid + 256] + b[tid + 256];
    xr[tid] = y0;           xr[tid + 256] = y1;
    unsigned short* yb = Yb + (size_t)row * 512;
    yb[tid] = f2b(y0);      yb[tid + 256] = f2b(y1);
}

// ---------------------------------------------------------------------------
// Local windowed attention. One block per (b, window, head). W=32, HD=64.
// ---------------------------------------------------------------------------
__global__ __launch_bounds__(256) void local_attn_kernel(
    const unsigned short* __restrict__ QKV, const float* __restrict__ rel,
    unsigned short* __restrict__ OUT)
{
    const int blk = blockIdx.x;          // (b*128 + win)*8 + h
    const int h = blk & 7;
    const int win = (blk >> 3) & 127;
    const int b = blk >> 10;
    const int rowbase = b * 4096 + win * 32;
    __shared__ float q[32][64], k[32][64], v[32][64];
    __shared__ float sc[32][33];
    const int tid = threadIdx.x;
    for (int idx = tid; idx < 2048; idx += 256) {
        int i = idx >> 6, d = idx & 63;
        const unsigned short* base = QKV + (size_t)(rowbase + i) * 1536 + h * 64 + d;
        q[i][d] = b2f(base[0]);
        k[i][d] = b2f(base[512]);
        v[i][d] = b2f(base[1024]);
    }
    __syncthreads();
    for (int idx = tid; idx < 1024; idx += 256) {
        int i = idx >> 5, j = idx & 31;
        float s = 0.f;
        #pragma unroll
        for (int d = 0; d < 64; d++) s += q[i][d] * k[j][d];
        sc[i][j] = s * 0.125f + rel[(i - j + 31) * 8 + h];
    }
    __syncthreads();
    if (tid < 32) {
        float mx = -1e30f;
        for (int j = 0; j < 32; j++) mx = fmaxf(mx, sc[tid][j]);
        float sum = 0.f;
        for (int j = 0; j < 32; j++) { float e = __expf(sc[tid][j] - mx); sc[tid][j] = e; sum += e; }
        float inv = 1.0f / sum;
        for (int j = 0; j < 32; j++) sc[tid][j] *= inv;
    }
    __syncthreads();
    for (int idx = tid; idx < 2048; idx += 256) {
        int i = idx >> 6, d = idx & 63;
        float o = 0.f;
        #pragma unroll
        for (int j = 0; j < 32; j++) o += sc[i][j] * v[j][d];
        OUT[(size_t)(rowbase + i) * 512 + h * 64 + d] = f2b(o);
    }
}

// ---------------------------------------------------------------------------
// Gather strided tokens for global attention
// ---------------------------------------------------------------------------
__global__ __launch_bounds__(256) void gather_xs_kernel(
    const float* __restrict__ XG, unsigned short* __restrict__ XSB)
{
    int i = blockIdx.x * 256 + threadIdx.x;   // 4*128*512 = 262144
    if (i < 262144) {
        int d = i & 511, t = (i >> 9) & 127, b = i >> 16;
        XSB[i] = f2b(XG[((size_t)b * 4096 + t * 32) * 512 + d]);
    }
}

// ---------------------------------------------------------------------------
// Global attention on 128 tokens/batch. Block per (b, h, qtile of 32).
// ---------------------------------------------------------------------------
__global__ __launch_bounds__(256) void global_attn_kernel(
    const unsigned short* __restrict__ GQKV, unsigned short* __restrict__ GOUT)
{
    const int blk = blockIdx.x;       // b*32 + h*4 + qt
    const int qt = blk & 3, h = (blk >> 2) & 7, b = blk >> 5;
    __shared__ unsigned short ks[128 * 64], vs[128 * 64];
    __shared__ float qs[32 * 64];
    __shared__ float sc[32 * 128];
    const int tid = threadIdx.x;
    for (int idx = tid; idx < 128 * 64; idx += 256) {
        int j = idx >> 6, d = idx & 63;
        const unsigned short* rowp = GQKV + (size_t)(b * 128 + j) * 1536 + h * 64 + d;
        ks[idx] = rowp[512];
        vs[idx] = rowp[1024];
    }
    for (int idx = tid; idx < 32 * 64; idx += 256) {
        int i = idx >> 6, d = idx & 63;
        qs[idx] = b2f(GQKV[(size_t)(b * 128 + qt * 32 + i) * 1536 + h * 64 + d]);
    }
    __syncthreads();
    for (int idx = tid; idx < 32 * 128; idx += 256) {
        int i = idx >> 7, j = idx & 127;
        float s = 0.f;
        #pragma unroll
        for (int d = 0; d < 64; d++) s += qs[i * 64 + d] * b2f(ks[j * 64 + d]);
        sc[idx] = s * 0.125f;
    }
    __syncthreads();
    if (tid < 32) {
        float mx = -1e30f;
        for (int j = 0; j < 128; j++) mx = fmaxf(mx, sc[tid * 128 + j]);
        float sum = 0.f;
        for (int j = 0; j < 128; j++) { float e = __expf(sc[tid * 128 + j] - mx); sc[tid * 128 + j] = e; sum += e; }
        float inv = 1.0f / sum;
        for (int j = 0; j < 128; j++) sc[tid * 128 + j] *= inv;
    }
    __syncthreads();
    for (int idx = tid; idx < 32 * 64; idx += 256) {
        int i = idx >> 6, d = idx & 63;
        float o = 0.f;
        for (int j = 0; j < 128; j++) o += sc[i * 128 + j] * b2f(vs[j * 64 + d]);
        GOUT[(size_t)(b * 128 + qt * 32 + i) * 512 + h * 64 + d] = f2b(o);
    }
}

// ---------------------------------------------------------------------------
// Y = X + dwconv(X) (K=7, zero pad). Writes f32 + bf16.
// ---------------------------------------------------------------------------
__global__ __launch_bounds__(256) void dwconv_add_kernel(
    const float* __restrict__ X, const float* __restrict__ wconv, const float* __restrict__ bconv,
    float* __restrict__ Yf, unsigned short* __restrict__ Yb)
{
    int i = blockIdx.x * 256 + threadIdx.x;
    if (i < 8388608) {
        int d = i & 511, s = (i >> 9) & 4095, b = i >> 21;
        float acc = bconv[d];
        #pragma unroll
        for (int t = 0; t < 7; t++) {
            int ss = s + t - 3;
            if (ss >= 0 && ss < 4096)
                acc += X[((size_t)b * 4096 + ss) * 512 + d] * wconv[d * 7 + t];
        }
        float v = X[i] + acc;
        Yf[i] = v;
        Yb[i] = f2b(v);
    }
}

// ---------------------------------------------------------------------------
// out = LN(w0*XL + w1*XG) with softmaxed scalar weights
// ---------------------------------------------------------------------------
__global__ __launch_bounds__(256) void final_kernel(
    const float* __restrict__ XL, const float* __restrict__ XG,
    const float* __restrict__ fwl, const float* __restrict__ fwg,
    const float* __restrict__ g, const float* __restrict__ bb, float* __restrict__ out)
{
    const int row = blockIdx.x, tid = threadIdx.x;
    float a = fwl[0], c = fwg[0];
    float m = fmaxf(a, c);
    float ea = __expf(a - m), ec = __expf(c - m);
    float w0 = ea / (ea + ec), w1 = ec / (ea + ec);
    const float* xlr = XL + (size_t)row * 512;
    const float* xgr = XG + (size_t)row * 512;
    float v0 = w0 * xlr[tid] + w1 * xgr[tid];
    float v1 = w0 * xlr[tid + 256] + w1 * xgr[tid + 256];
    float s = v0 + v1;
    #pragma unroll
    for (int o = 32; o > 0; o >>= 1) s += __shfl_down(s, o);
    __shared__ float red[4];
    __shared__ float stat[2];
    if ((tid & 63) == 0) red[tid >> 6] = s;
    __syncthreads();
    if (tid == 0) stat[0] = (red[0] + red[1] + red[2] + red[3]) * (1.0f / 512.0f);
    __syncthreads();
    float mu = stat[0];
    float d0 = v0 - mu, d1 = v1 - mu;
    float s2 = d0 * d0 + d1 * d1;
    #pragma unroll
    for (int o = 32; o > 0; o >>= 1) s2 += __shfl_down(s2, o);
    if ((tid & 63) == 0) red[tid >> 6] = s2;
    __syncthreads();
    if (tid == 0) stat[1] = rsqrtf((red[0] + red[1] + red[2] + red[3]) * (1.0f / 512.0f) + 1e-5f);
    __syncthreads();
    float rs = stat[1];
    float* orow = out + (size_t)row * 512;
    orow[tid]       = d0 * rs * g[tid] + bb[tid];
    orow[tid + 256] = d1 * rs * g[tid + 256] + bb[tid + 256];
}

// ---------------------------------------------------------------------------
extern "C" void kernel_launch(void* const* d_in, const int* in_sizes, int n_in,
                              void* d_out, int out_size, void* d_ws, size_t ws_size,
                              hipStream_t stream)
{
    (void)in_sizes; (void)n_in; (void)out_size; (void)ws_size;
    const float* x       = (const float*)d_in[0];
    const float* lqkv_w  = (const float*)d_in[1];
    const float* lqkv_b  = (const float*)d_in[2];
    const float* lproj_w = (const float*)d_in[3];
    const float* lproj_b = (const float*)d_in[4];
    const float* lrel    = (const float*)d_in[5];
    const float* lconv_w = (const float*)d_in[6];
    const float* lconv_b = (const float*)d_in[7];
    const float* ln1_g   = (const float*)d_in[8];
    const float* ln1_b   = (const float*)d_in[9];
    const float* lffn_w1 = (const float*)d_in[10];
    const float* lffn_b1 = (const float*)d_in[11];
    const float* lffn_w2 = (const float*)d_in[12];
    const float* lffn_b2 = (const float*)d_in[13];
    const float* ln2_g   = (const float*)d_in[14];
    const float* ln2_b   = (const float*)d_in[15];
    const float* gqkv_w  = (const float*)d_in[16];
    const float* gqkv_b  = (const float*)d_in[17];
    const float* gproj_w = (const float*)d_in[18];
    const float* gproj_b = (const float*)d_in[19];
    const float* gn1_g   = (const float*)d_in[20];
    const float* gn1_b   = (const float*)d_in[21];
    const float* gffn_w1 = (const float*)d_in[22];
    const float* gffn_b1 = (const float*)d_in[23];
    const float* gffn_w2 = (const float*)d_in[24];
    const float* gffn_b2 = (const float*)d_in[25];
    const float* gn2_g   = (const float*)d_in[26];
    const float* gn2_b   = (const float*)d_in[27];
    const float* fw_local  = (const float*)d_in[28];
    const float* fw_global = (const float*)d_in[29];
    const float* fn_g    = (const float*)d_in[30];
    const float* fn_b    = (const float*)d_in[31];
    float* out = (float*)d_out;

    const int Btot = 4 * 4096;     // 16384 token rows
    const int nel = Btot * 512;    // 8388608

    char* wsb = (char*)d_ws;
    size_t off = 0;
    auto alloc = [&](size_t bytes) -> void* {
        void* p = wsb + off;
        off = (off + bytes + 255) & ~(size_t)255;
        return p;
    };
    float*          XL   = (float*)alloc((size_t)nel * 4);
    float*          XG   = (float*)alloc((size_t)nel * 4);
    float*          TMP  = (float*)alloc((size_t)nel * 4);
    unsigned short* XBl  = (unsigned short*)alloc((size_t)nel * 2);
    unsigned short* XBg  = (unsigned short*)alloc((size_t)nel * 2);
    unsigned short* AOUT = (unsigned short*)alloc((size_t)nel * 2);
    unsigned short* BIG  = (unsigned short*)alloc((size_t)Btot * 2048 * 2);
    unsigned short* WT   = (unsigned short*)alloc((size_t)22020096 * 2);
    unsigned short* XSB  = (unsigned short*)alloc((size_t)512 * 512 * 2);
    unsigned short* GQKV = (unsigned short*)alloc((size_t)512 * 1536 * 2);
    unsigned short* GOUT = (unsigned short*)alloc((size_t)512 * 512 * 2);
    float*          GA   = (float*)alloc((size_t)512 * 512 * 4);

    const size_t perL = 3145728;   // bf16 elems of transposed weights per layer
    auto transpose = [&](const float* W_, unsigned short* WT_, int Kd, int Nd) {
        dim3 g(Nd / 32, Kd / 32);
        transpose_cast_kernel<<<g, dim3(256), 0, stream>>>(W_, WT_, Kd, Nd);
    };
    for (int i = 0; i < 4; i++) {
        unsigned short* base = WT + (size_t)i * perL;
        transpose(lqkv_w  + (size_t)i * 512 * 1536, base,                         512, 1536);
        transpose(lproj_w + (size_t)i * 512 * 512,  base + 786432,                512, 512);
        transpose(lffn_w1 + (size_t)i * 512 * 2048, base + 786432 + 262144,       512, 2048);
        transpose(lffn_w2 + (size_t)i * 2048 * 512, base + 786432 + 262144 + 1048576, 2048, 512);
    }
    for (int i = 0; i < 3; i++) {
        unsigned short* base = WT + (size_t)(4 + i) * perL;
        transpose(gqkv_w  + (size_t)i * 512 * 1536, base,                         512, 1536);
        transpose(gproj_w + (size_t)i * 512 * 512,  base + 786432,                512, 512);
        transpose(gffn_w1 + (size_t)i * 512 * 2048, base + 786432 + 262144,       512, 2048);
        transpose(gffn_w2 + (size_t)i * 2048 * 512, base + 786432 + 262144 + 1048576, 2048, 512);
    }

    copy_cast_kernel<<<dim3(nel / 256), dim3(256), 0, stream>>>(x, XL, XG, XBl, nel);

    auto gemm = [&](const unsigned short* A_, const unsigned short* BT_, const float* bias_,
                    const float* res_, float* Cf_, unsigned short* Cb_,
                    int M_, int N_, int K_, int act_) {
        if (N_ >= 1024) {
            dim3 g(M_ / 128, N_ / 128);
            gemm_db_kernel<128><<<g, dim3(256), 0, stream>>>(A_, BT_, bias_, res_, Cf_, Cb_, M_, N_, K_, act_);
        } else {
            dim3 g(M_ / 128, N_ / 64);
            gemm_db_kernel<64><<<g, dim3(256), 0, stream>>>(A_, BT_, bias_, res_, Cf_, Cb_, M_, N_, K_, act_);
        }
    };

    // ---------------- local branch: 4 layers ----------------
    for (int i = 0; i < 4; i++) {
        unsigned short* base  = WT + (size_t)i * perL;
        unsigned short* qkvT  = base;
        unsigned short* projT = base + 786432;
        unsigned short* w1T   = base + 786432 + 262144;
        unsigned short* w2T   = base + 786432 + 262144 + 1048576;

        gemm(XBl, qkvT, lqkv_b + i * 1536, nullptr, nullptr, BIG, Btot, 1536, 512, 0);
        local_attn_kernel<<<dim3(4096), dim3(256), 0, stream>>>(BIG, lrel + (size_t)i * 63 * 8, AOUT);
        gemm(AOUT, projT, lproj_b + i * 512, XL, TMP, nullptr, Btot, 512, 512, 0);
        ln_kernel<<<dim3(Btot), dim3(256), 0, stream>>>(TMP, ln1_g + i * 512, ln1_b + i * 512, XL, (unsigned short*)nullptr);
        dwconv_add_kernel<<<dim3(nel / 256), dim3(256), 0, stream>>>(XL, lconv_w + (size_t)i * 512 * 7, lconv_b + i * 512, TMP, XBl);
        gemm(XBl, w1T, lffn_b1 + i * 2048, nullptr, nullptr, BIG, Btot, 2048, 512, 1);
        gemm(BIG, w2T, lffn_b2 + i * 512, TMP, TMP, nullptr, Btot, 512, 2048, 0);
        ln_kernel<<<dim3(Btot), dim3(256), 0, stream>>>(TMP, ln2_g + i * 512, ln2_b + i * 512, XL, XBl);
    }

    // ---------------- global branch: 3 layers ----------------
    for (int i = 0; i < 3; i++) {
        unsigned short* base  = WT + (size_t)(4 + i) * perL;
        unsigned short* qkvT  = base;
        unsigned short* projT = base + 786432;
        unsigned short* w1T   = base + 786432 + 262144;
        unsigned short* w2T   = base + 786432 + 262144 + 1048576;

        gather_xs_kernel<<<dim3(1024), dim3(256), 0, stream>>>(XG, XSB);
        gemm(XSB, qkvT, gqkv_b + i * 1536, nullptr, nullptr, GQKV, 512, 1536, 512, 0);
        global_attn_kernel<<<dim3(128), dim3(256), 0, stream>>>(GQKV, GOUT);
        gemm(GOUT, projT, gproj_b + i * 512, nullptr, GA, nullptr, 512, 512, 512, 0);
        interp_ln_kernel<<<dim3(Btot), dim3(256), 0, stream>>>(GA, XG, gn1_g + i * 512, gn1_b + i * 512, XBg);
        gemm(XBg, w1T, gffn_b1 + i * 2048, nullptr, nullptr, BIG, Btot, 2048, 512, 1);
        gemm(BIG, w2T, gffn_b2 + i * 512, XG, TMP, nullptr, Btot, 512, 2048, 0);
        ln_kernel<<<dim3(Btot), dim3(256), 0, stream>>>(TMP, gn2_g + i * 512, gn2_b + i * 512, XG, XBg);
    }

    final_kernel<<<dim3(Btot), dim3(256), 0, stream>>>(XL, XG, fw_local, fw_global, fn_g, fn_b, out);
}

// Round 5
// 2246.152 us; speedup vs baseline: 1.2375x; 1.0471x over previous
//
#include <hip/hip_runtime.h>
#include <math.h>

typedef __attribute__((ext_vector_type(8))) short short8;
typedef __attribute__((ext_vector_type(4))) float float4_t;
typedef __attribute__((ext_vector_type(4))) unsigned short ushort4_t;

#define DEV static __device__ __forceinline__

DEV unsigned short f2b(float f) {
    union { float f; unsigned int u; } x; x.f = f;
    unsigned int r = x.u + 0x7fffu + ((x.u >> 16) & 1u);
    return (unsigned short)(r >> 16);
}
DEV float b2f(unsigned short u) {
    union { unsigned int u; float f; } x; x.u = ((unsigned int)u) << 16;
    return x.f;
}
// gelu(x) = x * sigmoid(2u), u = 0.79788456(x + 0.044715x^3); exp via v_exp_f32
DEV float gelu_f(float x) {
    float u = 0.7978845608028654f * (x + 0.044715f * x * x * x);
    float e = __expf(-2.0f * u);
    return x / (1.0f + e);
}

DEV void gld16(unsigned short* lds, const unsigned short* g) {
    __builtin_amdgcn_global_load_lds(
        (const __attribute__((address_space(1))) unsigned int*)g,
        (__attribute__((address_space(3))) unsigned int*)lds,
        16, 0, 0);
}

// ---------------------------------------------------------------------------
// Tiled transpose + cast: W (K x N, f32) -> WT (N x K, bf16)
// ---------------------------------------------------------------------------
__global__ __launch_bounds__(256) void transpose_cast_kernel(
    const float* __restrict__ W, unsigned short* __restrict__ WT, int Kd, int Nd)
{
    __shared__ float tile[32][33];
    int n0 = blockIdx.x * 32, k0 = blockIdx.y * 32;
    int tx = threadIdx.x & 31, ty = threadIdx.x >> 5;   // 32 x 8
    #pragma unroll
    for (int r = ty; r < 32; r += 8)
        tile[r][tx] = W[(size_t)(k0 + r) * Nd + n0 + tx];
    __syncthreads();
    #pragma unroll
    for (int r = ty; r < 32; r += 8)
        WT[(size_t)(n0 + r) * Kd + k0 + tx] = f2b(tile[tx][r]);
}

// ---------------------------------------------------------------------------
// copy x -> XL (f32), XG (f32), XB (bf16)
// ---------------------------------------------------------------------------
__global__ __launch_bounds__(256) void copy_cast_kernel(
    const float* __restrict__ x, float* __restrict__ xl, float* __restrict__ xg,
    unsigned short* __restrict__ xb, int n)
{
    int i = blockIdx.x * 256 + threadIdx.x;
    if (i < n) { float v = x[i]; xl[i] = v; xg[i] = v; xb[i] = f2b(v); }
}

// ---------------------------------------------------------------------------
// bf16 MFMA GEMM, double-buffered K-loop. OPERAND-SWAPPED MFMA:
// acc = mfma(b_frag, a_frag, acc)  =>  lane holds row = l16 (one C row),
// cols = quad*4 + reg (4 CONSECUTIVE columns) -> vectorized epilogue.
// BN=128: 4 waves 2x2, 64x64/wave (4x4 frags). BN=64: waves stacked on M.
// ---------------------------------------------------------------------------
template<int BN>
__global__ __launch_bounds__(256) void gemm_db_kernel(
    const unsigned short* __restrict__ A,
    const unsigned short* __restrict__ BT,
    const float* __restrict__ bias,
    const float* __restrict__ residual,
    float* __restrict__ Cf,
    unsigned short* __restrict__ Cb,
    int M, int N, int K, int act)
{
    constexpr int NI = (BN == 128) ? 4 : 2;
    __shared__ __align__(16) unsigned short As[2][128 * 32];
    __shared__ __align__(16) unsigned short Bs[2][BN * 32];
    const int tid = threadIdx.x;
    const int wave = tid >> 6, lane = tid & 63;
    const int quad = lane >> 4, l16 = lane & 15;
    const int m0 = blockIdx.x * 128, n0 = blockIdx.y * BN;
    const int wm = (BN == 128) ? (wave >> 1) * 64 : wave * 32;
    const int wn = (BN == 128) ? (wave & 1) * 64 : 0;

    float4_t acc[NI][4] = {};

    const int lrow = lane >> 2;           // 0..15
    const int lcol = (lane & 3) * 8;      // 0,8,16,24 (bf16 elems)
    const int r0 = wave * 16 + lrow;      // staging row, round 0
    const unsigned short* Ag0 = A  + (size_t)(m0 + r0) * K + lcol;
    const unsigned short* Ag1 = A  + (size_t)(m0 + 64 + r0) * K + lcol;
    const unsigned short* Bg0 = BT + (size_t)(n0 + r0) * K + lcol;
    const unsigned short* Bg1 = (BN == 128) ? BT + (size_t)(n0 + 64 + r0) * K + lcol : nullptr;
    const int soff = (wave * 16) * 32 + lane * 8;   // LDS write offset (elems)

    const int iters = K >> 5;
    gld16(&As[0][soff], Ag0);
    gld16(&As[0][soff + 64 * 32], Ag1);
    gld16(&Bs[0][soff], Bg0);
    if (BN == 128) gld16(&Bs[0][soff + 64 * 32], Bg1);
    __syncthreads();

    for (int k = 0; k < iters; k++) {
        const int cur = k & 1;
        if (k + 1 < iters) {
            const int koff = (k + 1) << 5;
            const int nxt = cur ^ 1;
            gld16(&As[nxt][soff], Ag0 + koff);
            gld16(&As[nxt][soff + 64 * 32], Ag1 + koff);
            gld16(&Bs[nxt][soff], Bg0 + koff);
            if (BN == 128) gld16(&Bs[nxt][soff + 64 * 32], Bg1 + koff);
        }
        short8 a[NI], b[4];
        #pragma unroll
        for (int i = 0; i < NI; i++)
            a[i] = *(const short8*)(&As[cur][(wm + i * 16 + l16) * 32 + quad * 8]);
        #pragma unroll
        for (int j = 0; j < 4; j++)
            b[j] = *(const short8*)(&Bs[cur][(wn + j * 16 + l16) * 32 + quad * 8]);
        #pragma unroll
        for (int i = 0; i < NI; i++)
            #pragma unroll
            for (int j = 0; j < 4; j++)
                acc[i][j] = __builtin_amdgcn_mfma_f32_16x16x32_bf16(b[j], a[i], acc[i][j], 0, 0, 0);
        __syncthreads();
    }

    // Epilogue: lane writes row = ...+l16, 4 consecutive cols per frag.
    #pragma unroll
    for (int i = 0; i < NI; i++) {
        const int row = m0 + wm + i * 16 + l16;
        #pragma unroll
        for (int j = 0; j < 4; j++) {
            const int col = n0 + wn + j * 16 + quad * 4;
            const size_t idx = (size_t)row * N + col;
            float4_t v = acc[i][j] + *(const float4_t*)(bias + col);
            if (act == 1) {
                #pragma unroll
                for (int r = 0; r < 4; r++) v[r] = gelu_f(v[r]);
            }
            if (residual) v += *(const float4_t*)(residual + idx);
            if (Cf) *(float4_t*)(Cf + idx) = v;
            if (Cb) {
                ushort4_t o = { f2b(v[0]), f2b(v[1]), f2b(v[2]), f2b(v[3]) };
                *(ushort4_t*)(Cb + idx) = o;
            }
        }
    }
}

// ---------------------------------------------------------------------------
// LayerNorm over D=512. One block (256 thr) per row. Optional f32/bf16 outs.
// ---------------------------------------------------------------------------
__global__ __launch_bounds__(256) void ln_kernel(
    const float* __restrict__ X, const float* __restrict__ g, const float* __restrict__ b,
    float* __restrict__ Yf, unsigned short* __restrict__ Yb)
{
    const int row = blockIdx.x, tid = threadIdx.x;
    const float* xr = X + (size_t)row * 512;
    float v0 = xr[tid], v1 = xr[tid + 256];
    float s = v0 + v1;
    #pragma unroll
    for (int o = 32; o > 0; o >>= 1) s += __shfl_down(s, o);
    __shared__ float red[4];
    __shared__ float stat[2];
    if ((tid & 63) == 0) red[tid >> 6] = s;
    __syncthreads();
    if (tid == 0) stat[0] = (red[0] + red[1] + red[2] + red[3]) * (1.0f / 512.0f);
    __syncthreads();
    float mu = stat[0];
    float d0 = v0 - mu, d1 = v1 - mu;
    float s2 = d0 * d0 + d1 * d1;
    #pragma unroll
    for (int o = 32; o > 0; o >>= 1) s2 += __shfl_down(s2, o);
    if ((tid & 63) == 0) red[tid >> 6] = s2;
    __syncthreads();
    if (tid == 0) stat[1] = rsqrtf((red[0] + red[1] + red[2] + red[3]) * (1.0f / 512.0f) + 1e-5f);
    __syncthreads();
    float rs = stat[1];
    float y0 = d0 * rs * g[tid] + b[tid];
    float y1 = d1 * rs * g[tid + 256] + b[tid + 256];
    if (Yf) { float* yr = Yf + (size_t)row * 512; yr[tid] = y0; yr[tid + 256] = y1; }
    if (Yb) { unsigned short* yb = Yb + (size_t)row * 512; yb[tid] = f2b(y0); yb[tid + 256] = f2b(y1); }
}

// ---------------------------------------------------------------------------
// Fused: v = XG + lin_interp(GA 128->4096);  XG = LN(v); XBg = bf16(XG)
// ---------------------------------------------------------------------------
__global__ __launch_bounds__(256) void interp_ln_kernel(
    const float* __restrict__ GA, float* __restrict__ XG,
    const float* __restrict__ g, const float* __restrict__ b,
    unsigned short* __restrict__ Yb)
{
    const int row = blockIdx.x, tid = threadIdx.x;
    const int bb = row >> 12, s = row & 4095;
    float pos = (s + 0.5f) * (128.0f / 4096.0f) - 0.5f;
    pos = fminf(fmaxf(pos, 0.0f), 127.0f);
    int i0 = (int)floorf(pos);
    int i1 = min(i0 + 1, 127);
    float w = pos - (float)i0;
    const float* ga0 = GA + ((size_t)bb * 128 + i0) * 512;
    const float* ga1 = GA + ((size_t)bb * 128 + i1) * 512;
    float* xr = XG + (size_t)row * 512;
    float v0 = xr[tid]       + ga0[tid]       * (1.0f - w) + ga1[tid]       * w;
    float v1 = xr[tid + 256] + ga0[tid + 256] * (1.0f - w) + ga1[tid + 256] * w;
    float sm = v0 + v1;
    #pragma unroll
    for (int o = 32; o > 0; o >>= 1) sm += __shfl_down(sm, o);
    __shared__ float red[4];
    __shared__ float stat[2];
    if ((tid & 63) == 0) red[tid >> 6] = sm;
    __syncthreads();
    if (tid == 0) stat[0] = (red[0] + red[1] + red[2] + red[3]) * (1.0f / 512.0f);
    __syncthreads();
    float mu = stat[0];
    float d0 = v0 - mu, d1 = v1 - mu;
    float s2 = d0 * d0 + d1 * d1;
    #pragma unroll
    for (int o = 32; o > 0; o >>= 1) s2 += __shfl_down(s2, o);
    if ((tid & 63) == 0) red[tid >> 6] = s2;
    __syncthreads();
    if (tid == 0) stat[1] = rsqrtf((red[0] + red[1] + red[2] + red[3]) * (1.0f / 512.0f) + 1e-5f);
    __syncthreads();
    float rs = stat[1];
    float y0 = d0 * rs * g[tid] + b[tid];
    float y1 = d1 * rs * g[tid + 256] + b[tid + 256];
    xr[tid] = y0;           xr[tid + 256] = y1;
    unsigned short* yb = Yb + (size_t)row * 512;
    yb[tid] = f2b(y0);      yb[tid + 256] = f2b(y1);
}

// ---------------------------------------------------------------------------
// Local windowed attention. One block per (b, window, head). W=32, HD=64.
// k padded to [32][65]: bank = (j+d) mod 32, kills the 32-way conflict in QK.
// ---------------------------------------------------------------------------
__global__ __launch_bounds__(256) void local_attn_kernel(
    const unsigned short* __restrict__ QKV, const float* __restrict__ rel,
    unsigned short* __restrict__ OUT)
{
    const int blk = blockIdx.x;          // (b*128 + win)*8 + h
    const int h = blk & 7;
    const int win = (blk >> 3) & 127;
    const int b = blk >> 10;
    const int rowbase = b * 4096 + win * 32;
    __shared__ float q[32][64], k[32][65], v[32][64];
    __shared__ float sc[32][33];
    const int tid = threadIdx.x;
    for (int idx = tid; idx < 2048; idx += 256) {
        int i = idx >> 6, d = idx & 63;
        const unsigned short* base = QKV + (size_t)(rowbase + i) * 1536 + h * 64 + d;
        q[i][d] = b2f(base[0]);
        k[i][d] = b2f(base[512]);
        v[i][d] = b2f(base[1024]);
    }
    __syncthreads();
    for (int idx = tid; idx < 1024; idx += 256) {
        int i = idx >> 5, j = idx & 31;
        float s = 0.f;
        #pragma unroll
        for (int d = 0; d < 64; d++) s += q[i][d] * k[j][d];
        sc[i][j] = s * 0.125f + rel[(i - j + 31) * 8 + h];
    }
    __syncthreads();
    if (tid < 32) {
        float mx = -1e30f;
        for (int j = 0; j < 32; j++) mx = fmaxf(mx, sc[tid][j]);
        float sum = 0.f;
        for (int j = 0; j < 32; j++) { float e = __expf(sc[tid][j] - mx); sc[tid][j] = e; sum += e; }
        float inv = 1.0f / sum;
        for (int j = 0; j < 32; j++) sc[tid][j] *= inv;
    }
    __syncthreads();
    for (int idx = tid; idx < 2048; idx += 256) {
        int i = idx >> 6, d = idx & 63;
        float o = 0.f;
        #pragma unroll
        for (int j = 0; j < 32; j++) o += sc[i][j] * v[j][d];
        OUT[(size_t)(rowbase + i) * 512 + h * 64 + d] = f2b(o);
    }
}

// ---------------------------------------------------------------------------
// Gather strided tokens for global attention
// ---------------------------------------------------------------------------
__global__ __launch_bounds__(256) void gather_xs_kernel(
    const float* __restrict__ XG, unsigned short* __restrict__ XSB)
{
    int i = blockIdx.x * 256 + threadIdx.x;   // 4*128*512 = 262144
    if (i < 262144) {
        int d = i & 511, t = (i >> 9) & 127, b = i >> 16;
        XSB[i] = f2b(XG[((size_t)b * 4096 + t * 32) * 512 + d]);
    }
}

// ---------------------------------------------------------------------------
// Global attention on 128 tokens/batch. Block per (b, h, qtile of 32).
// ---------------------------------------------------------------------------
__global__ __launch_bounds__(256) void global_attn_kernel(
    const unsigned short* __restrict__ GQKV, unsigned short* __restrict__ GOUT)
{
    const int blk = blockIdx.x;       // b*32 + h*4 + qt
    const int qt = blk & 3, h = (blk >> 2) & 7, b = blk >> 5;
    __shared__ unsigned short ks[128 * 64], vs[128 * 64];
    __shared__ float qs[32 * 64];
    __shared__ float sc[32 * 128];
    const int tid = threadIdx.x;
    for (int idx = tid; idx < 128 * 64; idx += 256) {
        int j = idx >> 6, d = idx & 63;
        const unsigned short* rowp = GQKV + (size_t)(b * 128 + j) * 1536 + h * 64 + d;
        ks[idx] = rowp[512];
        vs[idx] = rowp[1024];
    }
    for (int idx = tid; idx < 32 * 64; idx += 256) {
        int i = idx >> 6, d = idx & 63;
        qs[idx] = b2f(GQKV[(size_t)(b * 128 + qt * 32 + i) * 1536 + h * 64 + d]);
    }
    __syncthreads();
    for (int idx = tid; idx < 32 * 128; idx += 256) {
        int i = idx >> 7, j = idx & 127;
        float s = 0.f;
        #pragma unroll
        for (int d = 0; d < 64; d++) s += qs[i * 64 + d] * b2f(ks[j * 64 + d]);
        sc[idx] = s * 0.125f;
    }
    __syncthreads();
    if (tid < 32) {
        float mx = -1e30f;
        for (int j = 0; j < 128; j++) mx = fmaxf(mx, sc[tid * 128 + j]);
        float sum = 0.f;
        for (int j = 0; j < 128; j++) { float e = __expf(sc[tid * 128 + j] - mx); sc[tid * 128 + j] = e; sum += e; }
        float inv = 1.0f / sum;
        for (int j = 0; j < 128; j++) sc[tid * 128 + j] *= inv;
    }
    __syncthreads();
    for (int idx = tid; idx < 32 * 64; idx += 256) {
        int i = idx >> 6, d = idx & 63;
        float o = 0.f;
        for (int j = 0; j < 128; j++) o += sc[i * 128 + j] * b2f(vs[j * 64 + d]);
        GOUT[(size_t)(b * 128 + qt * 32 + i) * 512 + h * 64 + d] = f2b(o);
    }
}

// ---------------------------------------------------------------------------
// Y = X + dwconv(X) (K=7, zero pad). float4-vectorized. Writes f32 + bf16.
// ---------------------------------------------------------------------------
__global__ __launch_bounds__(256) void dwconv_add_kernel(
    const float* __restrict__ X, const float* __restrict__ wconv, const float* __restrict__ bconv,
    float* __restrict__ Yf, unsigned short* __restrict__ Yb)
{
    int i = blockIdx.x * 256 + threadIdx.x;   // over nel/4 = 2097152
    if (i < 2097152) {
        int dv = (i & 127) * 4;
        int s = (i >> 7) & 4095;
        int b = i >> 19;
        float4_t acc = *(const float4_t*)(bconv + dv);
        #pragma unroll
        for (int t = 0; t < 7; t++) {
            int ss = s + t - 3;
            if (ss >= 0 && ss < 4096) {
                float4_t xv = *(const float4_t*)(X + ((size_t)b * 4096 + ss) * 512 + dv);
                float4_t wv = { wconv[dv * 7 + t], wconv[(dv + 1) * 7 + t],
                                wconv[(dv + 2) * 7 + t], wconv[(dv + 3) * 7 + t] };
                acc += xv * wv;
            }
        }
        size_t e = (size_t)i * 4;
        float4_t v = *(const float4_t*)(X + e) + acc;
        *(float4_t*)(Yf + e) = v;
        ushort4_t o = { f2b(v[0]), f2b(v[1]), f2b(v[2]), f2b(v[3]) };
        *(ushort4_t*)(Yb + e) = o;
    }
}

// ---------------------------------------------------------------------------
// out = LN(w0*XL + w1*XG) with softmaxed scalar weights
// ---------------------------------------------------------------------------
__global__ __launch_bounds__(256) void final_kernel(
    const float* __restrict__ XL, const float* __restrict__ XG,
    const float* __restrict__ fwl, const float* __restrict__ fwg,
    const float* __restrict__ g, const float* __restrict__ bb, float* __restrict__ out)
{
    const int row = blockIdx.x, tid = threadIdx.x;
    float a = fwl[0], c = fwg[0];
    float m = fmaxf(a, c);
    float ea = __expf(a - m), ec = __expf(c - m);
    float w0 = ea / (ea + ec), w1 = ec / (ea + ec);
    const float* xlr = XL + (size_t)row * 512;
    const float* xgr = XG + (size_t)row * 512;
    float v0 = w0 * xlr[tid] + w1 * xgr[tid];
    float v1 = w0 * xlr[tid + 256] + w1 * xgr[tid + 256];
    float s = v0 + v1;
    #pragma unroll
    for (int o = 32; o > 0; o >>= 1) s += __shfl_down(s, o);
    __shared__ float red[4];
    __shared__ float stat[2];
    if ((tid & 63) == 0) red[tid >> 6] = s;
    __syncthreads();
    if (tid == 0) stat[0] = (red[0] + red[1] + red[2] + red[3]) * (1.0f / 512.0f);
    __syncthreads();
    float mu = stat[0];
    float d0 = v0 - mu, d1 = v1 - mu;
    float s2 = d0 * d0 + d1 * d1;
    #pragma unroll
    for (int o = 32; o > 0; o >>= 1) s2 += __shfl_down(s2, o);
    if ((tid & 63) == 0) red[tid >> 6] = s2;
    __syncthreads();
    if (tid == 0) stat[1] = rsqrtf((red[0] + red[1] + red[2] + red[3]) * (1.0f / 512.0f) + 1e-5f);
    __syncthreads();
    float rs = stat[1];
    float* orow = out + (size_t)row * 512;
    orow[tid]       = d0 * rs * g[tid] + bb[tid];
    orow[tid + 256] = d1 * rs * g[tid + 256] + bb[tid + 256];
}

// ---------------------------------------------------------------------------
extern "C" void kernel_launch(void* const* d_in, const int* in_sizes, int n_in,
                              void* d_out, int out_size, void* d_ws, size_t ws_size,
                              hipStream_t stream)
{
    (void)in_sizes; (void)n_in; (void)out_size; (void)ws_size;
    const float* x       = (const float*)d_in[0];
    const float* lqkv_w  = (const float*)d_in[1];
    const float* lqkv_b  = (const float*)d_in[2];
    const float* lproj_w = (const float*)d_in[3];
    const float* lproj_b = (const float*)d_in[4];
    const float* lrel    = (const float*)d_in[5];
    const float* lconv_w = (const float*)d_in[6];
    const float* lconv_b = (const float*)d_in[7];
    const float* ln1_g   = (const float*)d_in[8];
    const float* ln1_b   = (const float*)d_in[9];
    const float* lffn_w1 = (const float*)d_in[10];
    const float* lffn_b1 = (const float*)d_in[11];
    const float* lffn_w2 = (const float*)d_in[12];
    const float* lffn_b2 = (const float*)d_in[13];
    const float* ln2_g   = (const float*)d_in[14];
    const float* ln2_b   = (const float*)d_in[15];
    const float* gqkv_w  = (const float*)d_in[16];
    const float* gqkv_b  = (const float*)d_in[17];
    const float* gproj_w = (const float*)d_in[18];
    const float* gproj_b = (const float*)d_in[19];
    const float* gn1_g   = (const float*)d_in[20];
    const float* gn1_b   = (const float*)d_in[21];
    const float* gffn_w1 = (const float*)d_in[22];
    const float* gffn_b1 = (const float*)d_in[23];
    const float* gffn_w2 = (const float*)d_in[24];
    const float* gffn_b2 = (const float*)d_in[25];
    const float* gn2_g   = (const float*)d_in[26];
    const float* gn2_b   = (const float*)d_in[27];
    const float* fw_local  = (const float*)d_in[28];
    const float* fw_global = (const float*)d_in[29];
    const float* fn_g    = (const float*)d_in[30];
    const float* fn_b    = (const float*)d_in[31];
    float* out = (float*)d_out;

    const int Btot = 4 * 4096;     // 16384 token rows
    const int nel = Btot * 512;    // 8388608

    char* wsb = (char*)d_ws;
    size_t off = 0;
    auto alloc = [&](size_t bytes) -> void* {
        void* p = wsb + off;
        off = (off + bytes + 255) & ~(size_t)255;
        return p;
    };
    float*          XL   = (float*)alloc((size_t)nel * 4);
    float*          XG   = (float*)alloc((size_t)nel * 4);
    float*          TMP  = (float*)alloc((size_t)nel * 4);
    unsigned short* XBl  = (unsigned short*)alloc((size_t)nel * 2);
    unsigned short* XBg  = (unsigned short*)alloc((size_t)nel * 2);
    unsigned short* AOUT = (unsigned short*)alloc((size_t)nel * 2);
    unsigned short* BIG  = (unsigned short*)alloc((size_t)Btot * 2048 * 2);
    unsigned short* WT   = (unsigned short*)alloc((size_t)22020096 * 2);
    unsigned short* XSB  = (unsigned short*)alloc((size_t)512 * 512 * 2);
    unsigned short* GQKV = (unsigned short*)alloc((size_t)512 * 1536 * 2);
    unsigned short* GOUT = (unsigned short*)alloc((size_t)512 * 512 * 2);
    float*          GA   = (float*)alloc((size_t)512 * 512 * 4);

    const size_t perL = 3145728;   // bf16 elems of transposed weights per layer
    auto transpose = [&](const float* W_, unsigned short* WT_, int Kd, int Nd) {
        dim3 g(Nd / 32, Kd / 32);
        transpose_cast_kernel<<<g, dim3(256), 0, stream>>>(W_, WT_, Kd, Nd);
    };
    for (int i = 0; i < 4; i++) {
        unsigned short* base = WT + (size_t)i * perL;
        transpose(lqkv_w  + (size_t)i * 512 * 1536, base,                         512, 1536);
        transpose(lproj_w + (size_t)i * 512 * 512,  base + 786432,                512, 512);
        transpose(lffn_w1 + (size_t)i * 512 * 2048, base + 786432 + 262144,       512, 2048);
        transpose(lffn_w2 + (size_t)i * 2048 * 512, base + 786432 + 262144 + 1048576, 2048, 512);
    }
    for (int i = 0; i < 3; i++) {
        unsigned short* base = WT + (size_t)(4 + i) * perL;
        transpose(gqkv_w  + (size_t)i * 512 * 1536, base,                         512, 1536);
        transpose(gproj_w + (size_t)i * 512 * 512,  base + 786432,                512, 512);
        transpose(gffn_w1 + (size_t)i * 512 * 2048, base + 786432 + 262144,       512, 2048);
        transpose(gffn_w2 + (size_t)i * 2048 * 512, base + 786432 + 262144 + 1048576, 2048, 512);
    }

    copy_cast_kernel<<<dim3(nel / 256), dim3(256), 0, stream>>>(x, XL, XG, XBl, nel);

    auto gemm = [&](const unsigned short* A_, const unsigned short* BT_, const float* bias_,
                    const float* res_, float* Cf_, unsigned short* Cb_,
                    int M_, int N_, int K_, int act_) {
        if (N_ >= 1024) {
            dim3 g(M_ / 128, N_ / 128);
            gemm_db_kernel<128><<<g, dim3(256), 0, stream>>>(A_, BT_, bias_, res_, Cf_, Cb_, M_, N_, K_, act_);
        } else {
            dim3 g(M_ / 128, N_ / 64);
            gemm_db_kernel<64><<<g, dim3(256), 0, stream>>>(A_, BT_, bias_, res_, Cf_, Cb_, M_, N_, K_, act_);
        }
    };

    // ---------------- local branch: 4 layers ----------------
    for (int i = 0; i < 4; i++) {
        unsigned short* base  = WT + (size_t)i * perL;
        unsigned short* qkvT  = base;
        unsigned short* projT = base + 786432;
        unsigned short* w1T   = base + 786432 + 262144;
        unsigned short* w2T   = base + 786432 + 262144 + 1048576;

        gemm(XBl, qkvT, lqkv_b + i * 1536, nullptr, nullptr, BIG, Btot, 1536, 512, 0);
        local_attn_kernel<<<dim3(4096), dim3(256), 0, stream>>>(BIG, lrel + (size_t)i * 63 * 8, AOUT);
        gemm(AOUT, projT, lproj_b + i * 512, XL, TMP, nullptr, Btot, 512, 512, 0);
        ln_kernel<<<dim3(Btot), dim3(256), 0, stream>>>(TMP, ln1_g + i * 512, ln1_b + i * 512, XL, (unsigned short*)nullptr);
        dwconv_add_kernel<<<dim3(nel / 1024), dim3(256), 0, stream>>>(XL, lconv_w + (size_t)i * 512 * 7, lconv_b + i * 512, TMP, XBl);
        gemm(XBl, w1T, lffn_b1 + i * 2048, nullptr, nullptr, BIG, Btot, 2048, 512, 1);
        gemm(BIG, w2T, lffn_b2 + i * 512, TMP, TMP, nullptr, Btot, 512, 2048, 0);
        ln_kernel<<<dim3(Btot), dim3(256), 0, stream>>>(TMP, ln2_g + i * 512, ln2_b + i * 512, XL, XBl);
    }

    // ---------------- global branch: 3 layers ----------------
    for (int i = 0; i < 3; i++) {
        unsigned short* base  = WT + (size_t)(4 + i) * perL;
        unsigned short* qkvT  = base;
        unsigned short* projT = base + 786432;
        unsigned short* w1T   = base + 786432 + 262144;
        unsigned short* w2T   = base + 786432 + 262144 + 1048576;

        gather_xs_kernel<<<dim3(1024), dim3(256), 0, stream>>>(XG, XSB);
        gemm(XSB, qkvT, gqkv_b + i * 1536, nullptr, nullptr, GQKV, 512, 1536, 512, 0);
        global_attn_kernel<<<dim3(128), dim3(256), 0, stream>>>(GQKV, GOUT);
        gemm(GOUT, projT, gproj_b + i * 512, nullptr, GA, nullptr, 512, 512, 512, 0);
        interp_ln_kernel<<<dim3(Btot), dim3(256), 0, stream>>>(GA, XG, gn1_g + i * 512, gn1_b + i * 512, XBg);
        gemm(XBg, w1T, gffn_b1 + i * 2048, nullptr, nullptr, BIG, Btot, 2048, 512, 1);
        gemm(BIG, w2T, gffn_b2 + i * 512, XG, TMP, nullptr, Btot, 512, 2048, 0);
        ln_kernel<<<dim3(Btot), dim3(256), 0, stream>>>(TMP, gn2_g + i * 512, gn2_b + i * 512, XG, XBg);
    }

    final_kernel<<<dim3(Btot), dim3(256), 0, stream>>>(XL, XG, fw_local, fw_global, fn_g, fn_b, out);
}

// Round 6
// 2062.068 us; speedup vs baseline: 1.3479x; 1.0893x over previous
//
#include <hip/hip_runtime.h>
#include <hip/hip_bf16.h>
#include <math.h>

typedef __attribute__((ext_vector_type(8))) short short8;
typedef __attribute__((ext_vector_type(4))) float float4_t;
typedef __attribute__((ext_vector_type(4))) unsigned int uint4_t;
typedef __attribute__((ext_vector_type(2))) unsigned int uint2_t;

#define DEV static __device__ __forceinline__

DEV unsigned short f2b(float f) {
    union { float f; unsigned int u; } x; x.f = f;
    unsigned int r = x.u + 0x7fffu + ((x.u >> 16) & 1u);
    return (unsigned short)(r >> 16);
}
DEV float b2f(unsigned short u) {
    union { unsigned int u; float f; } x; x.u = ((unsigned int)u) << 16;
    return x.f;
}
// packed 2x f32 -> 2x bf16 (v_cvt_pk_bf16_f32 on gfx950, RNE)
DEV unsigned int f2b2(float lo, float hi) {
    union { __hip_bfloat162 h; unsigned int u; } c;
    c.h = __float22bfloat162_rn(make_float2(lo, hi));
    return c.u;
}
// gelu(x) = x / (1 + 2^(a*x + b*x^3));  a = -2*0.7978845608*log2(e)
DEV float gelu_f(float x) {
    const float a = -2.3022082f, b = -0.10294372f;
    float x2 = x * x;
    float p = __builtin_fmaf(x2, b, a);          // a + b*x^2
    float e = __builtin_amdgcn_exp2f(p * x);     // 2^(a x + b x^3)
    return x * __builtin_amdgcn_rcpf(1.0f + e);
}

DEV void gld16(unsigned short* lds, const unsigned short* g) {
    __builtin_amdgcn_global_load_lds(
        (const __attribute__((address_space(1))) unsigned int*)g,
        (__attribute__((address_space(3))) unsigned int*)lds,
        16, 0, 0);
}

// ---------------------------------------------------------------------------
// Batched tiled transpose + cast: W[z] (K x N, f32) -> WT[z] (N x K, bf16)
// z in [0, 7): z<nl -> local weights, else global. dst = dst0 + z*perL.
// ---------------------------------------------------------------------------
__global__ __launch_bounds__(256) void transpose_cast_batch_kernel(
    const float* __restrict__ srcL, const float* __restrict__ srcG, int nl,
    unsigned short* __restrict__ dst0, size_t perL, int Kd, int Nd)
{
    const int z = blockIdx.z;
    const float* W = (z < nl) ? srcL + (size_t)z * Kd * Nd
                              : srcG + (size_t)(z - nl) * Kd * Nd;
    unsigned short* WT = dst0 + (size_t)z * perL;
    __shared__ float tile[32][33];
    int n0 = blockIdx.x * 32, k0 = blockIdx.y * 32;
    int tx = threadIdx.x & 31, ty = threadIdx.x >> 5;   // 32 x 8
    #pragma unroll
    for (int r = ty; r < 32; r += 8)
        tile[r][tx] = W[(size_t)(k0 + r) * Nd + n0 + tx];
    __syncthreads();
    #pragma unroll
    for (int r = ty; r < 32; r += 8)
        WT[(size_t)(n0 + r) * Kd + k0 + tx] = f2b(tile[tx][r]);
}

// ---------------------------------------------------------------------------
// copy x -> XL (f32), XG (f32), XB (bf16), float4-vectorized
// ---------------------------------------------------------------------------
__global__ __launch_bounds__(256) void copy_cast_kernel(
    const float* __restrict__ x, float* __restrict__ xl, float* __restrict__ xg,
    unsigned short* __restrict__ xb, int n4)
{
    int i = blockIdx.x * 256 + threadIdx.x;
    if (i < n4) {
        float4_t v = ((const float4_t*)x)[i];
        ((float4_t*)xl)[i] = v;
        ((float4_t*)xg)[i] = v;
        uint2_t p = { f2b2(v[0], v[1]), f2b2(v[2], v[3]) };
        ((uint2_t*)xb)[i] = p;
    }
}

// ---------------------------------------------------------------------------
// bf16 MFMA GEMM, double-buffered K-loop, operand-swapped MFMA (row-major
// vectorized epilogue). BN=128: 4 waves 2x2, 64x64/wave. BN=64: stacked on M.
// ---------------------------------------------------------------------------
template<int BN>
__global__ __launch_bounds__(256, 3) void gemm_db_kernel(
    const unsigned short* __restrict__ A,
    const unsigned short* __restrict__ BT,
    const float* __restrict__ bias,
    const float* __restrict__ residual,
    float* __restrict__ Cf,
    unsigned short* __restrict__ Cb,
    int M, int N, int K, int act)
{
    constexpr int NI = (BN == 128) ? 4 : 2;
    __shared__ __align__(16) unsigned short As[2][128 * 32];
    __shared__ __align__(16) unsigned short Bs[2][BN * 32];
    const int tid = threadIdx.x;
    const int wave = tid >> 6, lane = tid & 63;
    const int quad = lane >> 4, l16 = lane & 15;
    const int m0 = blockIdx.x * 128, n0 = blockIdx.y * BN;
    const int wm = (BN == 128) ? (wave >> 1) * 64 : wave * 32;
    const int wn = (BN == 128) ? (wave & 1) * 64 : 0;

    float4_t acc[NI][4] = {};

    const int lrow = lane >> 2;
    const int lcol = (lane & 3) * 8;
    const int r0 = wave * 16 + lrow;
    const unsigned short* Ag0 = A  + (size_t)(m0 + r0) * K + lcol;
    const unsigned short* Ag1 = A  + (size_t)(m0 + 64 + r0) * K + lcol;
    const unsigned short* Bg0 = BT + (size_t)(n0 + r0) * K + lcol;
    const unsigned short* Bg1 = (BN == 128) ? BT + (size_t)(n0 + 64 + r0) * K + lcol : nullptr;
    const int soff = (wave * 16) * 32 + lane * 8;

    const int iters = K >> 5;
    gld16(&As[0][soff], Ag0);
    gld16(&As[0][soff + 64 * 32], Ag1);
    gld16(&Bs[0][soff], Bg0);
    if (BN == 128) gld16(&Bs[0][soff + 64 * 32], Bg1);
    __syncthreads();

    for (int k = 0; k < iters; k++) {
        const int cur = k & 1;
        if (k + 1 < iters) {
            const int koff = (k + 1) << 5;
            const int nxt = cur ^ 1;
            gld16(&As[nxt][soff], Ag0 + koff);
            gld16(&As[nxt][soff + 64 * 32], Ag1 + koff);
            gld16(&Bs[nxt][soff], Bg0 + koff);
            if (BN == 128) gld16(&Bs[nxt][soff + 64 * 32], Bg1 + koff);
        }
        short8 a[NI], b[4];
        #pragma unroll
        for (int i = 0; i < NI; i++)
            a[i] = *(const short8*)(&As[cur][(wm + i * 16 + l16) * 32 + quad * 8]);
        #pragma unroll
        for (int j = 0; j < 4; j++)
            b[j] = *(const short8*)(&Bs[cur][(wn + j * 16 + l16) * 32 + quad * 8]);
        #pragma unroll
        for (int i = 0; i < NI; i++)
            #pragma unroll
            for (int j = 0; j < 4; j++)
                acc[i][j] = __builtin_amdgcn_mfma_f32_16x16x32_bf16(b[j], a[i], acc[i][j], 0, 0, 0);
        __syncthreads();
    }

    #pragma unroll
    for (int i = 0; i < NI; i++) {
        const int row = m0 + wm + i * 16 + l16;
        #pragma unroll
        for (int j = 0; j < 4; j++) {
            const int col = n0 + wn + j * 16 + quad * 4;
            const size_t idx = (size_t)row * N + col;
            float4_t v = acc[i][j] + *(const float4_t*)(bias + col);
            if (act == 1) {
                #pragma unroll
                for (int r = 0; r < 4; r++) v[r] = gelu_f(v[r]);
            }
            if (residual) v += *(const float4_t*)(residual + idx);
            if (Cf) *(float4_t*)(Cf + idx) = v;
            if (Cb) {
                uint2_t o = { f2b2(v[0], v[1]), f2b2(v[2], v[3]) };
                *(uint2_t*)(Cb + idx) = o;
            }
        }
    }
}

// ---------------------------------------------------------------------------
// LayerNorm over D=512, one WAVE per row (no barriers). 4 rows/block.
// ---------------------------------------------------------------------------
__global__ __launch_bounds__(256) void ln_kernel(
    const float* __restrict__ X, const float* __restrict__ g, const float* __restrict__ b,
    float* __restrict__ Yf, unsigned short* __restrict__ Yb)
{
    const int row = blockIdx.x * 4 + (threadIdx.x >> 6);
    const int lane = threadIdx.x & 63;
    const float* xr = X + (size_t)row * 512 + lane * 8;
    float4_t v0 = *(const float4_t*)(xr);
    float4_t v1 = *(const float4_t*)(xr + 4);
    float s = v0[0] + v0[1] + v0[2] + v0[3] + v1[0] + v1[1] + v1[2] + v1[3];
    #pragma unroll
    for (int m = 32; m > 0; m >>= 1) s += __shfl_xor(s, m);
    float mu = s * (1.0f / 512.0f);
    float4_t d0 = v0 - mu, d1 = v1 - mu;
    float s2 = d0[0]*d0[0] + d0[1]*d0[1] + d0[2]*d0[2] + d0[3]*d0[3]
             + d1[0]*d1[0] + d1[1]*d1[1] + d1[2]*d1[2] + d1[3]*d1[3];
    #pragma unroll
    for (int m = 32; m > 0; m >>= 1) s2 += __shfl_xor(s2, m);
    float rs = rsqrtf(s2 * (1.0f / 512.0f) + 1e-5f);
    float4_t g0 = *(const float4_t*)(g + lane * 8);
    float4_t g1 = *(const float4_t*)(g + lane * 8 + 4);
    float4_t b0 = *(const float4_t*)(b + lane * 8);
    float4_t b1 = *(const float4_t*)(b + lane * 8 + 4);
    float4_t y0 = d0 * rs * g0 + b0;
    float4_t y1 = d1 * rs * g1 + b1;
    if (Yf) {
        float* yr = Yf + (size_t)row * 512 + lane * 8;
        *(float4_t*)(yr) = y0;
        *(float4_t*)(yr + 4) = y1;
    }
    if (Yb) {
        uint4_t pk = { f2b2(y0[0], y0[1]), f2b2(y0[2], y0[3]),
                       f2b2(y1[0], y1[1]), f2b2(y1[2], y1[3]) };
        *(uint4_t*)(Yb + (size_t)row * 512 + lane * 8) = pk;
    }
}

// ---------------------------------------------------------------------------
// Fused: v = XG + lin_interp(GA 128->4096); XG = LN(v); XBg = bf16. Wave/row.
// ---------------------------------------------------------------------------
__global__ __launch_bounds__(256) void interp_ln_kernel(
    const float* __restrict__ GA, float* __restrict__ XG,
    const float* __restrict__ g, const float* __restrict__ b,
    unsigned short* __restrict__ Yb)
{
    const int row = blockIdx.x * 4 + (threadIdx.x >> 6);
    const int lane = threadIdx.x & 63;
    const int bb = row >> 12, sfull = row & 4095;
    float pos = (sfull + 0.5f) * (128.0f / 4096.0f) - 0.5f;
    pos = fminf(fmaxf(pos, 0.0f), 127.0f);
    int i0 = (int)floorf(pos);
    int i1 = min(i0 + 1, 127);
    float w = pos - (float)i0;
    const float* ga0 = GA + ((size_t)bb * 128 + i0) * 512 + lane * 8;
    const float* ga1 = GA + ((size_t)bb * 128 + i1) * 512 + lane * 8;
    float* xr = XG + (size_t)row * 512 + lane * 8;
    float4_t v0 = *(const float4_t*)(xr)     + *(const float4_t*)(ga0)     * (1.0f - w) + *(const float4_t*)(ga1)     * w;
    float4_t v1 = *(const float4_t*)(xr + 4) + *(const float4_t*)(ga0 + 4) * (1.0f - w) + *(const float4_t*)(ga1 + 4) * w;
    float s = v0[0] + v0[1] + v0[2] + v0[3] + v1[0] + v1[1] + v1[2] + v1[3];
    #pragma unroll
    for (int m = 32; m > 0; m >>= 1) s += __shfl_xor(s, m);
    float mu = s * (1.0f / 512.0f);
    float4_t d0 = v0 - mu, d1 = v1 - mu;
    float s2 = d0[0]*d0[0] + d0[1]*d0[1] + d0[2]*d0[2] + d0[3]*d0[3]
             + d1[0]*d1[0] + d1[1]*d1[1] + d1[2]*d1[2] + d1[3]*d1[3];
    #pragma unroll
    for (int m = 32; m > 0; m >>= 1) s2 += __shfl_xor(s2, m);
    float rs = rsqrtf(s2 * (1.0f / 512.0f) + 1e-5f);
    float4_t g0 = *(const float4_t*)(g + lane * 8);
    float4_t g1 = *(const float4_t*)(g + lane * 8 + 4);
    float4_t b0 = *(const float4_t*)(b + lane * 8);
    float4_t b1 = *(const float4_t*)(b + lane * 8 + 4);
    float4_t y0 = d0 * rs * g0 + b0;
    float4_t y1 = d1 * rs * g1 + b1;
    *(float4_t*)(xr) = y0;
    *(float4_t*)(xr + 4) = y1;
    uint4_t pk = { f2b2(y0[0], y0[1]), f2b2(y0[2], y0[3]),
                   f2b2(y1[0], y1[1]), f2b2(y1[2], y1[3]) };
    *(uint4_t*)(Yb + (size_t)row * 512 + lane * 8) = pk;
}

// ---------------------------------------------------------------------------
// Local windowed attention. Block per (b, win, h). short8 loads, 256-thread
// softmax (8 lanes/row), packed 16B output stores. k padded [32][65].
// ---------------------------------------------------------------------------
__global__ __launch_bounds__(256) void local_attn_kernel(
    const unsigned short* __restrict__ QKV, const float* __restrict__ rel,
    unsigned short* __restrict__ OUT)
{
    const int blk = blockIdx.x;          // (b*128 + win)*8 + h
    const int h = blk & 7;
    const int win = (blk >> 3) & 127;
    const int b = blk >> 10;
    const int rowbase = b * 4096 + win * 32;
    __shared__ float q[32][64], k[32][65], v[32][64];
    __shared__ float sc[32][33];
    const int tid = threadIdx.x;
    const int i = tid >> 3, c = tid & 7;     // row 0..31, chunk 0..7
    {
        const unsigned short* base = QKV + (size_t)(rowbase + i) * 1536 + h * 64 + c * 8;
        short8 qv = *(const short8*)(base);
        short8 kv = *(const short8*)(base + 512);
        short8 vv = *(const short8*)(base + 1024);
        #pragma unroll
        for (int r = 0; r < 8; r++) {
            q[i][c * 8 + r] = b2f((unsigned short)qv[r]);
            k[i][c * 8 + r] = b2f((unsigned short)kv[r]);
            v[i][c * 8 + r] = b2f((unsigned short)vv[r]);
        }
    }
    __syncthreads();
    #pragma unroll
    for (int p = 0; p < 4; p++) {
        int idx = tid + p * 256;
        int si = idx >> 5, sj = idx & 31;
        float s = 0.f;
        #pragma unroll
        for (int d = 0; d < 64; d++) s += q[si][d] * k[sj][d];
        sc[si][sj] = s * 0.125f + rel[(si - sj + 31) * 8 + h];
    }
    __syncthreads();
    {
        const int j0 = c * 4;
        float a0 = sc[i][j0], a1 = sc[i][j0 + 1], a2 = sc[i][j0 + 2], a3 = sc[i][j0 + 3];
        float mx = fmaxf(fmaxf(a0, a1), fmaxf(a2, a3));
        #pragma unroll
        for (int m = 1; m < 8; m <<= 1) mx = fmaxf(mx, __shfl_xor(mx, m));
        float e0 = __expf(a0 - mx), e1 = __expf(a1 - mx), e2 = __expf(a2 - mx), e3 = __expf(a3 - mx);
        float sum = e0 + e1 + e2 + e3;
        #pragma unroll
        for (int m = 1; m < 8; m <<= 1) sum += __shfl_xor(sum, m);
        float inv = 1.0f / sum;
        sc[i][j0] = e0 * inv; sc[i][j0 + 1] = e1 * inv; sc[i][j0 + 2] = e2 * inv; sc[i][j0 + 3] = e3 * inv;
    }
    __syncthreads();
    float o[8] = {};
    #pragma unroll
    for (int j = 0; j < 32; j++) {
        float a = sc[i][j];
        #pragma unroll
        for (int r = 0; r < 8; r++) o[r] += a * v[j][c * 8 + r];
    }
    uint4_t pk = { f2b2(o[0], o[1]), f2b2(o[2], o[3]), f2b2(o[4], o[5]), f2b2(o[6], o[7]) };
    *(uint4_t*)(OUT + (size_t)(rowbase + i) * 512 + h * 64 + c * 8) = pk;
}

// ---------------------------------------------------------------------------
// Gather strided tokens for global attention (float4 + packed cvt)
// ---------------------------------------------------------------------------
__global__ __launch_bounds__(256) void gather_xs_kernel(
    const float* __restrict__ XG, unsigned short* __restrict__ XSB)
{
    int i = blockIdx.x * 256 + threadIdx.x;   // 65536 = 262144/4
    if (i < 65536) {
        int dv = (i & 127) * 4, t = (i >> 7) & 127, b = i >> 14;
        float4_t v = *(const float4_t*)(XG + ((size_t)b * 4096 + t * 32) * 512 + dv);
        uint2_t p = { f2b2(v[0], v[1]), f2b2(v[2], v[3]) };
        *(uint2_t*)(XSB + (size_t)i * 4) = p;
    }
}

// ---------------------------------------------------------------------------
// Global attention on 128 tokens/batch. Block per (b, h, qtile of 32).
// ---------------------------------------------------------------------------
__global__ __launch_bounds__(256) void global_attn_kernel(
    const unsigned short* __restrict__ GQKV, unsigned short* __restrict__ GOUT)
{
    const int blk = blockIdx.x;       // b*32 + h*4 + qt
    const int qt = blk & 3, h = (blk >> 2) & 7, b = blk >> 5;
    __shared__ unsigned short ks[128 * 64], vs[128 * 64];
    __shared__ float qs[32 * 64];
    __shared__ float sc[32 * 128];
    const int tid = threadIdx.x;
    for (int idx = tid; idx < 128 * 64; idx += 256) {
        int j = idx >> 6, d = idx & 63;
        const unsigned short* rowp = GQKV + (size_t)(b * 128 + j) * 1536 + h * 64 + d;
        ks[idx] = rowp[512];
        vs[idx] = rowp[1024];
    }
    for (int idx = tid; idx < 32 * 64; idx += 256) {
        int i = idx >> 6, d = idx & 63;
        qs[idx] = b2f(GQKV[(size_t)(b * 128 + qt * 32 + i) * 1536 + h * 64 + d]);
    }
    __syncthreads();
    for (int idx = tid; idx < 32 * 128; idx += 256) {
        int i = idx >> 7, j = idx & 127;
        float s = 0.f;
        #pragma unroll
        for (int d = 0; d < 64; d++) s += qs[i * 64 + d] * b2f(ks[j * 64 + d]);
        sc[idx] = s * 0.125f;
    }
    __syncthreads();
    if (tid < 32) {
        float mx = -1e30f;
        for (int j = 0; j < 128; j++) mx = fmaxf(mx, sc[tid * 128 + j]);
        float sum = 0.f;
        for (int j = 0; j < 128; j++) { float e = __expf(sc[tid * 128 + j] - mx); sc[tid * 128 + j] = e; sum += e; }
        float inv = 1.0f / sum;
        for (int j = 0; j < 128; j++) sc[tid * 128 + j] *= inv;
    }
    __syncthreads();
    for (int idx = tid; idx < 32 * 64; idx += 256) {
        int i = idx >> 6, d = idx & 63;
        float o = 0.f;
        for (int j = 0; j < 128; j++) o += sc[i * 128 + j] * b2f(vs[j * 64 + d]);
        GOUT[(size_t)(b * 128 + qt * 32 + i) * 512 + h * 64 + d] = f2b(o);
    }
}

// ---------------------------------------------------------------------------
// Y = X + dwconv(X) (K=7, zero pad). float4-vectorized. Writes f32 + bf16.
// ---------------------------------------------------------------------------
__global__ __launch_bounds__(256) void dwconv_add_kernel(
    const float* __restrict__ X, const float* __restrict__ wconv, const float* __restrict__ bconv,
    float* __restrict__ Yf, unsigned short* __restrict__ Yb)
{
    int i = blockIdx.x * 256 + threadIdx.x;   // over nel/4 = 2097152
    if (i < 2097152) {
        int dv = (i & 127) * 4;
        int s = (i >> 7) & 4095;
        int b = i >> 19;
        float4_t acc = *(const float4_t*)(bconv + dv);
        #pragma unroll
        for (int t = 0; t < 7; t++) {
            int ss = s + t - 3;
            if (ss >= 0 && ss < 4096) {
                float4_t xv = *(const float4_t*)(X + ((size_t)b * 4096 + ss) * 512 + dv);
                float4_t wv = { wconv[dv * 7 + t], wconv[(dv + 1) * 7 + t],
                                wconv[(dv + 2) * 7 + t], wconv[(dv + 3) * 7 + t] };
                acc += xv * wv;
            }
        }
        size_t e = (size_t)i * 4;
        float4_t v = *(const float4_t*)(X + e) + acc;
        *(float4_t*)(Yf + e) = v;
        uint2_t o = { f2b2(v[0], v[1]), f2b2(v[2], v[3]) };
        *(uint2_t*)(Yb + e) = o;
    }
}

// ---------------------------------------------------------------------------
// out = LN(w0*XL + w1*XG), softmaxed scalar weights. Wave per row.
// ---------------------------------------------------------------------------
__global__ __launch_bounds__(256) void final_kernel(
    const float* __restrict__ XL, const float* __restrict__ XG,
    const float* __restrict__ fwl, const float* __restrict__ fwg,
    const float* __restrict__ g, const float* __restrict__ bb, float* __restrict__ out)
{
    const int row = blockIdx.x * 4 + (threadIdx.x >> 6);
    const int lane = threadIdx.x & 63;
    float a = fwl[0], cc = fwg[0];
    float m = fmaxf(a, cc);
    float ea = __expf(a - m), ec = __expf(cc - m);
    float w0 = ea / (ea + ec), w1 = ec / (ea + ec);
    const float* xlr = XL + (size_t)row * 512 + lane * 8;
    const float* xgr = XG + (size_t)row * 512 + lane * 8;
    float4_t v0 = *(const float4_t*)(xlr)     * w0 + *(const float4_t*)(xgr)     * w1;
    float4_t v1 = *(const float4_t*)(xlr + 4) * w0 + *(const float4_t*)(xgr + 4) * w1;
    float s = v0[0] + v0[1] + v0[2] + v0[3] + v1[0] + v1[1] + v1[2] + v1[3];
    #pragma unroll
    for (int mm = 32; mm > 0; mm >>= 1) s += __shfl_xor(s, mm);
    float mu = s * (1.0f / 512.0f);
    float4_t d0 = v0 - mu, d1 = v1 - mu;
    float s2 = d0[0]*d0[0] + d0[1]*d0[1] + d0[2]*d0[2] + d0[3]*d0[3]
             + d1[0]*d1[0] + d1[1]*d1[1] + d1[2]*d1[2] + d1[3]*d1[3];
    #pragma unroll
    for (int mm = 32; mm > 0; mm >>= 1) s2 += __shfl_xor(s2, mm);
    float rs = rsqrtf(s2 * (1.0f / 512.0f) + 1e-5f);
    float4_t g0 = *(const float4_t*)(g + lane * 8);
    float4_t g1 = *(const float4_t*)(g + lane * 8 + 4);
    float4_t b0 = *(const float4_t*)(bb + lane * 8);
    float4_t b1 = *(const float4_t*)(bb + lane * 8 + 4);
    float* orow = out + (size_t)row * 512 + lane * 8;
    *(float4_t*)(orow)     = d0 * rs * g0 + b0;
    *(float4_t*)(orow + 4) = d1 * rs * g1 + b1;
}

// ---------------------------------------------------------------------------
extern "C" void kernel_launch(void* const* d_in, const int* in_sizes, int n_in,
                              void* d_out, int out_size, void* d_ws, size_t ws_size,
                              hipStream_t stream)
{
    (void)in_sizes; (void)n_in; (void)out_size; (void)ws_size;
    const float* x       = (const float*)d_in[0];
    const float* lqkv_w  = (const float*)d_in[1];
    const float* lqkv_b  = (const float*)d_in[2];
    const float* lproj_w = (const float*)d_in[3];
    const float* lproj_b = (const float*)d_in[4];
    const float* lrel    = (const float*)d_in[5];
    const float* lconv_w = (const float*)d_in[6];
    const float* lconv_b = (const float*)d_in[7];
    const float* ln1_g   = (const float*)d_in[8];
    const float* ln1_b   = (const float*)d_in[9];
    const float* lffn_w1 = (const float*)d_in[10];
    const float* lffn_b1 = (const float*)d_in[11];
    const float* lffn_w2 = (const float*)d_in[12];
    const float* lffn_b2 = (const float*)d_in[13];
    const float* ln2_g   = (const float*)d_in[14];
    const float* ln2_b   = (const float*)d_in[15];
    const float* gqkv_w  = (const float*)d_in[16];
    const float* gqkv_b  = (const float*)d_in[17];
    const float* gproj_w = (const float*)d_in[18];
    const float* gproj_b = (const float*)d_in[19];
    const float* gn1_g   = (const float*)d_in[20];
    const float* gn1_b   = (const float*)d_in[21];
    const float* gffn_w1 = (const float*)d_in[22];
    const float* gffn_b1 = (const float*)d_in[23];
    const float* gffn_w2 = (const float*)d_in[24];
    const float* gffn_b2 = (const float*)d_in[25];
    const float* gn2_g   = (const float*)d_in[26];
    const float* gn2_b   = (const float*)d_in[27];
    const float* fw_local  = (const float*)d_in[28];
    const float* fw_global = (const float*)d_in[29];
    const float* fn_g    = (const float*)d_in[30];
    const float* fn_b    = (const float*)d_in[31];
    float* out = (float*)d_out;

    const int Btot = 4 * 4096;     // 16384 token rows
    const int nel = Btot * 512;    // 8388608

    char* wsb = (char*)d_ws;
    size_t off = 0;
    auto alloc = [&](size_t bytes) -> void* {
        void* p = wsb + off;
        off = (off + bytes + 255) & ~(size_t)255;
        return p;
    };
    float*          XL   = (float*)alloc((size_t)nel * 4);
    float*          XG   = (float*)alloc((size_t)nel * 4);
    float*          TMP  = (float*)alloc((size_t)nel * 4);
    unsigned short* XBl  = (unsigned short*)alloc((size_t)nel * 2);
    unsigned short* XBg  = (unsigned short*)alloc((size_t)nel * 2);
    unsigned short* AOUT = (unsigned short*)alloc((size_t)nel * 2);
    unsigned short* BIG  = (unsigned short*)alloc((size_t)Btot * 2048 * 2);
    unsigned short* WT   = (unsigned short*)alloc((size_t)22020096 * 2);
    unsigned short* XSB  = (unsigned short*)alloc((size_t)512 * 512 * 2);
    unsigned short* GQKV = (unsigned short*)alloc((size_t)512 * 1536 * 2);
    unsigned short* GOUT = (unsigned short*)alloc((size_t)512 * 512 * 2);
    float*          GA   = (float*)alloc((size_t)512 * 512 * 4);

    const size_t perL = 3145728;   // bf16 elems of transposed weights per layer
    // batched weight transposes: 4 launches (qkv, proj, w1, w2), z = 7 layers
    {
        dim3 blk(256);
        transpose_cast_batch_kernel<<<dim3(1536/32, 512/32, 7), blk, 0, stream>>>(
            lqkv_w, gqkv_w, 4, WT, perL, 512, 1536);
        transpose_cast_batch_kernel<<<dim3(512/32, 512/32, 7), blk, 0, stream>>>(
            lproj_w, gproj_w, 4, WT + 786432, perL, 512, 512);
        transpose_cast_batch_kernel<<<dim3(2048/32, 512/32, 7), blk, 0, stream>>>(
            lffn_w1, gffn_w1, 4, WT + 786432 + 262144, perL, 512, 2048);
        transpose_cast_batch_kernel<<<dim3(512/32, 2048/32, 7), blk, 0, stream>>>(
            lffn_w2, gffn_w2, 4, WT + 786432 + 262144 + 1048576, perL, 2048, 512);
    }

    copy_cast_kernel<<<dim3(nel / 1024), dim3(256), 0, stream>>>(x, XL, XG, XBl, nel / 4);

    auto gemm = [&](const unsigned short* A_, const unsigned short* BT_, const float* bias_,
                    const float* res_, float* Cf_, unsigned short* Cb_,
                    int M_, int N_, int K_, int act_) {
        if (N_ >= 1024) {
            dim3 g(M_ / 128, N_ / 128);
            gemm_db_kernel<128><<<g, dim3(256), 0, stream>>>(A_, BT_, bias_, res_, Cf_, Cb_, M_, N_, K_, act_);
        } else {
            dim3 g(M_ / 128, N_ / 64);
            gemm_db_kernel<64><<<g, dim3(256), 0, stream>>>(A_, BT_, bias_, res_, Cf_, Cb_, M_, N_, K_, act_);
        }
    };

    // ---------------- local branch: 4 layers ----------------
    for (int i = 0; i < 4; i++) {
        unsigned short* base  = WT + (size_t)i * perL;
        unsigned short* qkvT  = base;
        unsigned short* projT = base + 786432;
        unsigned short* w1T   = base + 786432 + 262144;
        unsigned short* w2T   = base + 786432 + 262144 + 1048576;

        gemm(XBl, qkvT, lqkv_b + i * 1536, nullptr, nullptr, BIG, Btot, 1536, 512, 0);
        local_attn_kernel<<<dim3(4096), dim3(256), 0, stream>>>(BIG, lrel + (size_t)i * 63 * 8, AOUT);
        gemm(AOUT, projT, lproj_b + i * 512, XL, TMP, nullptr, Btot, 512, 512, 0);
        ln_kernel<<<dim3(Btot / 4), dim3(256), 0, stream>>>(TMP, ln1_g + i * 512, ln1_b + i * 512, XL, (unsigned short*)nullptr);
        dwconv_add_kernel<<<dim3(nel / 1024), dim3(256), 0, stream>>>(XL, lconv_w + (size_t)i * 512 * 7, lconv_b + i * 512, TMP, XBl);
        gemm(XBl, w1T, lffn_b1 + i * 2048, nullptr, nullptr, BIG, Btot, 2048, 512, 1);
        gemm(BIG, w2T, lffn_b2 + i * 512, TMP, TMP, nullptr, Btot, 512, 2048, 0);
        ln_kernel<<<dim3(Btot / 4), dim3(256), 0, stream>>>(TMP, ln2_g + i * 512, ln2_b + i * 512, XL, XBl);
    }

    // ---------------- global branch: 3 layers ----------------
    for (int i = 0; i < 3; i++) {
        unsigned short* base  = WT + (size_t)(4 + i) * perL;
        unsigned short* qkvT  = base;
        unsigned short* projT = base + 786432;
        unsigned short* w1T   = base + 786432 + 262144;
        unsigned short* w2T   = base + 786432 + 262144 + 1048576;

        gather_xs_kernel<<<dim3(256), dim3(256), 0, stream>>>(XG, XSB);
        gemm(XSB, qkvT, gqkv_b + i * 1536, nullptr, nullptr, GQKV, 512, 1536, 512, 0);
        global_attn_kernel<<<dim3(128), dim3(256), 0, stream>>>(GQKV, GOUT);
        gemm(GOUT, projT, gproj_b + i * 512, nullptr, GA, nullptr, 512, 512, 512, 0);
        interp_ln_kernel<<<dim3(Btot / 4), dim3(256), 0, stream>>>(GA, XG, gn1_g + i * 512, gn1_b + i * 512, XBg);
        gemm(XBg, w1T, gffn_b1 + i * 2048, nullptr, nullptr, BIG, Btot, 2048, 512, 1);
        gemm(BIG, w2T, gffn_b2 + i * 512, XG, TMP, nullptr, Btot, 512, 2048, 0);
        ln_kernel<<<dim3(Btot / 4), dim3(256), 0, stream>>>(TMP, gn2_g + i * 512, gn2_b + i * 512, XG, XBg);
    }

    final_kernel<<<dim3(Btot / 4), dim3(256), 0, stream>>>(XL, XG, fw_local, fw_global, fn_g, fn_b, out);
}

// Round 7
// 1885.141 us; speedup vs baseline: 1.4745x; 1.0939x over previous
//
#include <hip/hip_runtime.h>
#include <hip/hip_bf16.h>
#include <math.h>

typedef __attribute__((ext_vector_type(8))) short short8;
typedef __attribute__((ext_vector_type(4))) float float4_t;
typedef __attribute__((ext_vector_type(4))) unsigned int uint4_t;
typedef __attribute__((ext_vector_type(2))) unsigned int uint2_t;

#define DEV static __device__ __forceinline__

DEV unsigned short f2b(float f) {
    union { float f; unsigned int u; } x; x.f = f;
    unsigned int r = x.u + 0x7fffu + ((x.u >> 16) & 1u);
    return (unsigned short)(r >> 16);
}
DEV float b2f(unsigned short u) {
    union { unsigned int u; float f; } x; x.u = ((unsigned int)u) << 16;
    return x.f;
}
// packed 2x f32 -> 2x bf16 (v_cvt_pk_bf16_f32 on gfx950, RNE)
DEV unsigned int f2b2(float lo, float hi) {
    union { __hip_bfloat162 h; unsigned int u; } c;
    c.h = __float22bfloat162_rn(make_float2(lo, hi));
    return c.u;
}
// gelu(x) = x / (1 + 2^(a*x + b*x^3));  a = -2*0.7978845608*log2(e)
DEV float gelu_f(float x) {
    const float a = -2.3022082f, b = -0.10294372f;
    float x2 = x * x;
    float p = __builtin_fmaf(x2, b, a);          // a + b*x^2
    float e = __builtin_amdgcn_exp2f(p * x);     // 2^(a x + b x^3)
    return x * __builtin_amdgcn_rcpf(1.0f + e);
}

DEV void gld16(unsigned short* lds, const unsigned short* g) {
    __builtin_amdgcn_global_load_lds(
        (const __attribute__((address_space(1))) unsigned int*)g,
        (__attribute__((address_space(3))) unsigned int*)lds,
        16, 0, 0);
}

// ---------------------------------------------------------------------------
// Batched tiled transpose + cast: W[z] (K x N, f32) -> WT[z] (N x K, bf16)
// ---------------------------------------------------------------------------
__global__ __launch_bounds__(256) void transpose_cast_batch_kernel(
    const float* __restrict__ srcL, const float* __restrict__ srcG, int nl,
    unsigned short* __restrict__ dst0, size_t perL, int Kd, int Nd)
{
    const int z = blockIdx.z;
    const float* W = (z < nl) ? srcL + (size_t)z * Kd * Nd
                              : srcG + (size_t)(z - nl) * Kd * Nd;
    unsigned short* WT = dst0 + (size_t)z * perL;
    __shared__ float tile[32][33];
    int n0 = blockIdx.x * 32, k0 = blockIdx.y * 32;
    int tx = threadIdx.x & 31, ty = threadIdx.x >> 5;   // 32 x 8
    #pragma unroll
    for (int r = ty; r < 32; r += 8)
        tile[r][tx] = W[(size_t)(k0 + r) * Nd + n0 + tx];
    __syncthreads();
    #pragma unroll
    for (int r = ty; r < 32; r += 8)
        WT[(size_t)(n0 + r) * Kd + k0 + tx] = f2b(tile[tx][r]);
}

// ---------------------------------------------------------------------------
// copy x -> XL (f32), XG (f32), XB (bf16), float4-vectorized
// ---------------------------------------------------------------------------
__global__ __launch_bounds__(256) void copy_cast_kernel(
    const float* __restrict__ x, float* __restrict__ xl, float* __restrict__ xg,
    unsigned short* __restrict__ xb, int n4)
{
    int i = blockIdx.x * 256 + threadIdx.x;
    if (i < n4) {
        float4_t v = ((const float4_t*)x)[i];
        ((float4_t*)xl)[i] = v;
        ((float4_t*)xg)[i] = v;
        uint2_t p = { f2b2(v[0], v[1]), f2b2(v[2], v[3]) };
        ((uint2_t*)xb)[i] = p;
    }
}

// ---------------------------------------------------------------------------
// bf16 MFMA GEMM, double-buffered K-loop, operand-swapped MFMA (row-major
// vectorized epilogue). BN=128: 4 waves 2x2, 64x64/wave. BN=64: stacked on M.
// ---------------------------------------------------------------------------
template<int BN>
__global__ __launch_bounds__(256, 3) void gemm_db_kernel(
    const unsigned short* __restrict__ A,
    const unsigned short* __restrict__ BT,
    const float* __restrict__ bias,
    const float* __restrict__ residual,
    float* __restrict__ Cf,
    unsigned short* __restrict__ Cb,
    int M, int N, int K, int act)
{
    constexpr int NI = (BN == 128) ? 4 : 2;
    __shared__ __align__(16) unsigned short As[2][128 * 32];
    __shared__ __align__(16) unsigned short Bs[2][BN * 32];
    const int tid = threadIdx.x;
    const int wave = tid >> 6, lane = tid & 63;
    const int quad = lane >> 4, l16 = lane & 15;
    const int m0 = blockIdx.x * 128, n0 = blockIdx.y * BN;
    const int wm = (BN == 128) ? (wave >> 1) * 64 : wave * 32;
    const int wn = (BN == 128) ? (wave & 1) * 64 : 0;

    float4_t acc[NI][4] = {};

    const int lrow = lane >> 2;
    const int lcol = (lane & 3) * 8;
    const int r0 = wave * 16 + lrow;
    const unsigned short* Ag0 = A  + (size_t)(m0 + r0) * K + lcol;
    const unsigned short* Ag1 = A  + (size_t)(m0 + 64 + r0) * K + lcol;
    const unsigned short* Bg0 = BT + (size_t)(n0 + r0) * K + lcol;
    const unsigned short* Bg1 = (BN == 128) ? BT + (size_t)(n0 + 64 + r0) * K + lcol : nullptr;
    const int soff = (wave * 16) * 32 + lane * 8;

    const int iters = K >> 5;
    gld16(&As[0][soff], Ag0);
    gld16(&As[0][soff + 64 * 32], Ag1);
    gld16(&Bs[0][soff], Bg0);
    if (BN == 128) gld16(&Bs[0][soff + 64 * 32], Bg1);
    __syncthreads();

    for (int k = 0; k < iters; k++) {
        const int cur = k & 1;
        if (k + 1 < iters) {
            const int koff = (k + 1) << 5;
            const int nxt = cur ^ 1;
            gld16(&As[nxt][soff], Ag0 + koff);
            gld16(&As[nxt][soff + 64 * 32], Ag1 + koff);
            gld16(&Bs[nxt][soff], Bg0 + koff);
            if (BN == 128) gld16(&Bs[nxt][soff + 64 * 32], Bg1 + koff);
        }
        short8 a[NI], b[4];
        #pragma unroll
        for (int i = 0; i < NI; i++)
            a[i] = *(const short8*)(&As[cur][(wm + i * 16 + l16) * 32 + quad * 8]);
        #pragma unroll
        for (int j = 0; j < 4; j++)
            b[j] = *(const short8*)(&Bs[cur][(wn + j * 16 + l16) * 32 + quad * 8]);
        #pragma unroll
        for (int i = 0; i < NI; i++)
            #pragma unroll
            for (int j = 0; j < 4; j++)
                acc[i][j] = __builtin_amdgcn_mfma_f32_16x16x32_bf16(b[j], a[i], acc[i][j], 0, 0, 0);
        __syncthreads();
    }

    #pragma unroll
    for (int i = 0; i < NI; i++) {
        const int row = m0 + wm + i * 16 + l16;
        #pragma unroll
        for (int j = 0; j < 4; j++) {
            const int col = n0 + wn + j * 16 + quad * 4;
            const size_t idx = (size_t)row * N + col;
            float4_t v = acc[i][j] + *(const float4_t*)(bias + col);
            if (act == 1) {
                #pragma unroll
                for (int r = 0; r < 4; r++) v[r] = gelu_f(v[r]);
            }
            if (residual) v += *(const float4_t*)(residual + idx);
            if (Cf) *(float4_t*)(Cf + idx) = v;
            if (Cb) {
                uint2_t o = { f2b2(v[0], v[1]), f2b2(v[2], v[3]) };
                *(uint2_t*)(Cb + idx) = o;
            }
        }
    }
}

// ---------------------------------------------------------------------------
// LayerNorm over D=512, one WAVE per row (no barriers). 4 rows/block.
// ---------------------------------------------------------------------------
__global__ __launch_bounds__(256) void ln_kernel(
    const float* __restrict__ X, const float* __restrict__ g, const float* __restrict__ b,
    float* __restrict__ Yf, unsigned short* __restrict__ Yb)
{
    const int row = blockIdx.x * 4 + (threadIdx.x >> 6);
    const int lane = threadIdx.x & 63;
    const float* xr = X + (size_t)row * 512 + lane * 8;
    float4_t v0 = *(const float4_t*)(xr);
    float4_t v1 = *(const float4_t*)(xr + 4);
    float s = v0[0] + v0[1] + v0[2] + v0[3] + v1[0] + v1[1] + v1[2] + v1[3];
    #pragma unroll
    for (int m = 32; m > 0; m >>= 1) s += __shfl_xor(s, m);
    float mu = s * (1.0f / 512.0f);
    float4_t d0 = v0 - mu, d1 = v1 - mu;
    float s2 = d0[0]*d0[0] + d0[1]*d0[1] + d0[2]*d0[2] + d0[3]*d0[3]
             + d1[0]*d1[0] + d1[1]*d1[1] + d1[2]*d1[2] + d1[3]*d1[3];
    #pragma unroll
    for (int m = 32; m > 0; m >>= 1) s2 += __shfl_xor(s2, m);
    float rs = rsqrtf(s2 * (1.0f / 512.0f) + 1e-5f);
    float4_t g0 = *(const float4_t*)(g + lane * 8);
    float4_t g1 = *(const float4_t*)(g + lane * 8 + 4);
    float4_t b0 = *(const float4_t*)(b + lane * 8);
    float4_t b1 = *(const float4_t*)(b + lane * 8 + 4);
    float4_t y0 = d0 * rs * g0 + b0;
    float4_t y1 = d1 * rs * g1 + b1;
    if (Yf) {
        float* yr = Yf + (size_t)row * 512 + lane * 8;
        *(float4_t*)(yr) = y0;
        *(float4_t*)(yr + 4) = y1;
    }
    if (Yb) {
        uint4_t pk = { f2b2(y0[0], y0[1]), f2b2(y0[2], y0[3]),
                       f2b2(y1[0], y1[1]), f2b2(y1[2], y1[3]) };
        *(uint4_t*)(Yb + (size_t)row * 512 + lane * 8) = pk;
    }
}

// ---------------------------------------------------------------------------
// Fused: v = XG + lin_interp(GA 128->4096); XG = LN(v); XBg = bf16. Wave/row.
// ---------------------------------------------------------------------------
__global__ __launch_bounds__(256) void interp_ln_kernel(
    const float* __restrict__ GA, float* __restrict__ XG,
    const float* __restrict__ g, const float* __restrict__ b,
    unsigned short* __restrict__ Yb)
{
    const int row = blockIdx.x * 4 + (threadIdx.x >> 6);
    const int lane = threadIdx.x & 63;
    const int bb = row >> 12, sfull = row & 4095;
    float pos = (sfull + 0.5f) * (128.0f / 4096.0f) - 0.5f;
    pos = fminf(fmaxf(pos, 0.0f), 127.0f);
    int i0 = (int)floorf(pos);
    int i1 = min(i0 + 1, 127);
    float w = pos - (float)i0;
    const float* ga0 = GA + ((size_t)bb * 128 + i0) * 512 + lane * 8;
    const float* ga1 = GA + ((size_t)bb * 128 + i1) * 512 + lane * 8;
    float* xr = XG + (size_t)row * 512 + lane * 8;
    float4_t v0 = *(const float4_t*)(xr)     + *(const float4_t*)(ga0)     * (1.0f - w) + *(const float4_t*)(ga1)     * w;
    float4_t v1 = *(const float4_t*)(xr + 4) + *(const float4_t*)(ga0 + 4) * (1.0f - w) + *(const float4_t*)(ga1 + 4) * w;
    float s = v0[0] + v0[1] + v0[2] + v0[3] + v1[0] + v1[1] + v1[2] + v1[3];
    #pragma unroll
    for (int m = 32; m > 0; m >>= 1) s += __shfl_xor(s, m);
    float mu = s * (1.0f / 512.0f);
    float4_t d0 = v0 - mu, d1 = v1 - mu;
    float s2 = d0[0]*d0[0] + d0[1]*d0[1] + d0[2]*d0[2] + d0[3]*d0[3]
             + d1[0]*d1[0] + d1[1]*d1[1] + d1[2]*d1[2] + d1[3]*d1[3];
    #pragma unroll
    for (int m = 32; m > 0; m >>= 1) s2 += __shfl_xor(s2, m);
    float rs = rsqrtf(s2 * (1.0f / 512.0f) + 1e-5f);
    float4_t g0 = *(const float4_t*)(g + lane * 8);
    float4_t g1 = *(const float4_t*)(g + lane * 8 + 4);
    float4_t b0 = *(const float4_t*)(b + lane * 8);
    float4_t b1 = *(const float4_t*)(b + lane * 8 + 4);
    float4_t y0 = d0 * rs * g0 + b0;
    float4_t y1 = d1 * rs * g1 + b1;
    *(float4_t*)(xr) = y0;
    *(float4_t*)(xr + 4) = y1;
    uint4_t pk = { f2b2(y0[0], y0[1]), f2b2(y0[2], y0[3]),
                   f2b2(y1[0], y1[1]), f2b2(y1[2], y1[3]) };
    *(uint4_t*)(Yb + (size_t)row * 512 + lane * 8) = pk;
}

// ---------------------------------------------------------------------------
// Local windowed attention. Block per (b, win, h). short8 loads, 256-thread
// softmax (8 lanes/row), packed 16B output stores. k padded [32][65].
// ---------------------------------------------------------------------------
__global__ __launch_bounds__(256) void local_attn_kernel(
    const unsigned short* __restrict__ QKV, const float* __restrict__ rel,
    unsigned short* __restrict__ OUT)
{
    const int blk = blockIdx.x;          // (b*128 + win)*8 + h
    const int h = blk & 7;
    const int win = (blk >> 3) & 127;
    const int b = blk >> 10;
    const int rowbase = b * 4096 + win * 32;
    __shared__ float q[32][64], k[32][65], v[32][64];
    __shared__ float sc[32][33];
    const int tid = threadIdx.x;
    const int i = tid >> 3, c = tid & 7;     // row 0..31, chunk 0..7
    {
        const unsigned short* base = QKV + (size_t)(rowbase + i) * 1536 + h * 64 + c * 8;
        short8 qv = *(const short8*)(base);
        short8 kv = *(const short8*)(base + 512);
        short8 vv = *(const short8*)(base + 1024);
        #pragma unroll
        for (int r = 0; r < 8; r++) {
            q[i][c * 8 + r] = b2f((unsigned short)qv[r]);
            k[i][c * 8 + r] = b2f((unsigned short)kv[r]);
            v[i][c * 8 + r] = b2f((unsigned short)vv[r]);
        }
    }
    __syncthreads();
    #pragma unroll
    for (int p = 0; p < 4; p++) {
        int idx = tid + p * 256;
        int si = idx >> 5, sj = idx & 31;
        float s = 0.f;
        #pragma unroll
        for (int d = 0; d < 64; d++) s += q[si][d] * k[sj][d];
        sc[si][sj] = s * 0.125f + rel[(si - sj + 31) * 8 + h];
    }
    __syncthreads();
    {
        const int j0 = c * 4;
        float a0 = sc[i][j0], a1 = sc[i][j0 + 1], a2 = sc[i][j0 + 2], a3 = sc[i][j0 + 3];
        float mx = fmaxf(fmaxf(a0, a1), fmaxf(a2, a3));
        #pragma unroll
        for (int m = 1; m < 8; m <<= 1) mx = fmaxf(mx, __shfl_xor(mx, m));
        float e0 = __expf(a0 - mx), e1 = __expf(a1 - mx), e2 = __expf(a2 - mx), e3 = __expf(a3 - mx);
        float sum = e0 + e1 + e2 + e3;
        #pragma unroll
        for (int m = 1; m < 8; m <<= 1) sum += __shfl_xor(sum, m);
        float inv = 1.0f / sum;
        sc[i][j0] = e0 * inv; sc[i][j0 + 1] = e1 * inv; sc[i][j0 + 2] = e2 * inv; sc[i][j0 + 3] = e3 * inv;
    }
    __syncthreads();
    float o[8] = {};
    #pragma unroll
    for (int j = 0; j < 32; j++) {
        float a = sc[i][j];
        #pragma unroll
        for (int r = 0; r < 8; r++) o[r] += a * v[j][c * 8 + r];
    }
    uint4_t pk = { f2b2(o[0], o[1]), f2b2(o[2], o[3]), f2b2(o[4], o[5]), f2b2(o[6], o[7]) };
    *(uint4_t*)(OUT + (size_t)(rowbase + i) * 512 + h * 64 + c * 8) = pk;
}

// ---------------------------------------------------------------------------
// Gather strided tokens for global attention (float4 + packed cvt)
// ---------------------------------------------------------------------------
__global__ __launch_bounds__(256) void gather_xs_kernel(
    const float* __restrict__ XG, unsigned short* __restrict__ XSB)
{
    int i = blockIdx.x * 256 + threadIdx.x;   // 65536 = 262144/4
    if (i < 65536) {
        int dv = (i & 127) * 4, t = (i >> 7) & 127, b = i >> 14;
        float4_t v = *(const float4_t*)(XG + ((size_t)b * 4096 + t * 32) * 512 + dv);
        uint2_t p = { f2b2(v[0], v[1]), f2b2(v[2], v[3]) };
        *(uint2_t*)(XSB + (size_t)i * 4) = p;
    }
}

// ---------------------------------------------------------------------------
// Global attention on 128 tokens/batch. Block per (b, h, qtile of 32).
// ---------------------------------------------------------------------------
__global__ __launch_bounds__(256) void global_attn_kernel(
    const unsigned short* __restrict__ GQKV, unsigned short* __restrict__ GOUT)
{
    const int blk = blockIdx.x;       // b*32 + h*4 + qt
    const int qt = blk & 3, h = (blk >> 2) & 7, b = blk >> 5;
    __shared__ unsigned short ks[128 * 64], vs[128 * 64];
    __shared__ float qs[32 * 64];
    __shared__ float sc[32 * 128];
    const int tid = threadIdx.x;
    for (int idx = tid; idx < 128 * 64; idx += 256) {
        int j = idx >> 6, d = idx & 63;
        const unsigned short* rowp = GQKV + (size_t)(b * 128 + j) * 1536 + h * 64 + d;
        ks[idx] = rowp[512];
        vs[idx] = rowp[1024];
    }
    for (int idx = tid; idx < 32 * 64; idx += 256) {
        int i = idx >> 6, d = idx & 63;
        qs[idx] = b2f(GQKV[(size_t)(b * 128 + qt * 32 + i) * 1536 + h * 64 + d]);
    }
    __syncthreads();
    for (int idx = tid; idx < 32 * 128; idx += 256) {
        int i = idx >> 7, j = idx & 127;
        float s = 0.f;
        #pragma unroll
        for (int d = 0; d < 64; d++) s += qs[i * 64 + d] * b2f(ks[j * 64 + d]);
        sc[idx] = s * 0.125f;
    }
    __syncthreads();
    if (tid < 32) {
        float mx = -1e30f;
        for (int j = 0; j < 128; j++) mx = fmaxf(mx, sc[tid * 128 + j]);
        float sum = 0.f;
        for (int j = 0; j < 128; j++) { float e = __expf(sc[tid * 128 + j] - mx); sc[tid * 128 + j] = e; sum += e; }
        float inv = 1.0f / sum;
        for (int j = 0; j < 128; j++) sc[tid * 128 + j] *= inv;
    }
    __syncthreads();
    for (int idx = tid; idx < 32 * 64; idx += 256) {
        int i = idx >> 6, d = idx & 63;
        float o = 0.f;
        for (int j = 0; j < 128; j++) o += sc[i * 128 + j] * b2f(vs[j * 64 + d]);
        GOUT[(size_t)(b * 128 + qt * 32 + i) * 512 + h * 64 + d] = f2b(o);
    }
}

// ---------------------------------------------------------------------------
// Y = X + dwconv(X): sliding-window register version.
// Block = (b, 16 s-rows) x 512 ch. Thread: dv = (tid&127)*4, 8 consecutive s.
// Weights staged transposed in LDS (wT[t][d] -> ds_read_b128, conflict-free);
// X held in a 14-entry float4 window (residual = window center, no re-read).
// ---------------------------------------------------------------------------
__global__ __launch_bounds__(256) void dwconv_add_kernel(
    const float* __restrict__ X, const float* __restrict__ wconv, const float* __restrict__ bconv,
    float* __restrict__ Yf, unsigned short* __restrict__ Yb)
{
    __shared__ float wT[7][512];
    const int tid = threadIdx.x;
    for (int idx = tid; idx < 3584; idx += 256) {
        int d = idx / 7, t = idx - d * 7;       // wconv[d*7+t] -> wT[t][d]
        wT[t][d] = wconv[idx];
    }
    __syncthreads();
    const int b = blockIdx.y;
    const int s0 = blockIdx.x * 16 + (tid >> 7) * 8;   // first output s
    const int dv = (tid & 127) * 4;
    const float* Xb = X + ((size_t)b * 4096) * 512 + dv;

    float4_t win[14];
    #pragma unroll
    for (int j = 0; j < 14; j++) {
        int ss = s0 - 3 + j;
        win[j] = (ss >= 0 && ss < 4096) ? *(const float4_t*)(Xb + (size_t)ss * 512)
                                        : (float4_t){0.f, 0.f, 0.f, 0.f};
    }
    float4_t bias = *(const float4_t*)(bconv + dv);
    float4_t w[7];
    #pragma unroll
    for (int t = 0; t < 7; t++) w[t] = *(const float4_t*)(&wT[t][dv]);

    #pragma unroll
    for (int j = 0; j < 8; j++) {
        float4_t acc = bias;
        #pragma unroll
        for (int t = 0; t < 7; t++) acc += win[j + t] * w[t];
        float4_t v = win[j + 3] + acc;          // residual from window center
        size_t e = ((size_t)b * 4096 + s0 + j) * 512 + dv;
        *(float4_t*)(Yf + e) = v;
        uint2_t o = { f2b2(v[0], v[1]), f2b2(v[2], v[3]) };
        *(uint2_t*)(Yb + e) = o;
    }
}

// ---------------------------------------------------------------------------
// out = LN(w0*XL + w1*XG), softmaxed scalar weights. Wave per row.
// ---------------------------------------------------------------------------
__global__ __launch_bounds__(256) void final_kernel(
    const float* __restrict__ XL, const float* __restrict__ XG,
    const float* __restrict__ fwl, const float* __restrict__ fwg,
    const float* __restrict__ g, const float* __restrict__ bb, float* __restrict__ out)
{
    const int row = blockIdx.x * 4 + (threadIdx.x >> 6);
    const int lane = threadIdx.x & 63;
    float a = fwl[0], cc = fwg[0];
    float m = fmaxf(a, cc);
    float ea = __expf(a - m), ec = __expf(cc - m);
    float w0 = ea / (ea + ec), w1 = ec / (ea + ec);
    const float* xlr = XL + (size_t)row * 512 + lane * 8;
    const float* xgr = XG + (size_t)row * 512 + lane * 8;
    float4_t v0 = *(const float4_t*)(xlr)     * w0 + *(const float4_t*)(xgr)     * w1;
    float4_t v1 = *(const float4_t*)(xlr + 4) * w0 + *(const float4_t*)(xgr + 4) * w1;
    float s = v0[0] + v0[1] + v0[2] + v0[3] + v1[0] + v1[1] + v1[2] + v1[3];
    #pragma unroll
    for (int mm = 32; mm > 0; mm >>= 1) s += __shfl_xor(s, mm);
    float mu = s * (1.0f / 512.0f);
    float4_t d0 = v0 - mu, d1 = v1 - mu;
    float s2 = d0[0]*d0[0] + d0[1]*d0[1] + d0[2]*d0[2] + d0[3]*d0[3]
             + d1[0]*d1[0] + d1[1]*d1[1] + d1[2]*d1[2] + d1[3]*d1[3];
    #pragma unroll
    for (int mm = 32; mm > 0; mm >>= 1) s2 += __shfl_xor(s2, mm);
    float rs = rsqrtf(s2 * (1.0f / 512.0f) + 1e-5f);
    float4_t g0 = *(const float4_t*)(g + lane * 8);
    float4_t g1 = *(const float4_t*)(g + lane * 8 + 4);
    float4_t b0 = *(const float4_t*)(bb + lane * 8);
    float4_t b1 = *(const float4_t*)(bb + lane * 8 + 4);
    float* orow = out + (size_t)row * 512 + lane * 8;
    *(float4_t*)(orow)     = d0 * rs * g0 + b0;
    *(float4_t*)(orow + 4) = d1 * rs * g1 + b1;
}

// ---------------------------------------------------------------------------
extern "C" void kernel_launch(void* const* d_in, const int* in_sizes, int n_in,
                              void* d_out, int out_size, void* d_ws, size_t ws_size,
                              hipStream_t stream)
{
    (void)in_sizes; (void)n_in; (void)out_size; (void)ws_size;
    const float* x       = (const float*)d_in[0];
    const float* lqkv_w  = (const float*)d_in[1];
    const float* lqkv_b  = (const float*)d_in[2];
    const float* lproj_w = (const float*)d_in[3];
    const float* lproj_b = (const float*)d_in[4];
    const float* lrel    = (const float*)d_in[5];
    const float* lconv_w = (const float*)d_in[6];
    const float* lconv_b = (const float*)d_in[7];
    const float* ln1_g   = (const float*)d_in[8];
    const float* ln1_b   = (const float*)d_in[9];
    const float* lffn_w1 = (const float*)d_in[10];
    const float* lffn_b1 = (const float*)d_in[11];
    const float* lffn_w2 = (const float*)d_in[12];
    const float* lffn_b2 = (const float*)d_in[13];
    const float* ln2_g   = (const float*)d_in[14];
    const float* ln2_b   = (const float*)d_in[15];
    const float* gqkv_w  = (const float*)d_in[16];
    const float* gqkv_b  = (const float*)d_in[17];
    const float* gproj_w = (const float*)d_in[18];
    const float* gproj_b = (const float*)d_in[19];
    const float* gn1_g   = (const float*)d_in[20];
    const float* gn1_b   = (const float*)d_in[21];
    const float* gffn_w1 = (const float*)d_in[22];
    const float* gffn_b1 = (const float*)d_in[23];
    const float* gffn_w2 = (const float*)d_in[24];
    const float* gffn_b2 = (const float*)d_in[25];
    const float* gn2_g   = (const float*)d_in[26];
    const float* gn2_b   = (const float*)d_in[27];
    const float* fw_local  = (const float*)d_in[28];
    const float* fw_global = (const float*)d_in[29];
    const float* fn_g    = (const float*)d_in[30];
    const float* fn_b    = (const float*)d_in[31];
    float* out = (float*)d_out;

    const int Btot = 4 * 4096;     // 16384 token rows
    const int nel = Btot * 512;    // 8388608

    char* wsb = (char*)d_ws;
    size_t off = 0;
    auto alloc = [&](size_t bytes) -> void* {
        void* p = wsb + off;
        off = (off + bytes + 255) & ~(size_t)255;
        return p;
    };
    float*          XL   = (float*)alloc((size_t)nel * 4);
    float*          XG   = (float*)alloc((size_t)nel * 4);
    float*          TMP  = (float*)alloc((size_t)nel * 4);
    unsigned short* XBl  = (unsigned short*)alloc((size_t)nel * 2);
    unsigned short* XBg  = (unsigned short*)alloc((size_t)nel * 2);
    unsigned short* AOUT = (unsigned short*)alloc((size_t)nel * 2);
    unsigned short* BIG  = (unsigned short*)alloc((size_t)Btot * 2048 * 2);
    unsigned short* WT   = (unsigned short*)alloc((size_t)22020096 * 2);
    unsigned short* XSB  = (unsigned short*)alloc((size_t)512 * 512 * 2);
    unsigned short* GQKV = (unsigned short*)alloc((size_t)512 * 1536 * 2);
    unsigned short* GOUT = (unsigned short*)alloc((size_t)512 * 512 * 2);
    float*          GA   = (float*)alloc((size_t)512 * 512 * 4);

    const size_t perL = 3145728;   // bf16 elems of transposed weights per layer
    {
        dim3 blk(256);
        transpose_cast_batch_kernel<<<dim3(1536/32, 512/32, 7), blk, 0, stream>>>(
            lqkv_w, gqkv_w, 4, WT, perL, 512, 1536);
        transpose_cast_batch_kernel<<<dim3(512/32, 512/32, 7), blk, 0, stream>>>(
            lproj_w, gproj_w, 4, WT + 786432, perL, 512, 512);
        transpose_cast_batch_kernel<<<dim3(2048/32, 512/32, 7), blk, 0, stream>>>(
            lffn_w1, gffn_w1, 4, WT + 786432 + 262144, perL, 512, 2048);
        transpose_cast_batch_kernel<<<dim3(512/32, 2048/32, 7), blk, 0, stream>>>(
            lffn_w2, gffn_w2, 4, WT + 786432 + 262144 + 1048576, perL, 2048, 512);
    }

    copy_cast_kernel<<<dim3(nel / 1024), dim3(256), 0, stream>>>(x, XL, XG, XBl, nel / 4);

    auto gemm = [&](const unsigned short* A_, const unsigned short* BT_, const float* bias_,
                    const float* res_, float* Cf_, unsigned short* Cb_,
                    int M_, int N_, int K_, int act_) {
        if (N_ >= 1024) {
            dim3 g(M_ / 128, N_ / 128);
            gemm_db_kernel<128><<<g, dim3(256), 0, stream>>>(A_, BT_, bias_, res_, Cf_, Cb_, M_, N_, K_, act_);
        } else {
            dim3 g(M_ / 128, N_ / 64);
            gemm_db_kernel<64><<<g, dim3(256), 0, stream>>>(A_, BT_, bias_, res_, Cf_, Cb_, M_, N_, K_, act_);
        }
    };

    // ---------------- local branch: 4 layers ----------------
    for (int i = 0; i < 4; i++) {
        unsigned short* base  = WT + (size_t)i * perL;
        unsigned short* qkvT  = base;
        unsigned short* projT = base + 786432;
        unsigned short* w1T   = base + 786432 + 262144;
        unsigned short* w2T   = base + 786432 + 262144 + 1048576;

        gemm(XBl, qkvT, lqkv_b + i * 1536, nullptr, nullptr, BIG, Btot, 1536, 512, 0);
        local_attn_kernel<<<dim3(4096), dim3(256), 0, stream>>>(BIG, lrel + (size_t)i * 63 * 8, AOUT);
        gemm(AOUT, projT, lproj_b + i * 512, XL, TMP, nullptr, Btot, 512, 512, 0);
        ln_kernel<<<dim3(Btot / 4), dim3(256), 0, stream>>>(TMP, ln1_g + i * 512, ln1_b + i * 512, XL, (unsigned short*)nullptr);
        dwconv_add_kernel<<<dim3(256, 4), dim3(256), 0, stream>>>(XL, lconv_w + (size_t)i * 512 * 7, lconv_b + i * 512, TMP, XBl);
        gemm(XBl, w1T, lffn_b1 + i * 2048, nullptr, nullptr, BIG, Btot, 2048, 512, 1);
        gemm(BIG, w2T, lffn_b2 + i * 512, TMP, TMP, nullptr, Btot, 512, 2048, 0);
        ln_kernel<<<dim3(Btot / 4), dim3(256), 0, stream>>>(TMP, ln2_g + i * 512, ln2_b + i * 512, XL, XBl);
    }

    // ---------------- global branch: 3 layers ----------------
    for (int i = 0; i < 3; i++) {
        unsigned short* base  = WT + (size_t)(4 + i) * perL;
        unsigned short* qkvT  = base;
        unsigned short* projT = base + 786432;
        unsigned short* w1T   = base + 786432 + 262144;
        unsigned short* w2T   = base + 786432 + 262144 + 1048576;

        gather_xs_kernel<<<dim3(256), dim3(256), 0, stream>>>(XG, XSB);
        gemm(XSB, qkvT, gqkv_b + i * 1536, nullptr, nullptr, GQKV, 512, 1536, 512, 0);
        global_attn_kernel<<<dim3(128), dim3(256), 0, stream>>>(GQKV, GOUT);
        gemm(GOUT, projT, gproj_b + i * 512, nullptr, GA, nullptr, 512, 512, 512, 0);
        interp_ln_kernel<<<dim3(Btot / 4), dim3(256), 0, stream>>>(GA, XG, gn1_g + i * 512, gn1_b + i * 512, XBg);
        gemm(XBg, w1T, gffn_b1 + i * 2048, nullptr, nullptr, BIG, Btot, 2048, 512, 1);
        gemm(BIG, w2T, gffn_b2 + i * 512, XG, TMP, nullptr, Btot, 512, 2048, 0);
        ln_kernel<<<dim3(Btot / 4), dim3(256), 0, stream>>>(TMP, gn2_g + i * 512, gn2_b + i * 512, XG, XBg);
    }

    final_kernel<<<dim3(Btot / 4), dim3(256), 0, stream>>>(XL, XG, fw_local, fw_global, fn_g, fn_b, out);
}